// Round 4
// baseline (844.854 us; speedup 1.0000x reference)
//
#include <hip/hip_runtime.h>

typedef unsigned short u16;
typedef unsigned int u32;
typedef u16 u16x8 __attribute__((ext_vector_type(8)));
typedef short s16x8 __attribute__((ext_vector_type(8)));
typedef float f32x4 __attribute__((ext_vector_type(4)));

#define NN 32768
#define EE 262144
#define DD 512
#define WMAT (512 * 1024)   // elements per Bt matrix

__device__ __forceinline__ float b2f(u16 u) {
    return __uint_as_float(((u32)u) << 16);
}
__device__ __forceinline__ u16 f2b(float f) {
    u32 u = __float_as_uint(f);
    u32 r = (u + 0x7FFFu + ((u >> 16) & 1u)) >> 16;
    return (u16)r;
}

// -------- edge-index width detection: int64 (high words zero) vs int32 ------------------
__global__ void detect_kernel(const u32* __restrict__ ei, int* __restrict__ flags) {
    if (threadIdx.x == 0) {
        int allzero = 1;
        for (int i = 0; i < 64; ++i)
            if (ei[2 * i + 1] != 0u) allzero = 0;
        flags[0] = allzero;  // 1 => int64 layout
    }
}

__global__ void edges_kernel(const u32* __restrict__ ei, const int* __restrict__ flags,
                             int* __restrict__ s32, int* __restrict__ d32) {
    int t = blockIdx.x * 256 + threadIdx.x;
    u32 s, d;
    if (flags[0]) {  // int64
        s = ei[2 * t];
        d = ei[2 * EE + 2 * t];
    } else {         // int32
        s = ei[t];
        d = ei[EE + t];
    }
    s32[t] = (int)(s & (NN - 1));
    d32[t] = (int)(d & (NN - 1));
}

// -------- fp32 x -> bf16 xb (kept for tiers without fused gate path) ---------------------
__global__ void convert_kernel(const float* __restrict__ x, u16* __restrict__ xb) {
    int t = blockIdx.x * 256 + threadIdx.x;
    f32x4 a = ((const f32x4*)x)[t * 2];
    f32x4 b = ((const f32x4*)x)[t * 2 + 1];
    u16x8 o;
    o[0] = f2b(a[0]); o[1] = f2b(a[1]); o[2] = f2b(a[2]); o[3] = f2b(a[3]);
    o[4] = f2b(b[0]); o[5] = f2b(b[1]); o[6] = f2b(b[2]); o[7] = f2b(b[3]);
    ((u16x8*)xb)[t] = o;
}

// -------- weight transpose+cvt: W[e][l][k][n] fp32 -> Bt[e*2+l][n][k 0..1023] bf16 -------
__global__ void transpose_kernel(const float* __restrict__ Wl, const float* __restrict__ Wr,
                                 u16* __restrict__ Bt) {
    int bid = blockIdx.x;
    int matid = bid >> 8;
    int tile = bid & 255;
    int em = matid >> 1;
    int half = matid & 1;
    const float* W = (half ? Wr : Wl) + (size_t)em * DD * DD;
    u16* out = Bt + (size_t)em * DD * 1024 + half * DD;
    int tk = (tile >> 4) * 32, tn = (tile & 15) * 32;
    __shared__ float s[32][33];
    int t = threadIdx.x;
    int rr = t >> 5, cc = t & 31;
#pragma unroll
    for (int p = 0; p < 4; ++p) {
        int kr = p * 8 + rr;
        s[kr][cc] = W[(size_t)(tk + kr) * DD + tn + cc];
    }
    __syncthreads();
#pragma unroll
    for (int p = 0; p < 4; ++p) {
        int nr = p * 8 + rr;
        out[(size_t)(tn + nr) * 1024 + tk + cc] = f2b(s[cc][nr]);
    }
}

// -------- gating (standalone, tiers without xb) ------------------------------------------
__global__ void gate_kernel(const float* __restrict__ x, const float* __restrict__ gw,
                            const float* __restrict__ gb, float* __restrict__ wg) {
    int node = blockIdx.x * 4 + (threadIdx.x >> 6);
    int l = threadIdx.x & 63;
    const f32x4* xr = (const f32x4*)(x + (size_t)node * DD) + l * 2;
    f32x4 x0 = xr[0], x1 = xr[1];
    float a0 = 0.f, a1 = 0.f, a2 = 0.f, a3 = 0.f;
#pragma unroll
    for (int j = 0; j < 8; ++j) {
        float xf = (j < 4) ? x0[j & 3] : x1[j & 3];
        f32x4 wr = ((const f32x4*)gw)[l * 8 + j];
        a0 += xf * wr[0]; a1 += xf * wr[1]; a2 += xf * wr[2]; a3 += xf * wr[3];
    }
#pragma unroll
    for (int off = 32; off > 0; off >>= 1) {
        a0 += __shfl_down(a0, off, 64);
        a1 += __shfl_down(a1, off, 64);
        a2 += __shfl_down(a2, off, 64);
        a3 += __shfl_down(a3, off, 64);
    }
    if (l == 0) {
        float lg[4] = {a0 + gb[0], a1 + gb[1], a2 + gb[2], a3 + gb[3]};
        float m = fmaxf(fmaxf(lg[0], lg[1]), fmaxf(lg[2], lg[3]));
        float p[4]; float s = 0.f;
#pragma unroll
        for (int e = 0; e < 4; ++e) { p[e] = expf(lg[e] - m); s += p[e]; }
        float inv = 1.f / s;
#pragma unroll
        for (int e = 0; e < 4; ++e) p[e] *= inv;
        int i0 = 0;
#pragma unroll
        for (int e = 1; e < 4; ++e) if (p[e] > p[i0]) i0 = e;
        int i1 = -1;
#pragma unroll
        for (int e = 0; e < 4; ++e) if (e != i0 && (i1 < 0 || p[e] > p[i1])) i1 = e;
        float o[4] = {0.f, 0.f, 0.f, 0.f};
        o[i0] = p[i0]; o[i1] = p[i1];
        float* w = wg + (size_t)node * 4;
        w[0] = o[0]; w[1] = o[1]; w[2] = o[2]; w[3] = o[3];
    }
}

// -------- fused gating + fp32->bf16 convert: one pass over x -----------------------------
__global__ void gateconv_kernel(const float* __restrict__ x, const float* __restrict__ gw,
                                const float* __restrict__ gb, float* __restrict__ wg,
                                u16* __restrict__ xb) {
    int node = blockIdx.x * 4 + (threadIdx.x >> 6);
    int l = threadIdx.x & 63;
    const f32x4* xr = (const f32x4*)(x + (size_t)node * DD) + l * 2;
    f32x4 x0 = xr[0], x1 = xr[1];
    u16x8 o8;
    o8[0] = f2b(x0[0]); o8[1] = f2b(x0[1]); o8[2] = f2b(x0[2]); o8[3] = f2b(x0[3]);
    o8[4] = f2b(x1[0]); o8[5] = f2b(x1[1]); o8[6] = f2b(x1[2]); o8[7] = f2b(x1[3]);
    *((u16x8*)(xb + (size_t)node * DD) + l) = o8;
    float a0 = 0.f, a1 = 0.f, a2 = 0.f, a3 = 0.f;
#pragma unroll
    for (int j = 0; j < 8; ++j) {
        float xf = (j < 4) ? x0[j & 3] : x1[j & 3];
        f32x4 wr = ((const f32x4*)gw)[l * 8 + j];
        a0 += xf * wr[0]; a1 += xf * wr[1]; a2 += xf * wr[2]; a3 += xf * wr[3];
    }
#pragma unroll
    for (int off = 32; off > 0; off >>= 1) {
        a0 += __shfl_down(a0, off, 64);
        a1 += __shfl_down(a1, off, 64);
        a2 += __shfl_down(a2, off, 64);
        a3 += __shfl_down(a3, off, 64);
    }
    if (l == 0) {
        float lg[4] = {a0 + gb[0], a1 + gb[1], a2 + gb[2], a3 + gb[3]};
        float m = fmaxf(fmaxf(lg[0], lg[1]), fmaxf(lg[2], lg[3]));
        float p[4]; float s = 0.f;
#pragma unroll
        for (int e = 0; e < 4; ++e) { p[e] = expf(lg[e] - m); s += p[e]; }
        float inv = 1.f / s;
#pragma unroll
        for (int e = 0; e < 4; ++e) p[e] *= inv;
        int i0 = 0;
#pragma unroll
        for (int e = 1; e < 4; ++e) if (p[e] > p[i0]) i0 = e;
        int i1 = -1;
#pragma unroll
        for (int e = 0; e < 4; ++e) if (e != i0 && (i1 < 0 || p[e] > p[i1])) i1 = e;
        float o[4] = {0.f, 0.f, 0.f, 0.f};
        o[i0] = p[i0]; o[i1] = p[i1];
        float* w = wg + (size_t)node * 4;
        w[0] = o[0]; w[1] = o[1]; w[2] = o[2]; w[3] = o[3];
    }
}

// -------- expert compaction: per-expert active-node lists (order-free) -------------------
__global__ void compact_kernel(const float* __restrict__ wg, int* __restrict__ cnt,
                               int* __restrict__ list) {
    int node = blockIdx.x * 256 + threadIdx.x;
    const float* w = wg + (size_t)node * 4;
#pragma unroll
    for (int e = 0; e < 4; ++e)
        if (w[e] > 0.f) {
            int p = atomicAdd(&cnt[e], 1);
            list[e * NN + p] = node;
        }
}

// tile map: sequence of (expert, m-tile-within-expert) for compacted L1 GEMM.
// total rows = 2*NN (top-2) -> <= 512+4 tiles. Single-thread scalar loop (~2 us).
__global__ void tilemap_kernel(const int* __restrict__ cnt, int* __restrict__ tmap,
                               int* __restrict__ tcount) {
    if (threadIdx.x == 0) {
        int T = 0;
        for (int e = 0; e < 4; ++e) {
            int nt = (cnt[e] + 127) >> 7;
            for (int i = 0; i < nt; ++i) tmap[T++] = (e << 16) | i;
        }
        *tcount = T;
    }
}

// -------- CSR build ----------------------------------------------------------------------
__global__ void deg_kernel(const int* __restrict__ dst, int* __restrict__ deg) {
    int t = blockIdx.x * blockDim.x + threadIdx.x;
    if (t < EE) atomicAdd(&deg[dst[t]], 1);
}

__global__ void scan1_kernel(const int* __restrict__ deg, int* __restrict__ start,
                             float* __restrict__ invd, int* __restrict__ bsum) {
    int t = threadIdx.x;
    int idx = blockIdx.x * 1024 + t;
    int v = deg[idx];
    int sc = v;
#pragma unroll
    for (int off = 1; off < 64; off <<= 1) {
        int u = __shfl_up(sc, off, 64);
        if ((t & 63) >= off) sc += u;
    }
    __shared__ int wsum[16], woff[16];
    if ((t & 63) == 63) wsum[t >> 6] = sc;
    __syncthreads();
    if (t == 0) {
        int acc = 0;
        for (int w = 0; w < 16; ++w) { woff[w] = acc; acc += wsum[w]; }
        bsum[blockIdx.x] = acc;
    }
    __syncthreads();
    start[idx] = woff[t >> 6] + sc - v;
    invd[idx] = v > 0 ? 1.0f / (float)v : 0.0f;
}

__global__ void scan2_kernel(int* __restrict__ bsum, int* __restrict__ boff) {
    if (threadIdx.x == 0) {
        int acc = 0;
        for (int b = 0; b < 32; ++b) { boff[b] = acc; acc += bsum[b]; }
    }
}

__global__ void scan3_kernel(int* __restrict__ start, int* __restrict__ cursor,
                             const int* __restrict__ boff) {
    int idx = blockIdx.x * 256 + threadIdx.x;
    int s = start[idx] + boff[idx >> 10];
    start[idx] = s;
    cursor[idx] = s;
}

__global__ void scatter_kernel(const int* __restrict__ src, const int* __restrict__ dst,
                               int* __restrict__ cursor, int* __restrict__ csr) {
    int t = blockIdx.x * blockDim.x + threadIdx.x;
    if (t < EE) {
        int d = dst[t];
        int pos = atomicAdd(&cursor[d], 1);
        csr[pos] = src[t];
    }
}

// -------- mean aggregation over CSR; multi-expert: grid = nExp*8192 blocks ---------------
template <bool F32IN>
__global__ void aggr_kernel(const void* __restrict__ hv, u16* __restrict__ outB,
                            const int* __restrict__ start, const int* __restrict__ deg,
                            const int* __restrict__ csr, const float* __restrict__ invd,
                            const float* __restrict__ wg, int eBase, size_t stride) {
    int eo = blockIdx.x >> 13;
    int node = ((blockIdx.x & 8191) << 2) + (threadIdx.x >> 6);
    int expert = eBase + eo;
    if (wg != nullptr && wg[(size_t)node * 4 + expert] == 0.f) return;
    int l = threadIdx.x & 63;
    int s0 = start[node];
    int dg = deg[node];
    u16* out = outB + (size_t)eo * stride;
    const u16* hB = (const u16*)hv + (size_t)eo * stride;
    const float* hF = (const float*)hv + (size_t)eo * stride;
    float a[8] = {0.f, 0.f, 0.f, 0.f, 0.f, 0.f, 0.f, 0.f};

    for (int base = 0; base < dg; base += 64) {
        int cnt = dg - base;
        if (cnt > 64) cnt = 64;
        int vidx = 0;
        if (l < cnt) vidx = csr[s0 + base + l];
        int q = 0;
        if (!F32IN) {
            for (; q + 8 <= cnt; q += 8) {
                int j0 = __shfl(vidx, q, 64);
                int j1 = __shfl(vidx, q + 1, 64);
                int j2 = __shfl(vidx, q + 2, 64);
                int j3 = __shfl(vidx, q + 3, 64);
                int j4 = __shfl(vidx, q + 4, 64);
                int j5 = __shfl(vidx, q + 5, 64);
                int j6 = __shfl(vidx, q + 6, 64);
                int j7 = __shfl(vidx, q + 7, 64);
                u16x8 v0 = *((const u16x8*)(hB + (size_t)j0 * DD) + l);
                u16x8 v1 = *((const u16x8*)(hB + (size_t)j1 * DD) + l);
                u16x8 v2 = *((const u16x8*)(hB + (size_t)j2 * DD) + l);
                u16x8 v3 = *((const u16x8*)(hB + (size_t)j3 * DD) + l);
                u16x8 v4 = *((const u16x8*)(hB + (size_t)j4 * DD) + l);
                u16x8 v5 = *((const u16x8*)(hB + (size_t)j5 * DD) + l);
                u16x8 v6 = *((const u16x8*)(hB + (size_t)j6 * DD) + l);
                u16x8 v7 = *((const u16x8*)(hB + (size_t)j7 * DD) + l);
#pragma unroll
                for (int q2 = 0; q2 < 8; ++q2)
                    a[q2] += ((b2f(v0[q2]) + b2f(v1[q2])) + (b2f(v2[q2]) + b2f(v3[q2]))) +
                             ((b2f(v4[q2]) + b2f(v5[q2])) + (b2f(v6[q2]) + b2f(v7[q2])));
            }
        }
        for (; q + 4 <= cnt; q += 4) {
            int j0 = __shfl(vidx, q, 64);
            int j1 = __shfl(vidx, q + 1, 64);
            int j2 = __shfl(vidx, q + 2, 64);
            int j3 = __shfl(vidx, q + 3, 64);
            if (F32IN) {
                const f32x4* r0 = (const f32x4*)(hF + (size_t)j0 * DD) + l * 2;
                const f32x4* r1 = (const f32x4*)(hF + (size_t)j1 * DD) + l * 2;
                const f32x4* r2 = (const f32x4*)(hF + (size_t)j2 * DD) + l * 2;
                const f32x4* r3 = (const f32x4*)(hF + (size_t)j3 * DD) + l * 2;
                f32x4 u0 = r0[0], u1 = r0[1];
                f32x4 u2 = r1[0], u3 = r1[1];
                f32x4 u4 = r2[0], u5 = r2[1];
                f32x4 u6 = r3[0], u7 = r3[1];
#pragma unroll
                for (int q2 = 0; q2 < 4; ++q2) {
                    a[q2] += (u0[q2] + u2[q2]) + (u4[q2] + u6[q2]);
                    a[4 + q2] += (u1[q2] + u3[q2]) + (u5[q2] + u7[q2]);
                }
            } else {
                u16x8 v0 = *((const u16x8*)(hB + (size_t)j0 * DD) + l);
                u16x8 v1 = *((const u16x8*)(hB + (size_t)j1 * DD) + l);
                u16x8 v2 = *((const u16x8*)(hB + (size_t)j2 * DD) + l);
                u16x8 v3 = *((const u16x8*)(hB + (size_t)j3 * DD) + l);
#pragma unroll
                for (int q2 = 0; q2 < 8; ++q2)
                    a[q2] += (b2f(v0[q2]) + b2f(v1[q2])) + (b2f(v2[q2]) + b2f(v3[q2]));
            }
        }
        for (; q < cnt; ++q) {
            int j = __shfl(vidx, q, 64);
            if (F32IN) {
                const f32x4* r = (const f32x4*)(hF + (size_t)j * DD) + l * 2;
                f32x4 u0 = r[0], u1 = r[1];
#pragma unroll
                for (int q2 = 0; q2 < 4; ++q2) { a[q2] += u0[q2]; a[4 + q2] += u1[q2]; }
            } else {
                u16x8 v = *((const u16x8*)(hB + (size_t)j * DD) + l);
#pragma unroll
                for (int q2 = 0; q2 < 8; ++q2) a[q2] += b2f(v[q2]);
            }
        }
    }
    float sc = invd[node];
    u16x8 o;
#pragma unroll
    for (int q2 = 0; q2 < 8; ++q2) o[q2] = f2b(a[q2] * sc);
    *((u16x8*)(out + (size_t)node * DD) + l) = o;
}

// -------- dual-expert gated aggregation (top-2): one wave = one node, both active experts.
__global__ void aggr2_kernel(const u16* __restrict__ h, u16* __restrict__ outB,
                             const int* __restrict__ start, const int* __restrict__ deg,
                             const int* __restrict__ csr, const float* __restrict__ invd,
                             const float* __restrict__ wg) {
    const int node = (blockIdx.x << 2) + (threadIdx.x >> 6);
    const int l = threadIdx.x & 63;
    const float* w = wg + (size_t)node * 4;
    int e0 = -1, e1 = -1;
#pragma unroll
    for (int e = 0; e < 4; ++e) {
        if (w[e] > 0.f) { if (e0 < 0) e0 = e; else e1 = e; }
    }
    if (e0 < 0) return;
    const int dual = (e1 >= 0);
    if (!dual) e1 = e0;
    const size_t STRE = (size_t)NN * DD;
    const u16* hA = h + (size_t)e0 * STRE;
    const u16* hC = h + (size_t)e1 * STRE;
    const int s0 = start[node];
    const int dg = deg[node];
    float a0[8] = {0.f, 0.f, 0.f, 0.f, 0.f, 0.f, 0.f, 0.f};
    float a1[8] = {0.f, 0.f, 0.f, 0.f, 0.f, 0.f, 0.f, 0.f};

    for (int base = 0; base < dg; base += 64) {
        int cnt = dg - base;
        if (cnt > 64) cnt = 64;
        int vidx = 0;
        if (l < cnt) vidx = csr[s0 + base + l];
        int q = 0;
        for (; q + 4 <= cnt; q += 4) {
            int j0 = __shfl(vidx, q, 64);
            int j1 = __shfl(vidx, q + 1, 64);
            int j2 = __shfl(vidx, q + 2, 64);
            int j3 = __shfl(vidx, q + 3, 64);
            u16x8 u0 = *((const u16x8*)(hA + (size_t)j0 * DD) + l);
            u16x8 u1 = *((const u16x8*)(hA + (size_t)j1 * DD) + l);
            u16x8 u2 = *((const u16x8*)(hA + (size_t)j2 * DD) + l);
            u16x8 u3 = *((const u16x8*)(hA + (size_t)j3 * DD) + l);
            u16x8 t0 = *((const u16x8*)(hC + (size_t)j0 * DD) + l);
            u16x8 t1 = *((const u16x8*)(hC + (size_t)j1 * DD) + l);
            u16x8 t2 = *((const u16x8*)(hC + (size_t)j2 * DD) + l);
            u16x8 t3 = *((const u16x8*)(hC + (size_t)j3 * DD) + l);
#pragma unroll
            for (int q2 = 0; q2 < 8; ++q2) {
                a0[q2] += (b2f(u0[q2]) + b2f(u1[q2])) + (b2f(u2[q2]) + b2f(u3[q2]));
                a1[q2] += (b2f(t0[q2]) + b2f(t1[q2])) + (b2f(t2[q2]) + b2f(t3[q2]));
            }
        }
        for (; q < cnt; ++q) {
            int j = __shfl(vidx, q, 64);
            u16x8 u = *((const u16x8*)(hA + (size_t)j * DD) + l);
            u16x8 t = *((const u16x8*)(hC + (size_t)j * DD) + l);
#pragma unroll
            for (int q2 = 0; q2 < 8; ++q2) { a0[q2] += b2f(u[q2]); a1[q2] += b2f(t[q2]); }
        }
    }
    float sc = invd[node];
    u16x8 o0, o1;
#pragma unroll
    for (int q2 = 0; q2 < 8; ++q2) { o0[q2] = f2b(a0[q2] * sc); o1[q2] = f2b(a1[q2] * sc); }
    *((u16x8*)(outB + (size_t)e0 * STRE + (size_t)node * DD) + l) = o0;
    if (dual)
        *((u16x8*)(outB + (size_t)e1 * STRE + (size_t)node * DD) + l) = o1;
}

__device__ __forceinline__ void gload16(const void* g, void* l) {
    __builtin_amdgcn_global_load_lds((const __attribute__((address_space(1))) void*)g,
                                     (__attribute__((address_space(3))) void*)l, 16, 0, 0);
}

// -------- legacy fused GEMM (fallback tiers): A and B both staged through LDS ------------
template <bool A2F32>
__global__ void __launch_bounds__(256, 4) gemm_kernel(
    const u16* __restrict__ A1, const u16* __restrict__ A2b, const float* __restrict__ A2f,
    size_t sA, const u16* __restrict__ Bt, size_t sBt,
    const float* __restrict__ bias, size_t sBias,
    u16* __restrict__ Hout, size_t sH, float* __restrict__ Out,
    const float* __restrict__ wg, int mode, int eBase, int ntt) {
    __shared__ u16 lds[A2F32 ? 12288 : 8192];
    u16* ldsA = lds;
    float* ldsF = (float*)lds;
    u16* ldsB = lds + (A2F32 ? 8192 : 4096);
    const int tid = threadIdx.x;
    const int lane = tid & 63;
    const int w = tid >> 6;

    const int bid = blockIdx.x;
    const int xcd = bid & 7;
    const int local = bid >> 3;
    const int mtl = local / ntt;
    const int sub = local - mtl * ntt;
    const int expert = sub >> 2;
    const int wgE = eBase + expert;
    const int m0 = (xcd * 32 + mtl) * 128;
    const int n0 = (sub & 3) * 128;

    const u16* A1p = A1 + (size_t)expert * sA;
    const u16* A2p = A2b + (size_t)expert * sA;
    const u16* Btp = Bt + (size_t)expert * sBt;
    const float* biasp = bias + (size_t)expert * sBias;
    u16* Houtp = Hout + (size_t)expert * sH;

    const int wm = (w >> 1) * 64;
    const int wn = (w & 1) * 64;

    f32x4 acc[4][4];
#pragma unroll
    for (int i = 0; i < 4; ++i)
#pragma unroll
        for (int j = 0; j < 4; ++j) acc[i][j] = (f32x4){0.f, 0.f, 0.f, 0.f};

    const int p0 = tid, p1 = 256 + tid;
    const int r0 = p0 >> 2, c0 = ((p0 & 3) - (r0 >> 1)) & 3;
    const int r1 = p1 >> 2, c1 = ((p1 & 3) - (r1 >> 1)) & 3;
    const int arow = lane & 15;
    const int kc = lane >> 4;

    for (int kb = 0; kb < 32; ++kb) {
        __syncthreads();
        if (!A2F32 || kb < 16) {
            const u16* As = (kb < 16) ? A1p : A2p;
            const int kcol = (kb & 15) * 32;
            gload16(As + (size_t)(m0 + r0) * DD + kcol + c0 * 8, ldsA + p0 * 8);
            gload16(As + (size_t)(m0 + r1) * DD + kcol + c1 * 8, ldsA + p1 * 8);
        } else {
            const float* Af = A2f + (size_t)m0 * DD + (kb - 16) * 32;
#pragma unroll
            for (int q = 0; q < 4; ++q) {
                int p = q * 256 + tid;
                int rr = p >> 3, cpos = p & 7, cc2 = (cpos - rr) & 7;
                gload16(Af + (size_t)rr * DD + cc2 * 4, ldsF + p * 4);
            }
        }
        gload16(Btp + (size_t)(n0 + r0) * 1024 + kb * 32 + c0 * 8, ldsB + p0 * 8);
        gload16(Btp + (size_t)(n0 + r1) * 1024 + kb * 32 + c1 * 8, ldsB + p1 * 8);
        __syncthreads();
        s16x8 af[4], bf[4];
        if (!A2F32 || kb < 16) {
#pragma unroll
            for (int f = 0; f < 4; ++f) {
                int ra = wm + f * 16 + arow;
                int pa = (kc + (ra >> 1)) & 3;
                af[f] = *(const s16x8*)(ldsA + (ra * 4 + pa) * 8);
            }
        } else {
#pragma unroll
            for (int f = 0; f < 4; ++f) {
                int ra = wm + f * 16 + arow;
                int plo = ra * 8 + ((2 * kc + ra) & 7);
                int phi = ra * 8 + ((2 * kc + 1 + ra) & 7);
                f32x4 lo = *(const f32x4*)(ldsF + plo * 4);
                f32x4 hi = *(const f32x4*)(ldsF + phi * 4);
                s16x8 t;
                t[0] = (short)f2b(lo[0]); t[1] = (short)f2b(lo[1]);
                t[2] = (short)f2b(lo[2]); t[3] = (short)f2b(lo[3]);
                t[4] = (short)f2b(hi[0]); t[5] = (short)f2b(hi[1]);
                t[6] = (short)f2b(hi[2]); t[7] = (short)f2b(hi[3]);
                af[f] = t;
            }
        }
#pragma unroll
        for (int f = 0; f < 4; ++f) {
            int rb = wn + f * 16 + arow;
            int pb = (kc + (rb >> 1)) & 3;
            bf[f] = *(const s16x8*)(ldsB + (rb * 4 + pb) * 8);
        }
#pragma unroll
        for (int i = 0; i < 4; ++i)
#pragma unroll
            for (int j = 0; j < 4; ++j)
                acc[i][j] = __builtin_amdgcn_mfma_f32_16x16x32_bf16(af[i], bf[j], acc[i][j], 0, 0, 0);
    }

    const int colq = lane & 15;
    const int rq = lane >> 4;
#pragma unroll
    for (int i = 0; i < 4; ++i) {
#pragma unroll
        for (int j = 0; j < 4; ++j) {
            int col = n0 + wn + j * 16 + colq;
            float bv = biasp[col];
#pragma unroll
            for (int r = 0; r < 4; ++r) {
                int row = m0 + wm + i * 16 + rq * 4 + r;
                float v = fmaxf(acc[i][j][r] + bv, 0.f);
                size_t idx = (size_t)row * DD + col;
                if (mode == 0) {
                    Houtp[idx] = f2b(v);
                } else {
                    float wv = wg[(size_t)row * 4 + wgE];
                    if (mode == 1) {
                        Out[idx] = wv * v;
                    } else if (mode == 2) {
                        if (wv > 0.f) Out[idx] += wv * v;
                    } else {
                        if (wv > 0.f) unsafeAtomicAdd(&Out[idx], wv * v);
                    }
                }
            }
        }
    }
}

// -------- L0 GEMM, B direct-from-global: h1[e] = relu([aggr0|xb] @ Bt_e^T + b_e) ---------
// LDS holds only the A-panel (8 KB/K-step); B-fragments are vector-loaded straight to
// registers (B is L2-resident, 1 MB/expert). Halves LDS traffic per K-step (48->24 KB),
// which round-3 counters identified as the binding wall (MfmaUtil 31.8% at 0 conflicts,
// HBM 19%). The __syncthreads() vmcnt-drain synchronizes the B loads for free.
__global__ void __launch_bounds__(256, 4) gemm_bd_kernel(
    const u16* __restrict__ A1, const u16* __restrict__ A2,
    const u16* __restrict__ Bt, const float* __restrict__ bias,
    u16* __restrict__ Hout) {
    __shared__ u16 lds[4096];  // A only: 128 rows x 32 k
    const int tid = threadIdx.x;
    const int lane = tid & 63;
    const int w = tid >> 6;

    const int bid = blockIdx.x;
    const int xcd = bid & 7;
    const int local = bid >> 3;
    const int mtl = local >> 4;
    const int sub = local & 15;
    const int expert = sub >> 2;
    const int m0 = (xcd * 32 + mtl) * 128;
    const int n0 = (sub & 3) * 128;

    const u16* Btp = Bt + (size_t)expert * (2 * WMAT);
    const float* biasp = bias + (size_t)expert * 1024;
    u16* Houtp = Hout + (size_t)expert * ((size_t)NN * DD);

    const int wm = (w >> 1) * 64;
    const int wn = (w & 1) * 64;

    f32x4 acc[4][4];
#pragma unroll
    for (int i = 0; i < 4; ++i)
#pragma unroll
        for (int j = 0; j < 4; ++j) acc[i][j] = (f32x4){0.f, 0.f, 0.f, 0.f};

    const int p0 = tid, p1 = 256 + tid;
    const int r0 = p0 >> 2, c0 = ((p0 & 3) - (r0 >> 1)) & 3;
    const int r1 = p1 >> 2, c1 = ((p1 & 3) - (r1 >> 1)) & 3;
    const int arow = lane & 15;
    const int kc = lane >> 4;

    for (int kb = 0; kb < 32; ++kb) {
        __syncthreads();
        const u16* As = (kb < 16) ? A1 : A2;
        const int kcol = (kb & 15) * 32;
        gload16(As + (size_t)(m0 + r0) * DD + kcol + c0 * 8, lds + p0 * 8);
        gload16(As + (size_t)(m0 + r1) * DD + kcol + c1 * 8, lds + p1 * 8);
        s16x8 bf[4];
#pragma unroll
        for (int f = 0; f < 4; ++f) {
            int rb = n0 + wn + f * 16 + arow;
            bf[f] = *(const s16x8*)(Btp + (size_t)rb * 1024 + kb * 32 + kc * 8);
        }
        __syncthreads();
        s16x8 af[4];
#pragma unroll
        for (int f = 0; f < 4; ++f) {
            int ra = wm + f * 16 + arow;
            int pa = (kc + (ra >> 1)) & 3;
            af[f] = *(const s16x8*)(lds + (ra * 4 + pa) * 8);
        }
#pragma unroll
        for (int i = 0; i < 4; ++i)
#pragma unroll
            for (int j = 0; j < 4; ++j)
                acc[i][j] = __builtin_amdgcn_mfma_f32_16x16x32_bf16(af[i], bf[j], acc[i][j], 0, 0, 0);
    }

    const int colq = lane & 15;
    const int rq = lane >> 4;
#pragma unroll
    for (int i = 0; i < 4; ++i) {
#pragma unroll
        for (int j = 0; j < 4; ++j) {
            int col = n0 + wn + j * 16 + colq;
            float bv = biasp[col];
#pragma unroll
            for (int r = 0; r < 4; ++r) {
                int row = m0 + wm + i * 16 + rq * 4 + r;
                float v = fmaxf(acc[i][j][r] + bv, 0.f);
                Houtp[(size_t)row * DD + col] = f2b(v);
            }
        }
    }
}

// -------- L1 GEMM over compacted rows: out[node] += wv * relu([aggr1|h1]@Bt^T + b) -------
// Row set = exactly the (node,expert) pairs with wv>0 (top-2 => 2*NN rows, half the dense
// work). Tile t (from tmap) covers rows [mt*128, mt*128+128) of expert e's list; padding
// rows are clamped (duplicate compute) and masked at the write. A-row gathers cost the
// same as dense staging (rows are 1 KB apart either way).
__global__ void __launch_bounds__(256, 4) gemm_gather_kernel(
    const u16* __restrict__ A1, const u16* __restrict__ A2,
    const u16* __restrict__ Bt, const float* __restrict__ bias,
    float* __restrict__ Out, const float* __restrict__ wg,
    const int* __restrict__ list, const int* __restrict__ cnt,
    const int* __restrict__ tmap, const int* __restrict__ tcount) {
    const int t = blockIdx.x >> 2;
    if (t >= *tcount) return;
    const u32 mi = (u32)tmap[t];
    const int e = mi >> 16;
    const int mt = mi & 0xffff;
    const int cntE = cnt[e];
    const int base = mt << 7;
    const int n0 = (blockIdx.x & 3) * 128;

    __shared__ u16 lds[8192];
    u16* ldsA = lds;
    u16* ldsB = lds + 4096;
    const int tid = threadIdx.x;
    const int lane = tid & 63;
    const int w = tid >> 6;

    const size_t STRE = (size_t)NN * DD;
    const u16* A1p = A1 + (size_t)e * STRE;
    const u16* A2p = A2 + (size_t)e * STRE;
    const u16* Btp = Bt + (size_t)e * (2 * WMAT);
    const float* biasp = bias + (size_t)e * 1024;
    const int* listE = list + e * NN;

    const int wm = (w >> 1) * 64;
    const int wn = (w & 1) * 64;

    f32x4 acc[4][4];
#pragma unroll
    for (int i = 0; i < 4; ++i)
#pragma unroll
        for (int j = 0; j < 4; ++j) acc[i][j] = (f32x4){0.f, 0.f, 0.f, 0.f};

    const int p0 = tid, p1 = 256 + tid;
    const int r0 = p0 >> 2, c0 = ((p0 & 3) - (r0 >> 1)) & 3;
    const int r1 = p1 >> 2, c1 = ((p1 & 3) - (r1 >> 1)) & 3;
    int q0 = base + r0; if (q0 >= cntE) q0 = cntE - 1;
    int q1 = base + r1; if (q1 >= cntE) q1 = cntE - 1;
    const int gr0 = listE[q0];
    const int gr1 = listE[q1];
    const int arow = lane & 15;
    const int kc = lane >> 4;

    for (int kb = 0; kb < 32; ++kb) {
        __syncthreads();
        const u16* As = (kb < 16) ? A1p : A2p;
        const int kcol = (kb & 15) * 32;
        gload16(As + (size_t)gr0 * DD + kcol + c0 * 8, ldsA + p0 * 8);
        gload16(As + (size_t)gr1 * DD + kcol + c1 * 8, ldsA + p1 * 8);
        gload16(Btp + (size_t)(n0 + r0) * 1024 + kb * 32 + c0 * 8, ldsB + p0 * 8);
        gload16(Btp + (size_t)(n0 + r1) * 1024 + kb * 32 + c1 * 8, ldsB + p1 * 8);
        __syncthreads();
        s16x8 af[4], bf[4];
#pragma unroll
        for (int f = 0; f < 4; ++f) {
            int ra = wm + f * 16 + arow;
            int pa = (kc + (ra >> 1)) & 3;
            af[f] = *(const s16x8*)(ldsA + (ra * 4 + pa) * 8);
        }
#pragma unroll
        for (int f = 0; f < 4; ++f) {
            int rb = wn + f * 16 + arow;
            int pb = (kc + (rb >> 1)) & 3;
            bf[f] = *(const s16x8*)(ldsB + (rb * 4 + pb) * 8);
        }
#pragma unroll
        for (int i = 0; i < 4; ++i)
#pragma unroll
            for (int j = 0; j < 4; ++j)
                acc[i][j] = __builtin_amdgcn_mfma_f32_16x16x32_bf16(af[i], bf[j], acc[i][j], 0, 0, 0);
    }

    const int colq = lane & 15;
    const int rq = lane >> 4;
#pragma unroll
    for (int i = 0; i < 4; ++i) {
        int nd[4]; float wv4[4]; bool val[4];
#pragma unroll
        for (int r = 0; r < 4; ++r) {
            int rowl = base + wm + i * 16 + rq * 4 + r;
            val[r] = rowl < cntE;
            int qq = val[r] ? rowl : 0;
            nd[r] = listE[qq];
            wv4[r] = wg[(size_t)nd[r] * 4 + e];
        }
#pragma unroll
        for (int j = 0; j < 4; ++j) {
            int col = n0 + wn + j * 16 + colq;
            float bv = biasp[col];
#pragma unroll
            for (int r = 0; r < 4; ++r) {
                if (val[r]) {
                    float v = fmaxf(acc[i][j][r] + bv, 0.f);
                    unsafeAtomicAdd(&Out[(size_t)nd[r] * DD + col], wv4[r] * v);
                }
            }
        }
    }
}

extern "C" void kernel_launch(void* const* d_in, const int* in_sizes, int n_in,
                              void* d_out, int out_size, void* d_ws, size_t ws_size,
                              hipStream_t stream) {
    const float* x  = (const float*)d_in[0];
    const float* gW = (const float*)d_in[1];
    const float* gb = (const float*)d_in[2];
    const float* Wl = (const float*)d_in[3];
    const float* bl = (const float*)d_in[4];
    const float* Wr = (const float*)d_in[5];
    const u32*   ei = (const u32*)d_in[6];
    float* outp = (float*)d_out;

    char* ws = (char*)d_ws;
    size_t off = 0;
    auto alloc = [&](size_t bytes) -> void* {
        void* p = ws + off;
        off += (bytes + 255) & ~(size_t)255;
        return p;
    };
    const size_t MB32 = (size_t)NN * DD * 2;
    const size_t STR = (size_t)NN * DD;      // per-expert element stride
    int*   flags  = (int*)alloc(512);
    float* wg     = (float*)alloc((size_t)NN * 4 * 4);
    int*   deg    = (int*)alloc((size_t)NN * 4);
    int*   start  = (int*)alloc((size_t)NN * 4);
    int*   cursor = (int*)alloc((size_t)NN * 4);
    float* invd   = (float*)alloc((size_t)NN * 4);
    int*   src32  = (int*)alloc((size_t)EE * 4);
    int*   dst32  = (int*)alloc((size_t)EE * 4);
    int*   csr    = (int*)alloc((size_t)EE * 4);
    u16*   Bt     = (u16*)alloc((size_t)8 * WMAT * 2);       // 8 MB
    int*   cnt    = (int*)alloc(64);                          // cnt[0..3], tcount at [8]
    int*   tmap   = (int*)alloc(1040 * 4);
    int*   list   = (int*)alloc((size_t)4 * NN * 4);          // 512 KB

    size_t rem = (ws_size > off) ? ws_size - off : 0;
    int tier;
    if      (rem >= 9 * MB32 + 65536) tier = 0;
    else if (rem >= 7 * MB32 + 65536) tier = 1;
    else if (rem >= 6 * MB32 + 65536) tier = 2;
    else if (rem >= 5 * MB32 + 65536) tier = 3;
    else if (rem >= 4 * MB32 + 65536) tier = 4;
    else                              tier = 5;

    u16 *xb = nullptr, *h1 = nullptr, *aggr1 = nullptr, *aggr0 = nullptr;
    if (tier <= 2) {
        xb = (u16*)alloc(MB32);
        h1 = (u16*)alloc(4 * MB32);
        aggr1 = (u16*)alloc((tier == 0 ? 4 : tier == 1 ? 2 : 1) * MB32);
        aggr0 = aggr1;                      // aggr0 dead after fused L0; aliases aggr1[0]
    } else if (tier == 3) {
        aggr0 = (u16*)alloc(MB32);
        h1 = (u16*)alloc(4 * MB32);
        aggr1 = aggr0;
    } else if (tier == 4) {
        aggr0 = (u16*)alloc(MB32);
        xb = (u16*)alloc(MB32);
        h1 = (u16*)alloc(MB32);
        aggr1 = (u16*)alloc(MB32);
    } else {
        aggr0 = (u16*)alloc(MB32);
        h1 = (u16*)alloc(MB32);
        aggr1 = (u16*)alloc(MB32);
    }

    int* bsum = flags + 16;
    int* boff = flags + 64;

    hipMemsetAsync(deg, 0, (size_t)NN * 4, stream);
    if (tier == 0) hipMemsetAsync(cnt, 0, 64, stream);

    detect_kernel<<<1, 64, 0, stream>>>(ei, flags);
    edges_kernel<<<EE / 256, 256, 0, stream>>>(ei, flags, src32, dst32);
    transpose_kernel<<<16 * 256, 256, 0, stream>>>(Wl, Wr, Bt);
    if (xb != nullptr)
        gateconv_kernel<<<NN / 4, 256, 0, stream>>>(x, gW, gb, wg, xb);
    else
        gate_kernel<<<NN / 4, 256, 0, stream>>>(x, gW, gb, wg);
    if (tier == 0) {
        compact_kernel<<<NN / 256, 256, 0, stream>>>(wg, cnt, list);
        tilemap_kernel<<<1, 64, 0, stream>>>(cnt, tmap, cnt + 8);
    }
    deg_kernel<<<EE / 256, 256, 0, stream>>>(dst32, deg);
    scan1_kernel<<<32, 1024, 0, stream>>>(deg, start, invd, bsum);
    scan2_kernel<<<1, 64, 0, stream>>>(bsum, boff);
    scan3_kernel<<<NN / 256, 256, 0, stream>>>(start, cursor, boff);
    scatter_kernel<<<EE / 256, 256, 0, stream>>>(src32, dst32, cursor, csr);

    if (tier == 0) {
        // -------- bf16 path: L0 = B-direct dense GEMM; L1 = compacted gather-GEMM --------
        aggr_kernel<false><<<8192, 256, 0, stream>>>(xb, aggr0, start, deg, csr, invd,
                                                     nullptr, 0, 0);
        gemm_bd_kernel<<<256 * 16, 256, 0, stream>>>(aggr0, xb, Bt, bl, h1);
        hipMemsetAsync(outp, 0, (size_t)NN * DD * 4, stream);
        aggr2_kernel<<<8192, 256, 0, stream>>>(h1, aggr1, start, deg, csr, invd, wg);
        gemm_gather_kernel<<<520 * 4, 256, 0, stream>>>(
            aggr1, h1, Bt + WMAT, bl + 512, outp, wg, list, cnt, tmap, cnt + 8);
    } else if (tier <= 2) {
        aggr_kernel<false><<<8192, 256, 0, stream>>>(xb, aggr0, start, deg, csr, invd,
                                                     nullptr, 0, 0);
        gemm_kernel<false><<<256 * 16, 256, 0, stream>>>(
            aggr0, xb, nullptr, 0, Bt, 2 * WMAT, bl, 1024,
            h1, STR, nullptr, wg, 0, 0, 16);
        if (tier == 1) {
            hipMemsetAsync(outp, 0, (size_t)NN * DD * 4, stream);
            for (int p = 0; p < 2; ++p) {
                aggr_kernel<false><<<2 * 8192, 256, 0, stream>>>(
                    h1 + (size_t)2 * p * STR, aggr1, start, deg, csr, invd, wg, 2 * p, STR);
                gemm_kernel<false><<<256 * 8, 256, 0, stream>>>(
                    aggr1, h1 + (size_t)2 * p * STR, nullptr, STR,
                    Bt + WMAT + (size_t)2 * p * 2 * WMAT, 2 * WMAT,
                    bl + 512 + 2 * p * 1024, 1024,
                    nullptr, 0, outp, wg, 3, 2 * p, 8);
            }
        } else {
            for (int e = 0; e < 4; ++e) {
                aggr_kernel<false><<<8192, 256, 0, stream>>>(
                    h1 + (size_t)e * STR, aggr1, start, deg, csr, invd, wg, e, 0);
                gemm_kernel<false><<<256 * 4, 256, 0, stream>>>(
                    aggr1, h1 + (size_t)e * STR, nullptr, 0,
                    Bt + (size_t)(e * 2 + 1) * WMAT, 0, bl + (e * 2 + 1) * 512, 0,
                    nullptr, 0, outp, wg, (e == 0) ? 1 : 2, e, 4);
            }
        }
    } else if (tier == 3) {
        aggr_kernel<true><<<8192, 256, 0, stream>>>(x, aggr0, start, deg, csr, invd,
                                                    nullptr, 0, 0);
        gemm_kernel<true><<<256 * 16, 256, 0, stream>>>(
            aggr0, nullptr, x, 0, Bt, 2 * WMAT, bl, 1024,
            h1, STR, nullptr, wg, 0, 0, 16);
        for (int e = 0; e < 4; ++e) {
            aggr_kernel<false><<<8192, 256, 0, stream>>>(
                h1 + (size_t)e * STR, aggr1, start, deg, csr, invd, wg, e, 0);
            gemm_kernel<false><<<256 * 4, 256, 0, stream>>>(
                aggr1, h1 + (size_t)e * STR, nullptr, 0,
                Bt + (size_t)(e * 2 + 1) * WMAT, 0, bl + (e * 2 + 1) * 512, 0,
                nullptr, 0, outp, wg, (e == 0) ? 1 : 2, e, 4);
        }
    } else {
        if (tier == 4) {
            aggr_kernel<false><<<8192, 256, 0, stream>>>(xb, aggr0, start, deg, csr, invd,
                                                         nullptr, 0, 0);
        } else {
            aggr_kernel<true><<<8192, 256, 0, stream>>>(x, aggr0, start, deg, csr, invd,
                                                        nullptr, 0, 0);
        }
        for (int e = 0; e < 4; ++e) {
            const u16* BtL0 = Bt + (size_t)(e * 2 + 0) * WMAT;
            const u16* BtL1 = Bt + (size_t)(e * 2 + 1) * WMAT;
            const float* b0 = bl + (e * 2 + 0) * 512;
            const float* b1 = bl + (e * 2 + 1) * 512;
            if (tier == 4)
                gemm_kernel<false><<<256 * 4, 256, 0, stream>>>(
                    aggr0, xb, nullptr, 0, BtL0, 0, b0, 0, h1, 0, nullptr, wg, 0, e, 4);
            else
                gemm_kernel<true><<<256 * 4, 256, 0, stream>>>(
                    aggr0, nullptr, x, 0, BtL0, 0, b0, 0, h1, 0, nullptr, wg, 0, e, 4);
            aggr_kernel<false><<<8192, 256, 0, stream>>>(h1, aggr1, start, deg, csr, invd,
                                                         wg, e, 0);
            gemm_kernel<false><<<256 * 4, 256, 0, stream>>>(
                aggr1, h1, nullptr, 0, BtL1, 0, b1, 0, nullptr, 0, outp, wg,
                (e == 0) ? 1 : 2, e, 4);
        }
    }
}

// Round 5
// 843.715 us; speedup vs baseline: 1.0014x; 1.0014x over previous
//
#include <hip/hip_runtime.h>

typedef unsigned short u16;
typedef unsigned int u32;
typedef u16 u16x8 __attribute__((ext_vector_type(8)));
typedef short s16x8 __attribute__((ext_vector_type(8)));
typedef float f32x4 __attribute__((ext_vector_type(4)));

#define NN 32768
#define EE 262144
#define DD 512
#define WMAT (512 * 1024)   // elements per Bt matrix

__device__ __forceinline__ float b2f(u16 u) {
    return __uint_as_float(((u32)u) << 16);
}
__device__ __forceinline__ u16 f2b(float f) {
    u32 u = __float_as_uint(f);
    u32 r = (u + 0x7FFFu + ((u >> 16) & 1u)) >> 16;
    return (u16)r;
}

// -------- edge-index width detection: int64 (high words zero) vs int32 ------------------
__global__ void detect_kernel(const u32* __restrict__ ei, int* __restrict__ flags) {
    if (threadIdx.x == 0) {
        int allzero = 1;
        for (int i = 0; i < 64; ++i)
            if (ei[2 * i + 1] != 0u) allzero = 0;
        flags[0] = allzero;  // 1 => int64 layout
    }
}

__global__ void edges_kernel(const u32* __restrict__ ei, const int* __restrict__ flags,
                             int* __restrict__ s32, int* __restrict__ d32) {
    int t = blockIdx.x * 256 + threadIdx.x;
    u32 s, d;
    if (flags[0]) {  // int64
        s = ei[2 * t];
        d = ei[2 * EE + 2 * t];
    } else {         // int32
        s = ei[t];
        d = ei[EE + t];
    }
    s32[t] = (int)(s & (NN - 1));
    d32[t] = (int)(d & (NN - 1));
}

// -------- fp32 x -> bf16 xb (kept for tiers without fused gate path) ---------------------
__global__ void convert_kernel(const float* __restrict__ x, u16* __restrict__ xb) {
    int t = blockIdx.x * 256 + threadIdx.x;
    f32x4 a = ((const f32x4*)x)[t * 2];
    f32x4 b = ((const f32x4*)x)[t * 2 + 1];
    u16x8 o;
    o[0] = f2b(a[0]); o[1] = f2b(a[1]); o[2] = f2b(a[2]); o[3] = f2b(a[3]);
    o[4] = f2b(b[0]); o[5] = f2b(b[1]); o[6] = f2b(b[2]); o[7] = f2b(b[3]);
    ((u16x8*)xb)[t] = o;
}

// -------- weight transpose+cvt: W[e][l][k][n] fp32 -> Bt[e*2+l][n][k 0..1023] bf16 -------
__global__ void transpose_kernel(const float* __restrict__ Wl, const float* __restrict__ Wr,
                                 u16* __restrict__ Bt) {
    int bid = blockIdx.x;
    int matid = bid >> 8;
    int tile = bid & 255;
    int em = matid >> 1;
    int half = matid & 1;
    const float* W = (half ? Wr : Wl) + (size_t)em * DD * DD;
    u16* out = Bt + (size_t)em * DD * 1024 + half * DD;
    int tk = (tile >> 4) * 32, tn = (tile & 15) * 32;
    __shared__ float s[32][33];
    int t = threadIdx.x;
    int rr = t >> 5, cc = t & 31;
#pragma unroll
    for (int p = 0; p < 4; ++p) {
        int kr = p * 8 + rr;
        s[kr][cc] = W[(size_t)(tk + kr) * DD + tn + cc];
    }
    __syncthreads();
#pragma unroll
    for (int p = 0; p < 4; ++p) {
        int nr = p * 8 + rr;
        out[(size_t)(tn + nr) * 1024 + tk + cc] = f2b(s[cc][nr]);
    }
}

// -------- gating (standalone, tiers without xb) ------------------------------------------
__global__ void gate_kernel(const float* __restrict__ x, const float* __restrict__ gw,
                            const float* __restrict__ gb, float* __restrict__ wg) {
    int node = blockIdx.x * 4 + (threadIdx.x >> 6);
    int l = threadIdx.x & 63;
    const f32x4* xr = (const f32x4*)(x + (size_t)node * DD) + l * 2;
    f32x4 x0 = xr[0], x1 = xr[1];
    float a0 = 0.f, a1 = 0.f, a2 = 0.f, a3 = 0.f;
#pragma unroll
    for (int j = 0; j < 8; ++j) {
        float xf = (j < 4) ? x0[j & 3] : x1[j & 3];
        f32x4 wr = ((const f32x4*)gw)[l * 8 + j];
        a0 += xf * wr[0]; a1 += xf * wr[1]; a2 += xf * wr[2]; a3 += xf * wr[3];
    }
#pragma unroll
    for (int off = 32; off > 0; off >>= 1) {
        a0 += __shfl_down(a0, off, 64);
        a1 += __shfl_down(a1, off, 64);
        a2 += __shfl_down(a2, off, 64);
        a3 += __shfl_down(a3, off, 64);
    }
    if (l == 0) {
        float lg[4] = {a0 + gb[0], a1 + gb[1], a2 + gb[2], a3 + gb[3]};
        float m = fmaxf(fmaxf(lg[0], lg[1]), fmaxf(lg[2], lg[3]));
        float p[4]; float s = 0.f;
#pragma unroll
        for (int e = 0; e < 4; ++e) { p[e] = expf(lg[e] - m); s += p[e]; }
        float inv = 1.f / s;
#pragma unroll
        for (int e = 0; e < 4; ++e) p[e] *= inv;
        int i0 = 0;
#pragma unroll
        for (int e = 1; e < 4; ++e) if (p[e] > p[i0]) i0 = e;
        int i1 = -1;
#pragma unroll
        for (int e = 0; e < 4; ++e) if (e != i0 && (i1 < 0 || p[e] > p[i1])) i1 = e;
        float o[4] = {0.f, 0.f, 0.f, 0.f};
        o[i0] = p[i0]; o[i1] = p[i1];
        float* w = wg + (size_t)node * 4;
        w[0] = o[0]; w[1] = o[1]; w[2] = o[2]; w[3] = o[3];
    }
}

// -------- fused gating + fp32->bf16 convert: one pass over x -----------------------------
__global__ void gateconv_kernel(const float* __restrict__ x, const float* __restrict__ gw,
                                const float* __restrict__ gb, float* __restrict__ wg,
                                u16* __restrict__ xb) {
    int node = blockIdx.x * 4 + (threadIdx.x >> 6);
    int l = threadIdx.x & 63;
    const f32x4* xr = (const f32x4*)(x + (size_t)node * DD) + l * 2;
    f32x4 x0 = xr[0], x1 = xr[1];
    u16x8 o8;
    o8[0] = f2b(x0[0]); o8[1] = f2b(x0[1]); o8[2] = f2b(x0[2]); o8[3] = f2b(x0[3]);
    o8[4] = f2b(x1[0]); o8[5] = f2b(x1[1]); o8[6] = f2b(x1[2]); o8[7] = f2b(x1[3]);
    *((u16x8*)(xb + (size_t)node * DD) + l) = o8;
    float a0 = 0.f, a1 = 0.f, a2 = 0.f, a3 = 0.f;
#pragma unroll
    for (int j = 0; j < 8; ++j) {
        float xf = (j < 4) ? x0[j & 3] : x1[j & 3];
        f32x4 wr = ((const f32x4*)gw)[l * 8 + j];
        a0 += xf * wr[0]; a1 += xf * wr[1]; a2 += xf * wr[2]; a3 += xf * wr[3];
    }
#pragma unroll
    for (int off = 32; off > 0; off >>= 1) {
        a0 += __shfl_down(a0, off, 64);
        a1 += __shfl_down(a1, off, 64);
        a2 += __shfl_down(a2, off, 64);
        a3 += __shfl_down(a3, off, 64);
    }
    if (l == 0) {
        float lg[4] = {a0 + gb[0], a1 + gb[1], a2 + gb[2], a3 + gb[3]};
        float m = fmaxf(fmaxf(lg[0], lg[1]), fmaxf(lg[2], lg[3]));
        float p[4]; float s = 0.f;
#pragma unroll
        for (int e = 0; e < 4; ++e) { p[e] = expf(lg[e] - m); s += p[e]; }
        float inv = 1.f / s;
#pragma unroll
        for (int e = 0; e < 4; ++e) p[e] *= inv;
        int i0 = 0;
#pragma unroll
        for (int e = 1; e < 4; ++e) if (p[e] > p[i0]) i0 = e;
        int i1 = -1;
#pragma unroll
        for (int e = 0; e < 4; ++e) if (e != i0 && (i1 < 0 || p[e] > p[i1])) i1 = e;
        float o[4] = {0.f, 0.f, 0.f, 0.f};
        o[i0] = p[i0]; o[i1] = p[i1];
        float* w = wg + (size_t)node * 4;
        w[0] = o[0]; w[1] = o[1]; w[2] = o[2]; w[3] = o[3];
    }
}

// -------- expert compaction: per-expert active-node lists (order-free) -------------------
__global__ void compact_kernel(const float* __restrict__ wg, int* __restrict__ cnt,
                               int* __restrict__ list) {
    int node = blockIdx.x * 256 + threadIdx.x;
    const float* w = wg + (size_t)node * 4;
#pragma unroll
    for (int e = 0; e < 4; ++e)
        if (w[e] > 0.f) {
            int p = atomicAdd(&cnt[e], 1);
            list[e * NN + p] = node;
        }
}

// tile map: sequence of (expert, m-tile-within-expert) for compacted L1 GEMM.
// total rows = 2*NN (top-2) -> <= 512+4 tiles. Single-thread scalar loop (~2 us).
__global__ void tilemap_kernel(const int* __restrict__ cnt, int* __restrict__ tmap,
                               int* __restrict__ tcount) {
    if (threadIdx.x == 0) {
        int T = 0;
        for (int e = 0; e < 4; ++e) {
            int nt = (cnt[e] + 127) >> 7;
            for (int i = 0; i < nt; ++i) tmap[T++] = (e << 16) | i;
        }
        *tcount = T;
    }
}

// -------- CSR build ----------------------------------------------------------------------
__global__ void deg_kernel(const int* __restrict__ dst, int* __restrict__ deg) {
    int t = blockIdx.x * blockDim.x + threadIdx.x;
    if (t < EE) atomicAdd(&deg[dst[t]], 1);
}

__global__ void scan1_kernel(const int* __restrict__ deg, int* __restrict__ start,
                             float* __restrict__ invd, int* __restrict__ bsum) {
    int t = threadIdx.x;
    int idx = blockIdx.x * 1024 + t;
    int v = deg[idx];
    int sc = v;
#pragma unroll
    for (int off = 1; off < 64; off <<= 1) {
        int u = __shfl_up(sc, off, 64);
        if ((t & 63) >= off) sc += u;
    }
    __shared__ int wsum[16], woff[16];
    if ((t & 63) == 63) wsum[t >> 6] = sc;
    __syncthreads();
    if (t == 0) {
        int acc = 0;
        for (int w = 0; w < 16; ++w) { woff[w] = acc; acc += wsum[w]; }
        bsum[blockIdx.x] = acc;
    }
    __syncthreads();
    start[idx] = woff[t >> 6] + sc - v;
    invd[idx] = v > 0 ? 1.0f / (float)v : 0.0f;
}

__global__ void scan2_kernel(int* __restrict__ bsum, int* __restrict__ boff) {
    if (threadIdx.x == 0) {
        int acc = 0;
        for (int b = 0; b < 32; ++b) { boff[b] = acc; acc += bsum[b]; }
    }
}

__global__ void scan3_kernel(int* __restrict__ start, int* __restrict__ cursor,
                             const int* __restrict__ boff) {
    int idx = blockIdx.x * 256 + threadIdx.x;
    int s = start[idx] + boff[idx >> 10];
    start[idx] = s;
    cursor[idx] = s;
}

__global__ void scatter_kernel(const int* __restrict__ src, const int* __restrict__ dst,
                               int* __restrict__ cursor, int* __restrict__ csr) {
    int t = blockIdx.x * blockDim.x + threadIdx.x;
    if (t < EE) {
        int d = dst[t];
        int pos = atomicAdd(&cursor[d], 1);
        csr[pos] = src[t];
    }
}

// -------- mean aggregation over CSR; multi-expert: grid = nExp*8192 blocks ---------------
template <bool F32IN>
__global__ void aggr_kernel(const void* __restrict__ hv, u16* __restrict__ outB,
                            const int* __restrict__ start, const int* __restrict__ deg,
                            const int* __restrict__ csr, const float* __restrict__ invd,
                            const float* __restrict__ wg, int eBase, size_t stride) {
    int eo = blockIdx.x >> 13;
    int node = ((blockIdx.x & 8191) << 2) + (threadIdx.x >> 6);
    int expert = eBase + eo;
    if (wg != nullptr && wg[(size_t)node * 4 + expert] == 0.f) return;
    int l = threadIdx.x & 63;
    int s0 = start[node];
    int dg = deg[node];
    u16* out = outB + (size_t)eo * stride;
    const u16* hB = (const u16*)hv + (size_t)eo * stride;
    const float* hF = (const float*)hv + (size_t)eo * stride;
    float a[8] = {0.f, 0.f, 0.f, 0.f, 0.f, 0.f, 0.f, 0.f};

    for (int base = 0; base < dg; base += 64) {
        int cnt = dg - base;
        if (cnt > 64) cnt = 64;
        int vidx = 0;
        if (l < cnt) vidx = csr[s0 + base + l];
        int q = 0;
        if (!F32IN) {
            for (; q + 8 <= cnt; q += 8) {
                int j0 = __shfl(vidx, q, 64);
                int j1 = __shfl(vidx, q + 1, 64);
                int j2 = __shfl(vidx, q + 2, 64);
                int j3 = __shfl(vidx, q + 3, 64);
                int j4 = __shfl(vidx, q + 4, 64);
                int j5 = __shfl(vidx, q + 5, 64);
                int j6 = __shfl(vidx, q + 6, 64);
                int j7 = __shfl(vidx, q + 7, 64);
                u16x8 v0 = *((const u16x8*)(hB + (size_t)j0 * DD) + l);
                u16x8 v1 = *((const u16x8*)(hB + (size_t)j1 * DD) + l);
                u16x8 v2 = *((const u16x8*)(hB + (size_t)j2 * DD) + l);
                u16x8 v3 = *((const u16x8*)(hB + (size_t)j3 * DD) + l);
                u16x8 v4 = *((const u16x8*)(hB + (size_t)j4 * DD) + l);
                u16x8 v5 = *((const u16x8*)(hB + (size_t)j5 * DD) + l);
                u16x8 v6 = *((const u16x8*)(hB + (size_t)j6 * DD) + l);
                u16x8 v7 = *((const u16x8*)(hB + (size_t)j7 * DD) + l);
#pragma unroll
                for (int q2 = 0; q2 < 8; ++q2)
                    a[q2] += ((b2f(v0[q2]) + b2f(v1[q2])) + (b2f(v2[q2]) + b2f(v3[q2]))) +
                             ((b2f(v4[q2]) + b2f(v5[q2])) + (b2f(v6[q2]) + b2f(v7[q2])));
            }
        }
        for (; q + 4 <= cnt; q += 4) {
            int j0 = __shfl(vidx, q, 64);
            int j1 = __shfl(vidx, q + 1, 64);
            int j2 = __shfl(vidx, q + 2, 64);
            int j3 = __shfl(vidx, q + 3, 64);
            if (F32IN) {
                const f32x4* r0 = (const f32x4*)(hF + (size_t)j0 * DD) + l * 2;
                const f32x4* r1 = (const f32x4*)(hF + (size_t)j1 * DD) + l * 2;
                const f32x4* r2 = (const f32x4*)(hF + (size_t)j2 * DD) + l * 2;
                const f32x4* r3 = (const f32x4*)(hF + (size_t)j3 * DD) + l * 2;
                f32x4 u0 = r0[0], u1 = r0[1];
                f32x4 u2 = r1[0], u3 = r1[1];
                f32x4 u4 = r2[0], u5 = r2[1];
                f32x4 u6 = r3[0], u7 = r3[1];
#pragma unroll
                for (int q2 = 0; q2 < 4; ++q2) {
                    a[q2] += (u0[q2] + u2[q2]) + (u4[q2] + u6[q2]);
                    a[4 + q2] += (u1[q2] + u3[q2]) + (u5[q2] + u7[q2]);
                }
            } else {
                u16x8 v0 = *((const u16x8*)(hB + (size_t)j0 * DD) + l);
                u16x8 v1 = *((const u16x8*)(hB + (size_t)j1 * DD) + l);
                u16x8 v2 = *((const u16x8*)(hB + (size_t)j2 * DD) + l);
                u16x8 v3 = *((const u16x8*)(hB + (size_t)j3 * DD) + l);
#pragma unroll
                for (int q2 = 0; q2 < 8; ++q2)
                    a[q2] += (b2f(v0[q2]) + b2f(v1[q2])) + (b2f(v2[q2]) + b2f(v3[q2]));
            }
        }
        for (; q < cnt; ++q) {
            int j = __shfl(vidx, q, 64);
            if (F32IN) {
                const f32x4* r = (const f32x4*)(hF + (size_t)j * DD) + l * 2;
                f32x4 u0 = r[0], u1 = r[1];
#pragma unroll
                for (int q2 = 0; q2 < 4; ++q2) { a[q2] += u0[q2]; a[4 + q2] += u1[q2]; }
            } else {
                u16x8 v = *((const u16x8*)(hB + (size_t)j * DD) + l);
#pragma unroll
                for (int q2 = 0; q2 < 8; ++q2) a[q2] += b2f(v[q2]);
            }
        }
    }
    float sc = invd[node];
    u16x8 o;
#pragma unroll
    for (int q2 = 0; q2 < 8; ++q2) o[q2] = f2b(a[q2] * sc);
    *((u16x8*)(out + (size_t)node * DD) + l) = o;
}

// -------- dual-expert gated aggregation (top-2): one wave = one node, both active experts.
__global__ void aggr2_kernel(const u16* __restrict__ h, u16* __restrict__ outB,
                             const int* __restrict__ start, const int* __restrict__ deg,
                             const int* __restrict__ csr, const float* __restrict__ invd,
                             const float* __restrict__ wg) {
    const int node = (blockIdx.x << 2) + (threadIdx.x >> 6);
    const int l = threadIdx.x & 63;
    const float* w = wg + (size_t)node * 4;
    int e0 = -1, e1 = -1;
#pragma unroll
    for (int e = 0; e < 4; ++e) {
        if (w[e] > 0.f) { if (e0 < 0) e0 = e; else e1 = e; }
    }
    if (e0 < 0) return;
    const int dual = (e1 >= 0);
    if (!dual) e1 = e0;
    const size_t STRE = (size_t)NN * DD;
    const u16* hA = h + (size_t)e0 * STRE;
    const u16* hC = h + (size_t)e1 * STRE;
    const int s0 = start[node];
    const int dg = deg[node];
    float a0[8] = {0.f, 0.f, 0.f, 0.f, 0.f, 0.f, 0.f, 0.f};
    float a1[8] = {0.f, 0.f, 0.f, 0.f, 0.f, 0.f, 0.f, 0.f};

    for (int base = 0; base < dg; base += 64) {
        int cnt = dg - base;
        if (cnt > 64) cnt = 64;
        int vidx = 0;
        if (l < cnt) vidx = csr[s0 + base + l];
        int q = 0;
        for (; q + 4 <= cnt; q += 4) {
            int j0 = __shfl(vidx, q, 64);
            int j1 = __shfl(vidx, q + 1, 64);
            int j2 = __shfl(vidx, q + 2, 64);
            int j3 = __shfl(vidx, q + 3, 64);
            u16x8 u0 = *((const u16x8*)(hA + (size_t)j0 * DD) + l);
            u16x8 u1 = *((const u16x8*)(hA + (size_t)j1 * DD) + l);
            u16x8 u2 = *((const u16x8*)(hA + (size_t)j2 * DD) + l);
            u16x8 u3 = *((const u16x8*)(hA + (size_t)j3 * DD) + l);
            u16x8 t0 = *((const u16x8*)(hC + (size_t)j0 * DD) + l);
            u16x8 t1 = *((const u16x8*)(hC + (size_t)j1 * DD) + l);
            u16x8 t2 = *((const u16x8*)(hC + (size_t)j2 * DD) + l);
            u16x8 t3 = *((const u16x8*)(hC + (size_t)j3 * DD) + l);
#pragma unroll
            for (int q2 = 0; q2 < 8; ++q2) {
                a0[q2] += (b2f(u0[q2]) + b2f(u1[q2])) + (b2f(u2[q2]) + b2f(u3[q2]));
                a1[q2] += (b2f(t0[q2]) + b2f(t1[q2])) + (b2f(t2[q2]) + b2f(t3[q2]));
            }
        }
        for (; q < cnt; ++q) {
            int j = __shfl(vidx, q, 64);
            u16x8 u = *((const u16x8*)(hA + (size_t)j * DD) + l);
            u16x8 t = *((const u16x8*)(hC + (size_t)j * DD) + l);
#pragma unroll
            for (int q2 = 0; q2 < 8; ++q2) { a0[q2] += b2f(u[q2]); a1[q2] += b2f(t[q2]); }
        }
    }
    float sc = invd[node];
    u16x8 o0, o1;
#pragma unroll
    for (int q2 = 0; q2 < 8; ++q2) { o0[q2] = f2b(a0[q2] * sc); o1[q2] = f2b(a1[q2] * sc); }
    *((u16x8*)(outB + (size_t)e0 * STRE + (size_t)node * DD) + l) = o0;
    if (dual)
        *((u16x8*)(outB + (size_t)e1 * STRE + (size_t)node * DD) + l) = o1;
}

__device__ __forceinline__ void gload16(const void* g, void* l) {
    __builtin_amdgcn_global_load_lds((const __attribute__((address_space(1))) void*)g,
                                     (__attribute__((address_space(3))) void*)l, 16, 0, 0);
}

// -------- legacy fused GEMM (fallback tiers): A and B both staged through LDS ------------
template <bool A2F32>
__global__ void __launch_bounds__(256, 4) gemm_kernel(
    const u16* __restrict__ A1, const u16* __restrict__ A2b, const float* __restrict__ A2f,
    size_t sA, const u16* __restrict__ Bt, size_t sBt,
    const float* __restrict__ bias, size_t sBias,
    u16* __restrict__ Hout, size_t sH, float* __restrict__ Out,
    const float* __restrict__ wg, int mode, int eBase, int ntt) {
    __shared__ u16 lds[A2F32 ? 12288 : 8192];
    u16* ldsA = lds;
    float* ldsF = (float*)lds;
    u16* ldsB = lds + (A2F32 ? 8192 : 4096);
    const int tid = threadIdx.x;
    const int lane = tid & 63;
    const int w = tid >> 6;

    const int bid = blockIdx.x;
    const int xcd = bid & 7;
    const int local = bid >> 3;
    const int mtl = local / ntt;
    const int sub = local - mtl * ntt;
    const int expert = sub >> 2;
    const int wgE = eBase + expert;
    const int m0 = (xcd * 32 + mtl) * 128;
    const int n0 = (sub & 3) * 128;

    const u16* A1p = A1 + (size_t)expert * sA;
    const u16* A2p = A2b + (size_t)expert * sA;
    const u16* Btp = Bt + (size_t)expert * sBt;
    const float* biasp = bias + (size_t)expert * sBias;
    u16* Houtp = Hout + (size_t)expert * sH;

    const int wm = (w >> 1) * 64;
    const int wn = (w & 1) * 64;

    f32x4 acc[4][4];
#pragma unroll
    for (int i = 0; i < 4; ++i)
#pragma unroll
        for (int j = 0; j < 4; ++j) acc[i][j] = (f32x4){0.f, 0.f, 0.f, 0.f};

    const int p0 = tid, p1 = 256 + tid;
    const int r0 = p0 >> 2, c0 = ((p0 & 3) - (r0 >> 1)) & 3;
    const int r1 = p1 >> 2, c1 = ((p1 & 3) - (r1 >> 1)) & 3;
    const int arow = lane & 15;
    const int kc = lane >> 4;

    for (int kb = 0; kb < 32; ++kb) {
        __syncthreads();
        if (!A2F32 || kb < 16) {
            const u16* As = (kb < 16) ? A1p : A2p;
            const int kcol = (kb & 15) * 32;
            gload16(As + (size_t)(m0 + r0) * DD + kcol + c0 * 8, ldsA + p0 * 8);
            gload16(As + (size_t)(m0 + r1) * DD + kcol + c1 * 8, ldsA + p1 * 8);
        } else {
            const float* Af = A2f + (size_t)m0 * DD + (kb - 16) * 32;
#pragma unroll
            for (int q = 0; q < 4; ++q) {
                int p = q * 256 + tid;
                int rr = p >> 3, cpos = p & 7, cc2 = (cpos - rr) & 7;
                gload16(Af + (size_t)rr * DD + cc2 * 4, ldsF + p * 4);
            }
        }
        gload16(Btp + (size_t)(n0 + r0) * 1024 + kb * 32 + c0 * 8, ldsB + p0 * 8);
        gload16(Btp + (size_t)(n0 + r1) * 1024 + kb * 32 + c1 * 8, ldsB + p1 * 8);
        __syncthreads();
        s16x8 af[4], bf[4];
        if (!A2F32 || kb < 16) {
#pragma unroll
            for (int f = 0; f < 4; ++f) {
                int ra = wm + f * 16 + arow;
                int pa = (kc + (ra >> 1)) & 3;
                af[f] = *(const s16x8*)(ldsA + (ra * 4 + pa) * 8);
            }
        } else {
#pragma unroll
            for (int f = 0; f < 4; ++f) {
                int ra = wm + f * 16 + arow;
                int plo = ra * 8 + ((2 * kc + ra) & 7);
                int phi = ra * 8 + ((2 * kc + 1 + ra) & 7);
                f32x4 lo = *(const f32x4*)(ldsF + plo * 4);
                f32x4 hi = *(const f32x4*)(ldsF + phi * 4);
                s16x8 t;
                t[0] = (short)f2b(lo[0]); t[1] = (short)f2b(lo[1]);
                t[2] = (short)f2b(lo[2]); t[3] = (short)f2b(lo[3]);
                t[4] = (short)f2b(hi[0]); t[5] = (short)f2b(hi[1]);
                t[6] = (short)f2b(hi[2]); t[7] = (short)f2b(hi[3]);
                af[f] = t;
            }
        }
#pragma unroll
        for (int f = 0; f < 4; ++f) {
            int rb = wn + f * 16 + arow;
            int pb = (kc + (rb >> 1)) & 3;
            bf[f] = *(const s16x8*)(ldsB + (rb * 4 + pb) * 8);
        }
#pragma unroll
        for (int i = 0; i < 4; ++i)
#pragma unroll
            for (int j = 0; j < 4; ++j)
                acc[i][j] = __builtin_amdgcn_mfma_f32_16x16x32_bf16(af[i], bf[j], acc[i][j], 0, 0, 0);
    }

    const int colq = lane & 15;
    const int rq = lane >> 4;
#pragma unroll
    for (int i = 0; i < 4; ++i) {
#pragma unroll
        for (int j = 0; j < 4; ++j) {
            int col = n0 + wn + j * 16 + colq;
            float bv = biasp[col];
#pragma unroll
            for (int r = 0; r < 4; ++r) {
                int row = m0 + wm + i * 16 + rq * 4 + r;
                float v = fmaxf(acc[i][j][r] + bv, 0.f);
                size_t idx = (size_t)row * DD + col;
                if (mode == 0) {
                    Houtp[idx] = f2b(v);
                } else {
                    float wv = wg[(size_t)row * 4 + wgE];
                    if (mode == 1) {
                        Out[idx] = wv * v;
                    } else if (mode == 2) {
                        if (wv > 0.f) Out[idx] += wv * v;
                    } else {
                        if (wv > 0.f) unsafeAtomicAdd(&Out[idx], wv * v);
                    }
                }
            }
        }
    }
}

// -------- L0 GEMM, B direct-from-global: h1[e] = relu([aggr0|xb] @ Bt_e^T + b_e) ---------
// LDS holds only the A-panel (8 KB/K-step); B-fragments are vector-loaded straight to
// registers (B is L2-resident, 1 MB/expert). Halves LDS traffic per K-step (48->24 KB).
// The __syncthreads() vmcnt-drain synchronizes the B loads for free.
__global__ void __launch_bounds__(256, 4) gemm_bd_kernel(
    const u16* __restrict__ A1, const u16* __restrict__ A2,
    const u16* __restrict__ Bt, const float* __restrict__ bias,
    u16* __restrict__ Hout) {
    __shared__ u16 lds[4096];  // A only: 128 rows x 32 k
    const int tid = threadIdx.x;
    const int lane = tid & 63;
    const int w = tid >> 6;

    const int bid = blockIdx.x;
    const int xcd = bid & 7;
    const int local = bid >> 3;
    const int mtl = local >> 4;
    const int sub = local & 15;
    const int expert = sub >> 2;
    const int m0 = (xcd * 32 + mtl) * 128;
    const int n0 = (sub & 3) * 128;

    const u16* Btp = Bt + (size_t)expert * (2 * WMAT);
    const float* biasp = bias + (size_t)expert * 1024;
    u16* Houtp = Hout + (size_t)expert * ((size_t)NN * DD);

    const int wm = (w >> 1) * 64;
    const int wn = (w & 1) * 64;

    f32x4 acc[4][4];
#pragma unroll
    for (int i = 0; i < 4; ++i)
#pragma unroll
        for (int j = 0; j < 4; ++j) acc[i][j] = (f32x4){0.f, 0.f, 0.f, 0.f};

    const int p0 = tid, p1 = 256 + tid;
    const int r0 = p0 >> 2, c0 = ((p0 & 3) - (r0 >> 1)) & 3;
    const int r1 = p1 >> 2, c1 = ((p1 & 3) - (r1 >> 1)) & 3;
    const int arow = lane & 15;
    const int kc = lane >> 4;

    for (int kb = 0; kb < 32; ++kb) {
        __syncthreads();
        const u16* As = (kb < 16) ? A1 : A2;
        const int kcol = (kb & 15) * 32;
        gload16(As + (size_t)(m0 + r0) * DD + kcol + c0 * 8, lds + p0 * 8);
        gload16(As + (size_t)(m0 + r1) * DD + kcol + c1 * 8, lds + p1 * 8);
        s16x8 bf[4];
#pragma unroll
        for (int f = 0; f < 4; ++f) {
            int rb = n0 + wn + f * 16 + arow;
            bf[f] = *(const s16x8*)(Btp + (size_t)rb * 1024 + kb * 32 + kc * 8);
        }
        __syncthreads();
        s16x8 af[4];
#pragma unroll
        for (int f = 0; f < 4; ++f) {
            int ra = wm + f * 16 + arow;
            int pa = (kc + (ra >> 1)) & 3;
            af[f] = *(const s16x8*)(lds + (ra * 4 + pa) * 8);
        }
#pragma unroll
        for (int i = 0; i < 4; ++i)
#pragma unroll
            for (int j = 0; j < 4; ++j)
                acc[i][j] = __builtin_amdgcn_mfma_f32_16x16x32_bf16(af[i], bf[j], acc[i][j], 0, 0, 0);
    }

    const int colq = lane & 15;
    const int rq = lane >> 4;
#pragma unroll
    for (int i = 0; i < 4; ++i) {
#pragma unroll
        for (int j = 0; j < 4; ++j) {
            int col = n0 + wn + j * 16 + colq;
            float bv = biasp[col];
#pragma unroll
            for (int r = 0; r < 4; ++r) {
                int row = m0 + wm + i * 16 + rq * 4 + r;
                float v = fmaxf(acc[i][j][r] + bv, 0.f);
                Houtp[(size_t)row * DD + col] = f2b(v);
            }
        }
    }
}

// -------- L1 GEMM over compacted rows: out[node] += wv * relu([aggr1|h1]@Bt^T + b) -------
// Row set = exactly the (node,expert) pairs with wv>0 (top-2 => 2*NN rows, half the dense
// work). Padding rows are clamped (duplicate compute) and masked at the write.
__global__ void __launch_bounds__(256, 4) gemm_gather_kernel(
    const u16* __restrict__ A1, const u16* __restrict__ A2,
    const u16* __restrict__ Bt, const float* __restrict__ bias,
    float* __restrict__ Out, const float* __restrict__ wg,
    const int* __restrict__ list, const int* __restrict__ cnt,
    const int* __restrict__ tmap, const int* __restrict__ tcount) {
    const int t = blockIdx.x >> 2;
    if (t >= *tcount) return;
    const u32 mi = (u32)tmap[t];
    const int e = mi >> 16;
    const int mt = mi & 0xffff;
    const int cntE = cnt[e];
    const int base = mt << 7;
    const int n0 = (blockIdx.x & 3) * 128;

    __shared__ u16 lds[8192];
    u16* ldsA = lds;
    u16* ldsB = lds + 4096;
    const int tid = threadIdx.x;
    const int lane = tid & 63;
    const int w = tid >> 6;

    const size_t STRE = (size_t)NN * DD;
    const u16* A1p = A1 + (size_t)e * STRE;
    const u16* A2p = A2 + (size_t)e * STRE;
    const u16* Btp = Bt + (size_t)e * (2 * WMAT);
    const float* biasp = bias + (size_t)e * 1024;
    const int* listE = list + e * NN;

    const int wm = (w >> 1) * 64;
    const int wn = (w & 1) * 64;

    f32x4 acc[4][4];
#pragma unroll
    for (int i = 0; i < 4; ++i)
#pragma unroll
        for (int j = 0; j < 4; ++j) acc[i][j] = (f32x4){0.f, 0.f, 0.f, 0.f};

    const int p0 = tid, p1 = 256 + tid;
    const int r0 = p0 >> 2, c0 = ((p0 & 3) - (r0 >> 1)) & 3;
    const int r1 = p1 >> 2, c1 = ((p1 & 3) - (r1 >> 1)) & 3;
    int q0 = base + r0; if (q0 >= cntE) q0 = cntE - 1;
    int q1 = base + r1; if (q1 >= cntE) q1 = cntE - 1;
    const int gr0 = listE[q0];
    const int gr1 = listE[q1];
    const int arow = lane & 15;
    const int kc = lane >> 4;

    for (int kb = 0; kb < 32; ++kb) {
        __syncthreads();
        const u16* As = (kb < 16) ? A1p : A2p;
        const int kcol = (kb & 15) * 32;
        gload16(As + (size_t)gr0 * DD + kcol + c0 * 8, ldsA + p0 * 8);
        gload16(As + (size_t)gr1 * DD + kcol + c1 * 8, ldsA + p1 * 8);
        gload16(Btp + (size_t)(n0 + r0) * 1024 + kb * 32 + c0 * 8, ldsB + p0 * 8);
        gload16(Btp + (size_t)(n0 + r1) * 1024 + kb * 32 + c1 * 8, ldsB + p1 * 8);
        __syncthreads();
        s16x8 af[4], bf[4];
#pragma unroll
        for (int f = 0; f < 4; ++f) {
            int ra = wm + f * 16 + arow;
            int pa = (kc + (ra >> 1)) & 3;
            af[f] = *(const s16x8*)(ldsA + (ra * 4 + pa) * 8);
        }
#pragma unroll
        for (int f = 0; f < 4; ++f) {
            int rb = wn + f * 16 + arow;
            int pb = (kc + (rb >> 1)) & 3;
            bf[f] = *(const s16x8*)(ldsB + (rb * 4 + pb) * 8);
        }
#pragma unroll
        for (int i = 0; i < 4; ++i)
#pragma unroll
            for (int j = 0; j < 4; ++j)
                acc[i][j] = __builtin_amdgcn_mfma_f32_16x16x32_bf16(af[i], bf[j], acc[i][j], 0, 0, 0);
    }

    const int colq = lane & 15;
    const int rq = lane >> 4;
#pragma unroll
    for (int i = 0; i < 4; ++i) {
        int nd[4]; float wv4[4]; bool val[4];
#pragma unroll
        for (int r = 0; r < 4; ++r) {
            int rowl = base + wm + i * 16 + rq * 4 + r;
            val[r] = rowl < cntE;
            int qq = val[r] ? rowl : 0;
            nd[r] = listE[qq];
            wv4[r] = wg[(size_t)nd[r] * 4 + e];
        }
#pragma unroll
        for (int j = 0; j < 4; ++j) {
            int col = n0 + wn + j * 16 + colq;
            float bv = biasp[col];
#pragma unroll
            for (int r = 0; r < 4; ++r) {
                if (val[r]) {
                    float v = fmaxf(acc[i][j][r] + bv, 0.f);
                    unsafeAtomicAdd(&Out[(size_t)nd[r] * DD + col], wv4[r] * v);
                }
            }
        }
    }
}

extern "C" void kernel_launch(void* const* d_in, const int* in_sizes, int n_in,
                              void* d_out, int out_size, void* d_ws, size_t ws_size,
                              hipStream_t stream) {
    const float* x  = (const float*)d_in[0];
    const float* gW = (const float*)d_in[1];
    const float* gb = (const float*)d_in[2];
    const float* Wl = (const float*)d_in[3];
    const float* bl = (const float*)d_in[4];
    const float* Wr = (const float*)d_in[5];
    const u32*   ei = (const u32*)d_in[6];
    float* outp = (float*)d_out;

    char* ws = (char*)d_ws;
    size_t off = 0;
    auto alloc = [&](size_t bytes) -> void* {
        void* p = ws + off;
        off += (bytes + 255) & ~(size_t)255;
        return p;
    };
    const size_t MB32 = (size_t)NN * DD * 2;
    const size_t STR = (size_t)NN * DD;      // per-expert element stride
    int*   flags  = (int*)alloc(512);
    float* wg     = (float*)alloc((size_t)NN * 4 * 4);
    int*   deg    = (int*)alloc((size_t)NN * 4);
    int*   start  = (int*)alloc((size_t)NN * 4);
    int*   cursor = (int*)alloc((size_t)NN * 4);
    float* invd   = (float*)alloc((size_t)NN * 4);
    int*   src32  = (int*)alloc((size_t)EE * 4);
    int*   dst32  = (int*)alloc((size_t)EE * 4);
    int*   csr    = (int*)alloc((size_t)EE * 4);
    u16*   Bt     = (u16*)alloc((size_t)8 * WMAT * 2);       // 8 MB
    int*   cnt    = (int*)alloc(64);                          // cnt[0..3], tcount at [8]
    int*   tmap   = (int*)alloc(1040 * 4);
    // NOTE (round-4 bug): a dedicated 512 KB `list` alloc pushed base usage past the
    // tier-0 margin (slack 64 KB) and silently demoted to tier 1 -> new kernels never
    // ran. Fix: alias list onto dst32, which is dead after scatter_kernel.
    int*   list   = dst32;

    size_t rem = (ws_size > off) ? ws_size - off : 0;
    int tier;
    if      (rem >= 9 * MB32 + 65536) tier = 0;
    else if (rem >= 7 * MB32 + 65536) tier = 1;
    else if (rem >= 6 * MB32 + 65536) tier = 2;
    else if (rem >= 5 * MB32 + 65536) tier = 3;
    else if (rem >= 4 * MB32 + 65536) tier = 4;
    else                              tier = 5;

    u16 *xb = nullptr, *h1 = nullptr, *aggr1 = nullptr, *aggr0 = nullptr;
    if (tier <= 2) {
        xb = (u16*)alloc(MB32);
        h1 = (u16*)alloc(4 * MB32);
        aggr1 = (u16*)alloc((tier == 0 ? 4 : tier == 1 ? 2 : 1) * MB32);
        aggr0 = aggr1;                      // aggr0 dead after fused L0; aliases aggr1[0]
    } else if (tier == 3) {
        aggr0 = (u16*)alloc(MB32);
        h1 = (u16*)alloc(4 * MB32);
        aggr1 = aggr0;
    } else if (tier == 4) {
        aggr0 = (u16*)alloc(MB32);
        xb = (u16*)alloc(MB32);
        h1 = (u16*)alloc(MB32);
        aggr1 = (u16*)alloc(MB32);
    } else {
        aggr0 = (u16*)alloc(MB32);
        h1 = (u16*)alloc(MB32);
        aggr1 = (u16*)alloc(MB32);
    }

    int* bsum = flags + 16;
    int* boff = flags + 64;

    hipMemsetAsync(deg, 0, (size_t)NN * 4, stream);

    detect_kernel<<<1, 64, 0, stream>>>(ei, flags);
    edges_kernel<<<EE / 256, 256, 0, stream>>>(ei, flags, src32, dst32);
    transpose_kernel<<<16 * 256, 256, 0, stream>>>(Wl, Wr, Bt);
    if (xb != nullptr)
        gateconv_kernel<<<NN / 4, 256, 0, stream>>>(x, gW, gb, wg, xb);
    else
        gate_kernel<<<NN / 4, 256, 0, stream>>>(x, gW, gb, wg);
    deg_kernel<<<EE / 256, 256, 0, stream>>>(dst32, deg);
    scan1_kernel<<<32, 1024, 0, stream>>>(deg, start, invd, bsum);
    scan2_kernel<<<1, 64, 0, stream>>>(bsum, boff);
    scan3_kernel<<<NN / 256, 256, 0, stream>>>(start, cursor, boff);
    scatter_kernel<<<EE / 256, 256, 0, stream>>>(src32, dst32, cursor, csr);
    if (tier == 0) {
        // dst32 is dead from here on; its storage now backs `list`.
        hipMemsetAsync(cnt, 0, 64, stream);
        compact_kernel<<<NN / 256, 256, 0, stream>>>(wg, cnt, list);
        tilemap_kernel<<<1, 64, 0, stream>>>(cnt, tmap, cnt + 8);
    }

    if (tier == 0) {
        // -------- bf16 path: L0 = B-direct dense GEMM; L1 = compacted gather-GEMM --------
        aggr_kernel<false><<<8192, 256, 0, stream>>>(xb, aggr0, start, deg, csr, invd,
                                                     nullptr, 0, 0);
        gemm_bd_kernel<<<256 * 16, 256, 0, stream>>>(aggr0, xb, Bt, bl, h1);
        hipMemsetAsync(outp, 0, (size_t)NN * DD * 4, stream);
        aggr2_kernel<<<8192, 256, 0, stream>>>(h1, aggr1, start, deg, csr, invd, wg);
        gemm_gather_kernel<<<520 * 4, 256, 0, stream>>>(
            aggr1, h1, Bt + WMAT, bl + 512, outp, wg, list, cnt, tmap, cnt + 8);
    } else if (tier <= 2) {
        aggr_kernel<false><<<8192, 256, 0, stream>>>(xb, aggr0, start, deg, csr, invd,
                                                     nullptr, 0, 0);
        gemm_kernel<false><<<256 * 16, 256, 0, stream>>>(
            aggr0, xb, nullptr, 0, Bt, 2 * WMAT, bl, 1024,
            h1, STR, nullptr, wg, 0, 0, 16);
        if (tier == 1) {
            hipMemsetAsync(outp, 0, (size_t)NN * DD * 4, stream);
            for (int p = 0; p < 2; ++p) {
                aggr_kernel<false><<<2 * 8192, 256, 0, stream>>>(
                    h1 + (size_t)2 * p * STR, aggr1, start, deg, csr, invd, wg, 2 * p, STR);
                gemm_kernel<false><<<256 * 8, 256, 0, stream>>>(
                    aggr1, h1 + (size_t)2 * p * STR, nullptr, STR,
                    Bt + WMAT + (size_t)2 * p * 2 * WMAT, 2 * WMAT,
                    bl + 512 + 2 * p * 1024, 1024,
                    nullptr, 0, outp, wg, 3, 2 * p, 8);
            }
        } else {
            for (int e = 0; e < 4; ++e) {
                aggr_kernel<false><<<8192, 256, 0, stream>>>(
                    h1 + (size_t)e * STR, aggr1, start, deg, csr, invd, wg, e, 0);
                gemm_kernel<false><<<256 * 4, 256, 0, stream>>>(
                    aggr1, h1 + (size_t)e * STR, nullptr, 0,
                    Bt + (size_t)(e * 2 + 1) * WMAT, 0, bl + (e * 2 + 1) * 512, 0,
                    nullptr, 0, outp, wg, (e == 0) ? 1 : 2, e, 4);
            }
        }
    } else if (tier == 3) {
        aggr_kernel<true><<<8192, 256, 0, stream>>>(x, aggr0, start, deg, csr, invd,
                                                    nullptr, 0, 0);
        gemm_kernel<true><<<256 * 16, 256, 0, stream>>>(
            aggr0, nullptr, x, 0, Bt, 2 * WMAT, bl, 1024,
            h1, STR, nullptr, wg, 0, 0, 16);
        for (int e = 0; e < 4; ++e) {
            aggr_kernel<false><<<8192, 256, 0, stream>>>(
                h1 + (size_t)e * STR, aggr1, start, deg, csr, invd, wg, e, 0);
            gemm_kernel<false><<<256 * 4, 256, 0, stream>>>(
                aggr1, h1 + (size_t)e * STR, nullptr, 0,
                Bt + (size_t)(e * 2 + 1) * WMAT, 0, bl + (e * 2 + 1) * 512, 0,
                nullptr, 0, outp, wg, (e == 0) ? 1 : 2, e, 4);
        }
    } else {
        if (tier == 4) {
            aggr_kernel<false><<<8192, 256, 0, stream>>>(xb, aggr0, start, deg, csr, invd,
                                                         nullptr, 0, 0);
        } else {
            aggr_kernel<true><<<8192, 256, 0, stream>>>(x, aggr0, start, deg, csr, invd,
                                                        nullptr, 0, 0);
        }
        for (int e = 0; e < 4; ++e) {
            const u16* BtL0 = Bt + (size_t)(e * 2 + 0) * WMAT;
            const u16* BtL1 = Bt + (size_t)(e * 2 + 1) * WMAT;
            const float* b0 = bl + (e * 2 + 0) * 512;
            const float* b1 = bl + (e * 2 + 1) * 512;
            if (tier == 4)
                gemm_kernel<false><<<256 * 4, 256, 0, stream>>>(
                    aggr0, xb, nullptr, 0, BtL0, 0, b0, 0, h1, 0, nullptr, wg, 0, e, 4);
            else
                gemm_kernel<true><<<256 * 4, 256, 0, stream>>>(
                    aggr0, nullptr, x, 0, BtL0, 0, b0, 0, h1, 0, nullptr, wg, 0, e, 4);
            aggr_kernel<false><<<8192, 256, 0, stream>>>(h1, aggr1, start, deg, csr, invd,
                                                         wg, e, 0);
            gemm_kernel<false><<<256 * 4, 256, 0, stream>>>(
                aggr1, h1, nullptr, 0, BtL1, 0, b1, 0, nullptr, 0, outp, wg,
                (e == 0) ? 1 : 2, e, 4);
        }
    }
}

// Round 6
// 835.416 us; speedup vs baseline: 1.0113x; 1.0099x over previous
//
#include <hip/hip_runtime.h>

typedef unsigned short u16;
typedef unsigned int u32;
typedef u16 u16x8 __attribute__((ext_vector_type(8)));
typedef short s16x8 __attribute__((ext_vector_type(8)));
typedef float f32x4 __attribute__((ext_vector_type(4)));

#define NN 32768
#define EE 262144
#define DD 512
#define WMAT (512 * 1024)   // elements per Bt matrix

__device__ __forceinline__ float b2f(u16 u) {
    return __uint_as_float(((u32)u) << 16);
}
__device__ __forceinline__ u16 f2b(float f) {
    u32 u = __float_as_uint(f);
    u32 r = (u + 0x7FFFu + ((u >> 16) & 1u)) >> 16;
    return (u16)r;
}

// -------- edge-index width detection: int64 (high words zero) vs int32 ------------------
__global__ void detect_kernel(const u32* __restrict__ ei, int* __restrict__ flags) {
    if (threadIdx.x == 0) {
        int allzero = 1;
        for (int i = 0; i < 64; ++i)
            if (ei[2 * i + 1] != 0u) allzero = 0;
        flags[0] = allzero;  // 1 => int64 layout
    }
}

__global__ void edges_kernel(const u32* __restrict__ ei, const int* __restrict__ flags,
                             int* __restrict__ s32, int* __restrict__ d32) {
    int t = blockIdx.x * 256 + threadIdx.x;
    u32 s, d;
    if (flags[0]) {  // int64
        s = ei[2 * t];
        d = ei[2 * EE + 2 * t];
    } else {         // int32
        s = ei[t];
        d = ei[EE + t];
    }
    s32[t] = (int)(s & (NN - 1));
    d32[t] = (int)(d & (NN - 1));
}

// -------- weight transpose+cvt: W[e][l][k][n] fp32 -> Bt[e*2+l][n][k 0..1023] bf16 -------
__global__ void transpose_kernel(const float* __restrict__ Wl, const float* __restrict__ Wr,
                                 u16* __restrict__ Bt) {
    int bid = blockIdx.x;
    int matid = bid >> 8;
    int tile = bid & 255;
    int em = matid >> 1;
    int half = matid & 1;
    const float* W = (half ? Wr : Wl) + (size_t)em * DD * DD;
    u16* out = Bt + (size_t)em * DD * 1024 + half * DD;
    int tk = (tile >> 4) * 32, tn = (tile & 15) * 32;
    __shared__ float s[32][33];
    int t = threadIdx.x;
    int rr = t >> 5, cc = t & 31;
#pragma unroll
    for (int p = 0; p < 4; ++p) {
        int kr = p * 8 + rr;
        s[kr][cc] = W[(size_t)(tk + kr) * DD + tn + cc];
    }
    __syncthreads();
#pragma unroll
    for (int p = 0; p < 4; ++p) {
        int nr = p * 8 + rr;
        out[(size_t)(tn + nr) * 1024 + tk + cc] = f2b(s[cc][nr]);
    }
}

// -------- gating (standalone, tiers without xb) ------------------------------------------
__global__ void gate_kernel(const float* __restrict__ x, const float* __restrict__ gw,
                            const float* __restrict__ gb, float* __restrict__ wg) {
    int node = blockIdx.x * 4 + (threadIdx.x >> 6);
    int l = threadIdx.x & 63;
    const f32x4* xr = (const f32x4*)(x + (size_t)node * DD) + l * 2;
    f32x4 x0 = xr[0], x1 = xr[1];
    float a0 = 0.f, a1 = 0.f, a2 = 0.f, a3 = 0.f;
#pragma unroll
    for (int j = 0; j < 8; ++j) {
        float xf = (j < 4) ? x0[j & 3] : x1[j & 3];
        f32x4 wr = ((const f32x4*)gw)[l * 8 + j];
        a0 += xf * wr[0]; a1 += xf * wr[1]; a2 += xf * wr[2]; a3 += xf * wr[3];
    }
#pragma unroll
    for (int off = 32; off > 0; off >>= 1) {
        a0 += __shfl_down(a0, off, 64);
        a1 += __shfl_down(a1, off, 64);
        a2 += __shfl_down(a2, off, 64);
        a3 += __shfl_down(a3, off, 64);
    }
    if (l == 0) {
        float lg[4] = {a0 + gb[0], a1 + gb[1], a2 + gb[2], a3 + gb[3]};
        float m = fmaxf(fmaxf(lg[0], lg[1]), fmaxf(lg[2], lg[3]));
        float p[4]; float s = 0.f;
#pragma unroll
        for (int e = 0; e < 4; ++e) { p[e] = expf(lg[e] - m); s += p[e]; }
        float inv = 1.f / s;
#pragma unroll
        for (int e = 0; e < 4; ++e) p[e] *= inv;
        int i0 = 0;
#pragma unroll
        for (int e = 1; e < 4; ++e) if (p[e] > p[i0]) i0 = e;
        int i1 = -1;
#pragma unroll
        for (int e = 0; e < 4; ++e) if (e != i0 && (i1 < 0 || p[e] > p[i1])) i1 = e;
        float o[4] = {0.f, 0.f, 0.f, 0.f};
        o[i0] = p[i0]; o[i1] = p[i1];
        float* w = wg + (size_t)node * 4;
        w[0] = o[0]; w[1] = o[1]; w[2] = o[2]; w[3] = o[3];
    }
}

// -------- fused gating + fp32->bf16 convert: one pass over x -----------------------------
__global__ void gateconv_kernel(const float* __restrict__ x, const float* __restrict__ gw,
                                const float* __restrict__ gb, float* __restrict__ wg,
                                u16* __restrict__ xb) {
    int node = blockIdx.x * 4 + (threadIdx.x >> 6);
    int l = threadIdx.x & 63;
    const f32x4* xr = (const f32x4*)(x + (size_t)node * DD) + l * 2;
    f32x4 x0 = xr[0], x1 = xr[1];
    u16x8 o8;
    o8[0] = f2b(x0[0]); o8[1] = f2b(x0[1]); o8[2] = f2b(x0[2]); o8[3] = f2b(x0[3]);
    o8[4] = f2b(x1[0]); o8[5] = f2b(x1[1]); o8[6] = f2b(x1[2]); o8[7] = f2b(x1[3]);
    *((u16x8*)(xb + (size_t)node * DD) + l) = o8;
    float a0 = 0.f, a1 = 0.f, a2 = 0.f, a3 = 0.f;
#pragma unroll
    for (int j = 0; j < 8; ++j) {
        float xf = (j < 4) ? x0[j & 3] : x1[j & 3];
        f32x4 wr = ((const f32x4*)gw)[l * 8 + j];
        a0 += xf * wr[0]; a1 += xf * wr[1]; a2 += xf * wr[2]; a3 += xf * wr[3];
    }
#pragma unroll
    for (int off = 32; off > 0; off >>= 1) {
        a0 += __shfl_down(a0, off, 64);
        a1 += __shfl_down(a1, off, 64);
        a2 += __shfl_down(a2, off, 64);
        a3 += __shfl_down(a3, off, 64);
    }
    if (l == 0) {
        float lg[4] = {a0 + gb[0], a1 + gb[1], a2 + gb[2], a3 + gb[3]};
        float m = fmaxf(fmaxf(lg[0], lg[1]), fmaxf(lg[2], lg[3]));
        float p[4]; float s = 0.f;
#pragma unroll
        for (int e = 0; e < 4; ++e) { p[e] = expf(lg[e] - m); s += p[e]; }
        float inv = 1.f / s;
#pragma unroll
        for (int e = 0; e < 4; ++e) p[e] *= inv;
        int i0 = 0;
#pragma unroll
        for (int e = 1; e < 4; ++e) if (p[e] > p[i0]) i0 = e;
        int i1 = -1;
#pragma unroll
        for (int e = 0; e < 4; ++e) if (e != i0 && (i1 < 0 || p[e] > p[i1])) i1 = e;
        float o[4] = {0.f, 0.f, 0.f, 0.f};
        o[i0] = p[i0]; o[i1] = p[i1];
        float* w = wg + (size_t)node * 4;
        w[0] = o[0]; w[1] = o[1]; w[2] = o[2]; w[3] = o[3];
    }
}

// -------- expert compaction: per-expert active-node lists + positions --------------------
__global__ void compact_kernel(const float* __restrict__ wg, int* __restrict__ cnt,
                               int* __restrict__ list, int* __restrict__ posn) {
    int node = blockIdx.x * 256 + threadIdx.x;
    const float* w = wg + (size_t)node * 4;
#pragma unroll
    for (int e = 0; e < 4; ++e)
        if (w[e] > 0.f) {
            int p = atomicAdd(&cnt[e], 1);
            list[e * NN + p] = node;
            posn[node * 4 + e] = p;
        }
}

// tile map + per-expert compacted base offsets. cnt[0..3]=counts, cnt[4..7]=ebase,
// cnt[8]=tcount. Total compacted rows = exactly 2*NN (top-2) -> <= 516 tiles.
__global__ void tilemap_kernel(int* __restrict__ cnt, int* __restrict__ tmap) {
    if (threadIdx.x == 0) {
        int T = 0, acc = 0;
        for (int e = 0; e < 4; ++e) {
            cnt[4 + e] = acc;
            int c = cnt[e];
            acc += c;
            int nt = (c + 127) >> 7;
            for (int i = 0; i < nt; ++i) tmap[T++] = (e << 16) | i;
        }
        cnt[8] = T;
    }
}

// -------- CSR build ----------------------------------------------------------------------
__global__ void deg_kernel(const int* __restrict__ dst, int* __restrict__ deg) {
    int t = blockIdx.x * blockDim.x + threadIdx.x;
    if (t < EE) atomicAdd(&deg[dst[t]], 1);
}

__global__ void scan1_kernel(const int* __restrict__ deg, int* __restrict__ start,
                             float* __restrict__ invd, int* __restrict__ bsum) {
    int t = threadIdx.x;
    int idx = blockIdx.x * 1024 + t;
    int v = deg[idx];
    int sc = v;
#pragma unroll
    for (int off = 1; off < 64; off <<= 1) {
        int u = __shfl_up(sc, off, 64);
        if ((t & 63) >= off) sc += u;
    }
    __shared__ int wsum[16], woff[16];
    if ((t & 63) == 63) wsum[t >> 6] = sc;
    __syncthreads();
    if (t == 0) {
        int acc = 0;
        for (int w = 0; w < 16; ++w) { woff[w] = acc; acc += wsum[w]; }
        bsum[blockIdx.x] = acc;
    }
    __syncthreads();
    start[idx] = woff[t >> 6] + sc - v;
    invd[idx] = v > 0 ? 1.0f / (float)v : 0.0f;
}

__global__ void scan2_kernel(int* __restrict__ bsum, int* __restrict__ boff) {
    if (threadIdx.x == 0) {
        int acc = 0;
        for (int b = 0; b < 32; ++b) { boff[b] = acc; acc += bsum[b]; }
    }
}

__global__ void scan3_kernel(int* __restrict__ start, int* __restrict__ cursor,
                             const int* __restrict__ boff) {
    int idx = blockIdx.x * 256 + threadIdx.x;
    int s = start[idx] + boff[idx >> 10];
    start[idx] = s;
    cursor[idx] = s;
}

__global__ void scatter_kernel(const int* __restrict__ src, const int* __restrict__ dst,
                               int* __restrict__ cursor, int* __restrict__ csr) {
    int t = blockIdx.x * blockDim.x + threadIdx.x;
    if (t < EE) {
        int d = dst[t];
        int pos = atomicAdd(&cursor[d], 1);
        csr[pos] = src[t];
    }
}

// -------- mean aggregation over CSR; multi-expert: grid = nExp*8192 blocks ---------------
template <bool F32IN>
__global__ void aggr_kernel(const void* __restrict__ hv, u16* __restrict__ outB,
                            const int* __restrict__ start, const int* __restrict__ deg,
                            const int* __restrict__ csr, const float* __restrict__ invd,
                            const float* __restrict__ wg, int eBase, size_t stride) {
    int eo = blockIdx.x >> 13;
    int node = ((blockIdx.x & 8191) << 2) + (threadIdx.x >> 6);
    int expert = eBase + eo;
    if (wg != nullptr && wg[(size_t)node * 4 + expert] == 0.f) return;
    int l = threadIdx.x & 63;
    int s0 = start[node];
    int dg = deg[node];
    u16* out = outB + (size_t)eo * stride;
    const u16* hB = (const u16*)hv + (size_t)eo * stride;
    const float* hF = (const float*)hv + (size_t)eo * stride;
    float a[8] = {0.f, 0.f, 0.f, 0.f, 0.f, 0.f, 0.f, 0.f};

    for (int base = 0; base < dg; base += 64) {
        int cnt = dg - base;
        if (cnt > 64) cnt = 64;
        int vidx = 0;
        if (l < cnt) vidx = csr[s0 + base + l];
        int q = 0;
        if (!F32IN) {
            for (; q + 8 <= cnt; q += 8) {
                int j0 = __shfl(vidx, q, 64);
                int j1 = __shfl(vidx, q + 1, 64);
                int j2 = __shfl(vidx, q + 2, 64);
                int j3 = __shfl(vidx, q + 3, 64);
                int j4 = __shfl(vidx, q + 4, 64);
                int j5 = __shfl(vidx, q + 5, 64);
                int j6 = __shfl(vidx, q + 6, 64);
                int j7 = __shfl(vidx, q + 7, 64);
                u16x8 v0 = *((const u16x8*)(hB + (size_t)j0 * DD) + l);
                u16x8 v1 = *((const u16x8*)(hB + (size_t)j1 * DD) + l);
                u16x8 v2 = *((const u16x8*)(hB + (size_t)j2 * DD) + l);
                u16x8 v3 = *((const u16x8*)(hB + (size_t)j3 * DD) + l);
                u16x8 v4 = *((const u16x8*)(hB + (size_t)j4 * DD) + l);
                u16x8 v5 = *((const u16x8*)(hB + (size_t)j5 * DD) + l);
                u16x8 v6 = *((const u16x8*)(hB + (size_t)j6 * DD) + l);
                u16x8 v7 = *((const u16x8*)(hB + (size_t)j7 * DD) + l);
#pragma unroll
                for (int q2 = 0; q2 < 8; ++q2)
                    a[q2] += ((b2f(v0[q2]) + b2f(v1[q2])) + (b2f(v2[q2]) + b2f(v3[q2]))) +
                             ((b2f(v4[q2]) + b2f(v5[q2])) + (b2f(v6[q2]) + b2f(v7[q2])));
            }
        }
        for (; q + 4 <= cnt; q += 4) {
            int j0 = __shfl(vidx, q, 64);
            int j1 = __shfl(vidx, q + 1, 64);
            int j2 = __shfl(vidx, q + 2, 64);
            int j3 = __shfl(vidx, q + 3, 64);
            if (F32IN) {
                const f32x4* r0 = (const f32x4*)(hF + (size_t)j0 * DD) + l * 2;
                const f32x4* r1 = (const f32x4*)(hF + (size_t)j1 * DD) + l * 2;
                const f32x4* r2 = (const f32x4*)(hF + (size_t)j2 * DD) + l * 2;
                const f32x4* r3 = (const f32x4*)(hF + (size_t)j3 * DD) + l * 2;
                f32x4 u0 = r0[0], u1 = r0[1];
                f32x4 u2 = r1[0], u3 = r1[1];
                f32x4 u4 = r2[0], u5 = r2[1];
                f32x4 u6 = r3[0], u7 = r3[1];
#pragma unroll
                for (int q2 = 0; q2 < 4; ++q2) {
                    a[q2] += (u0[q2] + u2[q2]) + (u4[q2] + u6[q2]);
                    a[4 + q2] += (u1[q2] + u3[q2]) + (u5[q2] + u7[q2]);
                }
            } else {
                u16x8 v0 = *((const u16x8*)(hB + (size_t)j0 * DD) + l);
                u16x8 v1 = *((const u16x8*)(hB + (size_t)j1 * DD) + l);
                u16x8 v2 = *((const u16x8*)(hB + (size_t)j2 * DD) + l);
                u16x8 v3 = *((const u16x8*)(hB + (size_t)j3 * DD) + l);
#pragma unroll
                for (int q2 = 0; q2 < 8; ++q2)
                    a[q2] += (b2f(v0[q2]) + b2f(v1[q2])) + (b2f(v2[q2]) + b2f(v3[q2]));
            }
        }
        for (; q < cnt; ++q) {
            int j = __shfl(vidx, q, 64);
            if (F32IN) {
                const f32x4* r = (const f32x4*)(hF + (size_t)j * DD) + l * 2;
                f32x4 u0 = r[0], u1 = r[1];
#pragma unroll
                for (int q2 = 0; q2 < 4; ++q2) { a[q2] += u0[q2]; a[4 + q2] += u1[q2]; }
            } else {
                u16x8 v = *((const u16x8*)(hB + (size_t)j * DD) + l);
#pragma unroll
                for (int q2 = 0; q2 < 8; ++q2) a[q2] += b2f(v[q2]);
            }
        }
    }
    float sc = invd[node];
    u16x8 o;
#pragma unroll
    for (int q2 = 0; q2 < 8; ++q2) o[q2] = f2b(a[q2] * sc);
    *((u16x8*)(out + (size_t)node * DD) + l) = o;
}

// -------- dual-expert gated aggregation -> COMPACTED output ------------------------------
// One wave = one node, both active experts; one csr index stream serves both; results
// written at compacted row ebase[e] + posn[node][e] so aggr1c is only 2*NN rows (64 MB).
__global__ void aggr2_kernel(const u16* __restrict__ h, u16* __restrict__ outC,
                             const int* __restrict__ start, const int* __restrict__ deg,
                             const int* __restrict__ csr, const float* __restrict__ invd,
                             const float* __restrict__ wg, const int* __restrict__ posn,
                             const int* __restrict__ cntb) {
    const int node = (blockIdx.x << 2) + (threadIdx.x >> 6);
    const int l = threadIdx.x & 63;
    const float* w = wg + (size_t)node * 4;
    int e0 = -1, e1 = -1;
#pragma unroll
    for (int e = 0; e < 4; ++e) {
        if (w[e] > 0.f) { if (e0 < 0) e0 = e; else e1 = e; }
    }
    if (e0 < 0) return;
    const int dual = (e1 >= 0);
    if (!dual) e1 = e0;
    const size_t STRE = (size_t)NN * DD;
    const u16* hA = h + (size_t)e0 * STRE;
    const u16* hC = h + (size_t)e1 * STRE;
    const int g0 = cntb[4 + e0] + posn[node * 4 + e0];
    const int g1 = cntb[4 + e1] + posn[node * 4 + e1];
    const int s0 = start[node];
    const int dg = deg[node];
    float a0[8] = {0.f, 0.f, 0.f, 0.f, 0.f, 0.f, 0.f, 0.f};
    float a1[8] = {0.f, 0.f, 0.f, 0.f, 0.f, 0.f, 0.f, 0.f};

    for (int base = 0; base < dg; base += 64) {
        int cnt = dg - base;
        if (cnt > 64) cnt = 64;
        int vidx = 0;
        if (l < cnt) vidx = csr[s0 + base + l];
        int q = 0;
        for (; q + 4 <= cnt; q += 4) {
            int j0 = __shfl(vidx, q, 64);
            int j1 = __shfl(vidx, q + 1, 64);
            int j2 = __shfl(vidx, q + 2, 64);
            int j3 = __shfl(vidx, q + 3, 64);
            u16x8 u0 = *((const u16x8*)(hA + (size_t)j0 * DD) + l);
            u16x8 u1 = *((const u16x8*)(hA + (size_t)j1 * DD) + l);
            u16x8 u2 = *((const u16x8*)(hA + (size_t)j2 * DD) + l);
            u16x8 u3 = *((const u16x8*)(hA + (size_t)j3 * DD) + l);
            u16x8 t0 = *((const u16x8*)(hC + (size_t)j0 * DD) + l);
            u16x8 t1 = *((const u16x8*)(hC + (size_t)j1 * DD) + l);
            u16x8 t2 = *((const u16x8*)(hC + (size_t)j2 * DD) + l);
            u16x8 t3 = *((const u16x8*)(hC + (size_t)j3 * DD) + l);
#pragma unroll
            for (int q2 = 0; q2 < 8; ++q2) {
                a0[q2] += (b2f(u0[q2]) + b2f(u1[q2])) + (b2f(u2[q2]) + b2f(u3[q2]));
                a1[q2] += (b2f(t0[q2]) + b2f(t1[q2])) + (b2f(t2[q2]) + b2f(t3[q2]));
            }
        }
        for (; q < cnt; ++q) {
            int j = __shfl(vidx, q, 64);
            u16x8 u = *((const u16x8*)(hA + (size_t)j * DD) + l);
            u16x8 t = *((const u16x8*)(hC + (size_t)j * DD) + l);
#pragma unroll
            for (int q2 = 0; q2 < 8; ++q2) { a0[q2] += b2f(u[q2]); a1[q2] += b2f(t[q2]); }
        }
    }
    float sc = invd[node];
    u16x8 o0, o1;
#pragma unroll
    for (int q2 = 0; q2 < 8; ++q2) { o0[q2] = f2b(a0[q2] * sc); o1[q2] = f2b(a1[q2] * sc); }
    *((u16x8*)(outC + (size_t)g0 * DD) + l) = o0;
    if (dual)
        *((u16x8*)(outC + (size_t)g1 * DD) + l) = o1;
}

__device__ __forceinline__ void gload16(const void* g, void* l) {
    __builtin_amdgcn_global_load_lds((const __attribute__((address_space(1))) void*)g,
                                     (__attribute__((address_space(3))) void*)l, 16, 0, 0);
}

// -------- legacy fused GEMM (fallback tiers): A and B both staged through LDS ------------
template <bool A2F32>
__global__ void __launch_bounds__(256, 4) gemm_kernel(
    const u16* __restrict__ A1, const u16* __restrict__ A2b, const float* __restrict__ A2f,
    size_t sA, const u16* __restrict__ Bt, size_t sBt,
    const float* __restrict__ bias, size_t sBias,
    u16* __restrict__ Hout, size_t sH, float* __restrict__ Out,
    const float* __restrict__ wg, int mode, int eBase, int ntt) {
    __shared__ u16 lds[A2F32 ? 12288 : 8192];
    u16* ldsA = lds;
    float* ldsF = (float*)lds;
    u16* ldsB = lds + (A2F32 ? 8192 : 4096);
    const int tid = threadIdx.x;
    const int lane = tid & 63;
    const int w = tid >> 6;

    const int bid = blockIdx.x;
    const int xcd = bid & 7;
    const int local = bid >> 3;
    const int mtl = local / ntt;
    const int sub = local - mtl * ntt;
    const int expert = sub >> 2;
    const int wgE = eBase + expert;
    const int m0 = (xcd * 32 + mtl) * 128;
    const int n0 = (sub & 3) * 128;

    const u16* A1p = A1 + (size_t)expert * sA;
    const u16* A2p = A2b + (size_t)expert * sA;
    const u16* Btp = Bt + (size_t)expert * sBt;
    const float* biasp = bias + (size_t)expert * sBias;
    u16* Houtp = Hout + (size_t)expert * sH;

    const int wm = (w >> 1) * 64;
    const int wn = (w & 1) * 64;

    f32x4 acc[4][4];
#pragma unroll
    for (int i = 0; i < 4; ++i)
#pragma unroll
        for (int j = 0; j < 4; ++j) acc[i][j] = (f32x4){0.f, 0.f, 0.f, 0.f};

    const int p0 = tid, p1 = 256 + tid;
    const int r0 = p0 >> 2, c0 = ((p0 & 3) - (r0 >> 1)) & 3;
    const int r1 = p1 >> 2, c1 = ((p1 & 3) - (r1 >> 1)) & 3;
    const int arow = lane & 15;
    const int kc = lane >> 4;

    for (int kb = 0; kb < 32; ++kb) {
        __syncthreads();
        if (!A2F32 || kb < 16) {
            const u16* As = (kb < 16) ? A1p : A2p;
            const int kcol = (kb & 15) * 32;
            gload16(As + (size_t)(m0 + r0) * DD + kcol + c0 * 8, ldsA + p0 * 8);
            gload16(As + (size_t)(m0 + r1) * DD + kcol + c1 * 8, ldsA + p1 * 8);
        } else {
            const float* Af = A2f + (size_t)m0 * DD + (kb - 16) * 32;
#pragma unroll
            for (int q = 0; q < 4; ++q) {
                int p = q * 256 + tid;
                int rr = p >> 3, cpos = p & 7, cc2 = (cpos - rr) & 7;
                gload16(Af + (size_t)rr * DD + cc2 * 4, ldsF + p * 4);
            }
        }
        gload16(Btp + (size_t)(n0 + r0) * 1024 + kb * 32 + c0 * 8, ldsB + p0 * 8);
        gload16(Btp + (size_t)(n0 + r1) * 1024 + kb * 32 + c1 * 8, ldsB + p1 * 8);
        __syncthreads();
        s16x8 af[4], bf[4];
        if (!A2F32 || kb < 16) {
#pragma unroll
            for (int f = 0; f < 4; ++f) {
                int ra = wm + f * 16 + arow;
                int pa = (kc + (ra >> 1)) & 3;
                af[f] = *(const s16x8*)(ldsA + (ra * 4 + pa) * 8);
            }
        } else {
#pragma unroll
            for (int f = 0; f < 4; ++f) {
                int ra = wm + f * 16 + arow;
                int plo = ra * 8 + ((2 * kc + ra) & 7);
                int phi = ra * 8 + ((2 * kc + 1 + ra) & 7);
                f32x4 lo = *(const f32x4*)(ldsF + plo * 4);
                f32x4 hi = *(const f32x4*)(ldsF + phi * 4);
                s16x8 t;
                t[0] = (short)f2b(lo[0]); t[1] = (short)f2b(lo[1]);
                t[2] = (short)f2b(lo[2]); t[3] = (short)f2b(lo[3]);
                t[4] = (short)f2b(hi[0]); t[5] = (short)f2b(hi[1]);
                t[6] = (short)f2b(hi[2]); t[7] = (short)f2b(hi[3]);
                af[f] = t;
            }
        }
#pragma unroll
        for (int f = 0; f < 4; ++f) {
            int rb = wn + f * 16 + arow;
            int pb = (kc + (rb >> 1)) & 3;
            bf[f] = *(const s16x8*)(ldsB + (rb * 4 + pb) * 8);
        }
#pragma unroll
        for (int i = 0; i < 4; ++i)
#pragma unroll
            for (int j = 0; j < 4; ++j)
                acc[i][j] = __builtin_amdgcn_mfma_f32_16x16x32_bf16(af[i], bf[j], acc[i][j], 0, 0, 0);
    }

    const int colq = lane & 15;
    const int rq = lane >> 4;
#pragma unroll
    for (int i = 0; i < 4; ++i) {
#pragma unroll
        for (int j = 0; j < 4; ++j) {
            int col = n0 + wn + j * 16 + colq;
            float bv = biasp[col];
#pragma unroll
            for (int r = 0; r < 4; ++r) {
                int row = m0 + wm + i * 16 + rq * 4 + r;
                float v = fmaxf(acc[i][j][r] + bv, 0.f);
                size_t idx = (size_t)row * DD + col;
                if (mode == 0) {
                    Houtp[idx] = f2b(v);
                } else {
                    float wv = wg[(size_t)row * 4 + wgE];
                    if (mode == 1) {
                        Out[idx] = wv * v;
                    } else if (mode == 2) {
                        if (wv > 0.f) Out[idx] += wv * v;
                    } else {
                        if (wv > 0.f) unsafeAtomicAdd(&Out[idx], wv * v);
                    }
                }
            }
        }
    }
}

// -------- L0 GEMM, B direct-from-global: h1[e] = relu([aggr0|xb] @ Bt_e^T + b_e) ---------
// LDS holds only the A-panel (8 KB/K-step); B-fragments vector-loaded straight to regs
// (B is L2-resident, 1 MB/expert). Halves LDS traffic per K-step (48->24 KB).
__global__ void __launch_bounds__(256, 4) gemm_bd_kernel(
    const u16* __restrict__ A1, const u16* __restrict__ A2,
    const u16* __restrict__ Bt, const float* __restrict__ bias,
    u16* __restrict__ Hout) {
    __shared__ u16 lds[4096];  // A only: 128 rows x 32 k
    const int tid = threadIdx.x;
    const int lane = tid & 63;
    const int w = tid >> 6;

    const int bid = blockIdx.x;
    const int xcd = bid & 7;
    const int local = bid >> 3;
    const int mtl = local >> 4;
    const int sub = local & 15;
    const int expert = sub >> 2;
    const int m0 = (xcd * 32 + mtl) * 128;
    const int n0 = (sub & 3) * 128;

    const u16* Btp = Bt + (size_t)expert * (2 * WMAT);
    const float* biasp = bias + (size_t)expert * 1024;
    u16* Houtp = Hout + (size_t)expert * ((size_t)NN * DD);

    const int wm = (w >> 1) * 64;
    const int wn = (w & 1) * 64;

    f32x4 acc[4][4];
#pragma unroll
    for (int i = 0; i < 4; ++i)
#pragma unroll
        for (int j = 0; j < 4; ++j) acc[i][j] = (f32x4){0.f, 0.f, 0.f, 0.f};

    const int p0 = tid, p1 = 256 + tid;
    const int r0 = p0 >> 2, c0 = ((p0 & 3) - (r0 >> 1)) & 3;
    const int r1 = p1 >> 2, c1 = ((p1 & 3) - (r1 >> 1)) & 3;
    const int arow = lane & 15;
    const int kc = lane >> 4;

    for (int kb = 0; kb < 32; ++kb) {
        __syncthreads();
        const u16* As = (kb < 16) ? A1 : A2;
        const int kcol = (kb & 15) * 32;
        gload16(As + (size_t)(m0 + r0) * DD + kcol + c0 * 8, lds + p0 * 8);
        gload16(As + (size_t)(m0 + r1) * DD + kcol + c1 * 8, lds + p1 * 8);
        s16x8 bf[4];
#pragma unroll
        for (int f = 0; f < 4; ++f) {
            int rb = n0 + wn + f * 16 + arow;
            bf[f] = *(const s16x8*)(Btp + (size_t)rb * 1024 + kb * 32 + kc * 8);
        }
        __syncthreads();
        s16x8 af[4];
#pragma unroll
        for (int f = 0; f < 4; ++f) {
            int ra = wm + f * 16 + arow;
            int pa = (kc + (ra >> 1)) & 3;
            af[f] = *(const s16x8*)(lds + (ra * 4 + pa) * 8);
        }
#pragma unroll
        for (int i = 0; i < 4; ++i)
#pragma unroll
            for (int j = 0; j < 4; ++j)
                acc[i][j] = __builtin_amdgcn_mfma_f32_16x16x32_bf16(af[i], bf[j], acc[i][j], 0, 0, 0);
    }

    const int colq = lane & 15;
    const int rq = lane >> 4;
#pragma unroll
    for (int i = 0; i < 4; ++i) {
#pragma unroll
        for (int j = 0; j < 4; ++j) {
            int col = n0 + wn + j * 16 + colq;
            float bv = biasp[col];
#pragma unroll
            for (int r = 0; r < 4; ++r) {
                int row = m0 + wm + i * 16 + rq * 4 + r;
                float v = fmaxf(acc[i][j][r] + bv, 0.f);
                Houtp[(size_t)row * DD + col] = f2b(v);
            }
        }
    }
}

// -------- L1 GEMM over compacted rows: out[node] += wv * relu([aggr1c|h1]@Bt^T + b) ------
// A1 = compacted aggregation (LINEAR rows, ebase[e]+base+r); A2 = h1 gathered via list;
// exactly the top-2 rows (2*NN) -> half the dense work. Padding rows clamped + masked.
__global__ void __launch_bounds__(256, 4) gemm_gather_kernel(
    const u16* __restrict__ A1c, const u16* __restrict__ A2,
    const u16* __restrict__ Bt, const float* __restrict__ bias,
    float* __restrict__ Out, const float* __restrict__ wg,
    const int* __restrict__ list, const int* __restrict__ cntb,
    const int* __restrict__ tmap) {
    const int t = blockIdx.x >> 2;
    if (t >= cntb[8]) return;
    const u32 mi = (u32)tmap[t];
    const int e = mi >> 16;
    const int mt = mi & 0xffff;
    const int cntE = cntb[e];
    const int eb = cntb[4 + e];
    const int base = mt << 7;
    const int n0 = (blockIdx.x & 3) * 128;

    __shared__ u16 lds[8192];
    u16* ldsA = lds;
    u16* ldsB = lds + 4096;
    const int tid = threadIdx.x;
    const int lane = tid & 63;
    const int w = tid >> 6;

    const size_t STRE = (size_t)NN * DD;
    const u16* A2p = A2 + (size_t)e * STRE;
    const u16* Btp = Bt + (size_t)e * (2 * WMAT);
    const float* biasp = bias + (size_t)e * 1024;
    const int* listE = list + e * NN;

    const int wm = (w >> 1) * 64;
    const int wn = (w & 1) * 64;

    f32x4 acc[4][4];
#pragma unroll
    for (int i = 0; i < 4; ++i)
#pragma unroll
        for (int j = 0; j < 4; ++j) acc[i][j] = (f32x4){0.f, 0.f, 0.f, 0.f};

    const int p0 = tid, p1 = 256 + tid;
    const int r0 = p0 >> 2, c0 = ((p0 & 3) - (r0 >> 1)) & 3;
    const int r1 = p1 >> 2, c1 = ((p1 & 3) - (r1 >> 1)) & 3;
    int g0 = eb + base + r0; if (g0 > 2 * NN - 1) g0 = 2 * NN - 1;
    int g1 = eb + base + r1; if (g1 > 2 * NN - 1) g1 = 2 * NN - 1;
    int q0 = base + r0; if (q0 >= cntE) q0 = cntE - 1;
    int q1 = base + r1; if (q1 >= cntE) q1 = cntE - 1;
    const int gr0 = listE[q0];
    const int gr1 = listE[q1];
    const int arow = lane & 15;
    const int kc = lane >> 4;

    for (int kb = 0; kb < 32; ++kb) {
        __syncthreads();
        if (kb < 16) {
            const int kcol = kb * 32;
            gload16(A1c + (size_t)g0 * DD + kcol + c0 * 8, ldsA + p0 * 8);
            gload16(A1c + (size_t)g1 * DD + kcol + c1 * 8, ldsA + p1 * 8);
        } else {
            const int kcol = (kb - 16) * 32;
            gload16(A2p + (size_t)gr0 * DD + kcol + c0 * 8, ldsA + p0 * 8);
            gload16(A2p + (size_t)gr1 * DD + kcol + c1 * 8, ldsA + p1 * 8);
        }
        gload16(Btp + (size_t)(n0 + r0) * 1024 + kb * 32 + c0 * 8, ldsB + p0 * 8);
        gload16(Btp + (size_t)(n0 + r1) * 1024 + kb * 32 + c1 * 8, ldsB + p1 * 8);
        __syncthreads();
        s16x8 af[4], bf[4];
#pragma unroll
        for (int f = 0; f < 4; ++f) {
            int ra = wm + f * 16 + arow;
            int pa = (kc + (ra >> 1)) & 3;
            af[f] = *(const s16x8*)(ldsA + (ra * 4 + pa) * 8);
        }
#pragma unroll
        for (int f = 0; f < 4; ++f) {
            int rb = wn + f * 16 + arow;
            int pb = (kc + (rb >> 1)) & 3;
            bf[f] = *(const s16x8*)(ldsB + (rb * 4 + pb) * 8);
        }
#pragma unroll
        for (int i = 0; i < 4; ++i)
#pragma unroll
            for (int j = 0; j < 4; ++j)
                acc[i][j] = __builtin_amdgcn_mfma_f32_16x16x32_bf16(af[i], bf[j], acc[i][j], 0, 0, 0);
    }

    const int colq = lane & 15;
    const int rq = lane >> 4;
#pragma unroll
    for (int i = 0; i < 4; ++i) {
        int nd[4]; float wv4[4]; bool val[4];
#pragma unroll
        for (int r = 0; r < 4; ++r) {
            int rowl = base + wm + i * 16 + rq * 4 + r;
            val[r] = rowl < cntE;
            int qq = val[r] ? rowl : 0;
            nd[r] = listE[qq];
            wv4[r] = wg[(size_t)nd[r] * 4 + e];
        }
#pragma unroll
        for (int j = 0; j < 4; ++j) {
            int col = n0 + wn + j * 16 + colq;
            float bv = biasp[col];
#pragma unroll
            for (int r = 0; r < 4; ++r) {
                if (val[r]) {
                    float v = fmaxf(acc[i][j][r] + bv, 0.f);
                    unsafeAtomicAdd(&Out[(size_t)nd[r] * DD + col], wv4[r] * v);
                }
            }
        }
    }
}

extern "C" void kernel_launch(void* const* d_in, const int* in_sizes, int n_in,
                              void* d_out, int out_size, void* d_ws, size_t ws_size,
                              hipStream_t stream) {
    const float* x  = (const float*)d_in[0];
    const float* gW = (const float*)d_in[1];
    const float* gb = (const float*)d_in[2];
    const float* Wl = (const float*)d_in[3];
    const float* bl = (const float*)d_in[4];
    const float* Wr = (const float*)d_in[5];
    const u32*   ei = (const u32*)d_in[6];
    float* outp = (float*)d_out;

    char* ws = (char*)d_ws;
    size_t off = 0;
    auto alloc = [&](size_t bytes) -> void* {
        void* p = ws + off;
        off += (bytes + 255) & ~(size_t)255;
        return p;
    };
    const size_t MB32 = (size_t)NN * DD * 2;
    const size_t STR = (size_t)NN * DD;      // per-expert element stride
    int*   flags  = (int*)alloc(512);
    float* wg     = (float*)alloc((size_t)NN * 4 * 4);
    int*   deg    = (int*)alloc((size_t)NN * 4);
    int*   start  = (int*)alloc((size_t)NN * 4);
    int*   cursor = (int*)alloc((size_t)NN * 4);
    float* invd   = (float*)alloc((size_t)NN * 4);
    int*   src32  = (int*)alloc((size_t)EE * 4);
    int*   dst32  = (int*)alloc((size_t)EE * 4);
    int*   csr    = (int*)alloc((size_t)EE * 4);
    u16*   Bt     = (u16*)alloc((size_t)8 * WMAT * 2);       // 8 MB
    int*   cnt    = (int*)alloc(64);                          // [0..3] cnt, [4..7] ebase, [8] tcount
    int*   tmap   = (int*)alloc(1040 * 4);
    // Aliases (dead after scatter_kernel): list <- dst32 (512 KB of 1 MB),
    // posn <- src32 (512 KB of 1 MB). Keeps base footprint == validated tier-1 footprint.
    int*   list   = dst32;
    int*   posn   = src32;

    size_t rem = (ws_size > off) ? ws_size - off : 0;
    // WS accounting (round-5 post-mortem): ws_size ~= 256 MiB on this harness -> the old
    // 288 MB tier 0 NEVER ran; every round actually executed the 224 MB tier-1 path.
    // New tier 0 = compacted-fused path sized to EXACTLY the validated 224 MB budget:
    //   xb (32) + h1 (128) + aggr1c (64, compacted 2*NN rows; aggr0 aliases its head).
    int tier;
    if      (rem >= 7 * MB32 + 65536) tier = 0;   // compact-fused (224 MB)
    else if (rem >= 6 * MB32 + 65536) tier = 2;   // bf16 fused L0, sequential L1 (192 MB)
    else if (rem >= 5 * MB32 + 65536) tier = 3;   // fp32-staged fused L0 (160 MB)
    else if (rem >= 4 * MB32 + 65536) tier = 4;   // sequential (128 MB)
    else                              tier = 5;   // fp32 fallback (96 MB)

    u16 *xb = nullptr, *h1 = nullptr, *aggr1 = nullptr, *aggr0 = nullptr;
    if (tier == 0) {
        xb = (u16*)alloc(MB32);
        h1 = (u16*)alloc(4 * MB32);
        aggr1 = (u16*)alloc(2 * MB32);      // compacted: 2*NN rows
        aggr0 = aggr1;                      // dense L0 aggr (32 MB) aliases head; dead before aggr2
    } else if (tier == 2) {
        xb = (u16*)alloc(MB32);
        h1 = (u16*)alloc(4 * MB32);
        aggr1 = (u16*)alloc(MB32);
        aggr0 = aggr1;
    } else if (tier == 3) {
        aggr0 = (u16*)alloc(MB32);
        h1 = (u16*)alloc(4 * MB32);
        aggr1 = aggr0;
    } else if (tier == 4) {
        aggr0 = (u16*)alloc(MB32);
        xb = (u16*)alloc(MB32);
        h1 = (u16*)alloc(MB32);
        aggr1 = (u16*)alloc(MB32);
    } else {
        aggr0 = (u16*)alloc(MB32);
        h1 = (u16*)alloc(MB32);
        aggr1 = (u16*)alloc(MB32);
    }

    int* bsum = flags + 16;
    int* boff = flags + 64;

    hipMemsetAsync(deg, 0, (size_t)NN * 4, stream);

    detect_kernel<<<1, 64, 0, stream>>>(ei, flags);
    edges_kernel<<<EE / 256, 256, 0, stream>>>(ei, flags, src32, dst32);
    transpose_kernel<<<16 * 256, 256, 0, stream>>>(Wl, Wr, Bt);
    if (xb != nullptr)
        gateconv_kernel<<<NN / 4, 256, 0, stream>>>(x, gW, gb, wg, xb);
    else
        gate_kernel<<<NN / 4, 256, 0, stream>>>(x, gW, gb, wg);
    deg_kernel<<<EE / 256, 256, 0, stream>>>(dst32, deg);
    scan1_kernel<<<32, 1024, 0, stream>>>(deg, start, invd, bsum);
    scan2_kernel<<<1, 64, 0, stream>>>(bsum, boff);
    scan3_kernel<<<NN / 256, 256, 0, stream>>>(start, cursor, boff);
    scatter_kernel<<<EE / 256, 256, 0, stream>>>(src32, dst32, cursor, csr);

    if (tier == 0) {
        // src32/dst32 dead; their storage backs posn/list from here.
        hipMemsetAsync(cnt, 0, 64, stream);
        compact_kernel<<<NN / 256, 256, 0, stream>>>(wg, cnt, list, posn);
        tilemap_kernel<<<1, 64, 0, stream>>>(cnt, tmap);
        // L0: dense aggr + B-direct GEMM
        aggr_kernel<false><<<8192, 256, 0, stream>>>(xb, aggr0, start, deg, csr, invd,
                                                     nullptr, 0, 0);
        gemm_bd_kernel<<<256 * 16, 256, 0, stream>>>(aggr0, xb, Bt, bl, h1);
        hipMemsetAsync(outp, 0, (size_t)NN * DD * 4, stream);
        // L1: dual-expert aggr -> compacted rows; gather-GEMM over exactly top-2 rows
        aggr2_kernel<<<8192, 256, 0, stream>>>(h1, aggr1, start, deg, csr, invd, wg,
                                               posn, cnt);
        gemm_gather_kernel<<<516 * 4, 256, 0, stream>>>(
            aggr1, h1, Bt + WMAT, bl + 512, outp, wg, list, cnt, tmap);
    } else if (tier == 2) {
        aggr_kernel<false><<<8192, 256, 0, stream>>>(xb, aggr0, start, deg, csr, invd,
                                                     nullptr, 0, 0);
        gemm_kernel<false><<<256 * 16, 256, 0, stream>>>(
            aggr0, xb, nullptr, 0, Bt, 2 * WMAT, bl, 1024,
            h1, STR, nullptr, wg, 0, 0, 16);
        for (int e = 0; e < 4; ++e) {
            aggr_kernel<false><<<8192, 256, 0, stream>>>(
                h1 + (size_t)e * STR, aggr1, start, deg, csr, invd, wg, e, 0);
            gemm_kernel<false><<<256 * 4, 256, 0, stream>>>(
                aggr1, h1 + (size_t)e * STR, nullptr, 0,
                Bt + (size_t)(e * 2 + 1) * WMAT, 0, bl + (e * 2 + 1) * 512, 0,
                nullptr, 0, outp, wg, (e == 0) ? 1 : 2, e, 4);
        }
    } else if (tier == 3) {
        aggr_kernel<true><<<8192, 256, 0, stream>>>(x, aggr0, start, deg, csr, invd,
                                                    nullptr, 0, 0);
        gemm_kernel<true><<<256 * 16, 256, 0, stream>>>(
            aggr0, nullptr, x, 0, Bt, 2 * WMAT, bl, 1024,
            h1, STR, nullptr, wg, 0, 0, 16);
        for (int e = 0; e < 4; ++e) {
            aggr_kernel<false><<<8192, 256, 0, stream>>>(
                h1 + (size_t)e * STR, aggr1, start, deg, csr, invd, wg, e, 0);
            gemm_kernel<false><<<256 * 4, 256, 0, stream>>>(
                aggr1, h1 + (size_t)e * STR, nullptr, 0,
                Bt + (size_t)(e * 2 + 1) * WMAT, 0, bl + (e * 2 + 1) * 512, 0,
                nullptr, 0, outp, wg, (e == 0) ? 1 : 2, e, 4);
        }
    } else {
        if (tier == 4) {
            aggr_kernel<false><<<8192, 256, 0, stream>>>(xb, aggr0, start, deg, csr, invd,
                                                         nullptr, 0, 0);
        } else {
            aggr_kernel<true><<<8192, 256, 0, stream>>>(x, aggr0, start, deg, csr, invd,
                                                        nullptr, 0, 0);
        }
        for (int e = 0; e < 4; ++e) {
            const u16* BtL0 = Bt + (size_t)(e * 2 + 0) * WMAT;
            const u16* BtL1 = Bt + (size_t)(e * 2 + 1) * WMAT;
            const float* b0 = bl + (e * 2 + 0) * 512;
            const float* b1 = bl + (e * 2 + 1) * 512;
            if (tier == 4)
                gemm_kernel<false><<<256 * 4, 256, 0, stream>>>(
                    aggr0, xb, nullptr, 0, BtL0, 0, b0, 0, h1, 0, nullptr, wg, 0, e, 4);
            else
                gemm_kernel<true><<<256 * 4, 256, 0, stream>>>(
                    aggr0, nullptr, x, 0, BtL0, 0, b0, 0, h1, 0, nullptr, wg, 0, e, 4);
            aggr_kernel<false><<<8192, 256, 0, stream>>>(h1, aggr1, start, deg, csr, invd,
                                                         wg, e, 0);
            gemm_kernel<false><<<256 * 4, 256, 0, stream>>>(
                aggr1, h1, nullptr, 0, BtL1, 0, b1, 0, nullptr, 0, outp, wg,
                (e == 0) ? 1 : 2, e, 4);
        }
    }
}

// Round 7
// 730.637 us; speedup vs baseline: 1.1563x; 1.1434x over previous
//
#include <hip/hip_runtime.h>

typedef unsigned short u16;
typedef unsigned int u32;
typedef u16 u16x8 __attribute__((ext_vector_type(8)));
typedef short s16x8 __attribute__((ext_vector_type(8)));
typedef float f32x4 __attribute__((ext_vector_type(4)));

#define NN 32768
#define EE 262144
#define DD 512
#define WMAT (512 * 1024)   // elements per Bt matrix

__device__ __forceinline__ float b2f(u16 u) {
    return __uint_as_float(((u32)u) << 16);
}
__device__ __forceinline__ u16 f2b(float f) {
    u32 u = __float_as_uint(f);
    u32 r = (u + 0x7FFFu + ((u >> 16) & 1u)) >> 16;
    return (u16)r;
}

// -------- edge-index width detection: int64 (high words zero) vs int32 ------------------
__global__ void detect_kernel(const u32* __restrict__ ei, int* __restrict__ flags) {
    if (threadIdx.x == 0) {
        int allzero = 1;
        for (int i = 0; i < 64; ++i)
            if (ei[2 * i + 1] != 0u) allzero = 0;
        flags[0] = allzero;  // 1 => int64 layout
    }
}

__global__ void edges_kernel(const u32* __restrict__ ei, const int* __restrict__ flags,
                             int* __restrict__ s32, int* __restrict__ d32) {
    int t = blockIdx.x * 256 + threadIdx.x;
    u32 s, d;
    if (flags[0]) {  // int64
        s = ei[2 * t];
        d = ei[2 * EE + 2 * t];
    } else {         // int32
        s = ei[t];
        d = ei[EE + t];
    }
    s32[t] = (int)(s & (NN - 1));
    d32[t] = (int)(d & (NN - 1));
}

// -------- weight transpose+cvt: W[e][l][k][n] fp32 -> Bt[e*2+l][n][k 0..1023] bf16 -------
__global__ void transpose_kernel(const float* __restrict__ Wl, const float* __restrict__ Wr,
                                 u16* __restrict__ Bt) {
    int bid = blockIdx.x;
    int matid = bid >> 8;
    int tile = bid & 255;
    int em = matid >> 1;
    int half = matid & 1;
    const float* W = (half ? Wr : Wl) + (size_t)em * DD * DD;
    u16* out = Bt + (size_t)em * DD * 1024 + half * DD;
    int tk = (tile >> 4) * 32, tn = (tile & 15) * 32;
    __shared__ float s[32][33];
    int t = threadIdx.x;
    int rr = t >> 5, cc = t & 31;
#pragma unroll
    for (int p = 0; p < 4; ++p) {
        int kr = p * 8 + rr;
        s[kr][cc] = W[(size_t)(tk + kr) * DD + tn + cc];
    }
    __syncthreads();
#pragma unroll
    for (int p = 0; p < 4; ++p) {
        int nr = p * 8 + rr;
        out[(size_t)(tn + nr) * 1024 + tk + cc] = f2b(s[cc][nr]);
    }
}

// -------- gating (standalone, tiers without xb) ------------------------------------------
__global__ void gate_kernel(const float* __restrict__ x, const float* __restrict__ gw,
                            const float* __restrict__ gb, float* __restrict__ wg) {
    int node = blockIdx.x * 4 + (threadIdx.x >> 6);
    int l = threadIdx.x & 63;
    const f32x4* xr = (const f32x4*)(x + (size_t)node * DD) + l * 2;
    f32x4 x0 = xr[0], x1 = xr[1];
    float a0 = 0.f, a1 = 0.f, a2 = 0.f, a3 = 0.f;
#pragma unroll
    for (int j = 0; j < 8; ++j) {
        float xf = (j < 4) ? x0[j & 3] : x1[j & 3];
        f32x4 wr = ((const f32x4*)gw)[l * 8 + j];
        a0 += xf * wr[0]; a1 += xf * wr[1]; a2 += xf * wr[2]; a3 += xf * wr[3];
    }
#pragma unroll
    for (int off = 32; off > 0; off >>= 1) {
        a0 += __shfl_down(a0, off, 64);
        a1 += __shfl_down(a1, off, 64);
        a2 += __shfl_down(a2, off, 64);
        a3 += __shfl_down(a3, off, 64);
    }
    if (l == 0) {
        float lg[4] = {a0 + gb[0], a1 + gb[1], a2 + gb[2], a3 + gb[3]};
        float m = fmaxf(fmaxf(lg[0], lg[1]), fmaxf(lg[2], lg[3]));
        float p[4]; float s = 0.f;
#pragma unroll
        for (int e = 0; e < 4; ++e) { p[e] = expf(lg[e] - m); s += p[e]; }
        float inv = 1.f / s;
#pragma unroll
        for (int e = 0; e < 4; ++e) p[e] *= inv;
        int i0 = 0;
#pragma unroll
        for (int e = 1; e < 4; ++e) if (p[e] > p[i0]) i0 = e;
        int i1 = -1;
#pragma unroll
        for (int e = 0; e < 4; ++e) if (e != i0 && (i1 < 0 || p[e] > p[i1])) i1 = e;
        float o[4] = {0.f, 0.f, 0.f, 0.f};
        o[i0] = p[i0]; o[i1] = p[i1];
        float* w = wg + (size_t)node * 4;
        w[0] = o[0]; w[1] = o[1]; w[2] = o[2]; w[3] = o[3];
    }
}

// -------- fused gating + fp32->bf16 convert: one pass over x -----------------------------
__global__ void gateconv_kernel(const float* __restrict__ x, const float* __restrict__ gw,
                                const float* __restrict__ gb, float* __restrict__ wg,
                                u16* __restrict__ xb) {
    int node = blockIdx.x * 4 + (threadIdx.x >> 6);
    int l = threadIdx.x & 63;
    const f32x4* xr = (const f32x4*)(x + (size_t)node * DD) + l * 2;
    f32x4 x0 = xr[0], x1 = xr[1];
    u16x8 o8;
    o8[0] = f2b(x0[0]); o8[1] = f2b(x0[1]); o8[2] = f2b(x0[2]); o8[3] = f2b(x0[3]);
    o8[4] = f2b(x1[0]); o8[5] = f2b(x1[1]); o8[6] = f2b(x1[2]); o8[7] = f2b(x1[3]);
    *((u16x8*)(xb + (size_t)node * DD) + l) = o8;
    float a0 = 0.f, a1 = 0.f, a2 = 0.f, a3 = 0.f;
#pragma unroll
    for (int j = 0; j < 8; ++j) {
        float xf = (j < 4) ? x0[j & 3] : x1[j & 3];
        f32x4 wr = ((const f32x4*)gw)[l * 8 + j];
        a0 += xf * wr[0]; a1 += xf * wr[1]; a2 += xf * wr[2]; a3 += xf * wr[3];
    }
#pragma unroll
    for (int off = 32; off > 0; off >>= 1) {
        a0 += __shfl_down(a0, off, 64);
        a1 += __shfl_down(a1, off, 64);
        a2 += __shfl_down(a2, off, 64);
        a3 += __shfl_down(a3, off, 64);
    }
    if (l == 0) {
        float lg[4] = {a0 + gb[0], a1 + gb[1], a2 + gb[2], a3 + gb[3]};
        float m = fmaxf(fmaxf(lg[0], lg[1]), fmaxf(lg[2], lg[3]));
        float p[4]; float s = 0.f;
#pragma unroll
        for (int e = 0; e < 4; ++e) { p[e] = expf(lg[e] - m); s += p[e]; }
        float inv = 1.f / s;
#pragma unroll
        for (int e = 0; e < 4; ++e) p[e] *= inv;
        int i0 = 0;
#pragma unroll
        for (int e = 1; e < 4; ++e) if (p[e] > p[i0]) i0 = e;
        int i1 = -1;
#pragma unroll
        for (int e = 0; e < 4; ++e) if (e != i0 && (i1 < 0 || p[e] > p[i1])) i1 = e;
        float o[4] = {0.f, 0.f, 0.f, 0.f};
        o[i0] = p[i0]; o[i1] = p[i1];
        float* w = wg + (size_t)node * 4;
        w[0] = o[0]; w[1] = o[1]; w[2] = o[2]; w[3] = o[3];
    }
}

// -------- expert compaction: per-expert active-node lists + positions --------------------
__global__ void compact_kernel(const float* __restrict__ wg, int* __restrict__ cnt,
                               int* __restrict__ list, int* __restrict__ posn) {
    int node = blockIdx.x * 256 + threadIdx.x;
    const float* w = wg + (size_t)node * 4;
#pragma unroll
    for (int e = 0; e < 4; ++e)
        if (w[e] > 0.f) {
            int p = atomicAdd(&cnt[e], 1);
            list[e * NN + p] = node;
            posn[node * 4 + e] = p;
        }
}

// tile map + per-expert compacted base offsets. cnt[0..3]=counts, cnt[4..7]=ebase,
// cnt[8]=tcount. Total compacted rows = exactly 2*NN (top-2) -> <= 516 tiles.
__global__ void tilemap_kernel(int* __restrict__ cnt, int* __restrict__ tmap) {
    if (threadIdx.x == 0) {
        int T = 0, acc = 0;
        for (int e = 0; e < 4; ++e) {
            cnt[4 + e] = acc;
            int c = cnt[e];
            acc += c;
            int nt = (c + 127) >> 7;
            for (int i = 0; i < nt; ++i) tmap[T++] = (e << 16) | i;
        }
        cnt[8] = T;
    }
}

// -------- CSR build ----------------------------------------------------------------------
__global__ void deg_kernel(const int* __restrict__ dst, int* __restrict__ deg) {
    int t = blockIdx.x * blockDim.x + threadIdx.x;
    if (t < EE) atomicAdd(&deg[dst[t]], 1);
}

__global__ void scan1_kernel(const int* __restrict__ deg, int* __restrict__ start,
                             float* __restrict__ invd, int* __restrict__ bsum) {
    int t = threadIdx.x;
    int idx = blockIdx.x * 1024 + t;
    int v = deg[idx];
    int sc = v;
#pragma unroll
    for (int off = 1; off < 64; off <<= 1) {
        int u = __shfl_up(sc, off, 64);
        if ((t & 63) >= off) sc += u;
    }
    __shared__ int wsum[16], woff[16];
    if ((t & 63) == 63) wsum[t >> 6] = sc;
    __syncthreads();
    if (t == 0) {
        int acc = 0;
        for (int w = 0; w < 16; ++w) { woff[w] = acc; acc += wsum[w]; }
        bsum[blockIdx.x] = acc;
    }
    __syncthreads();
    start[idx] = woff[t >> 6] + sc - v;
    invd[idx] = v > 0 ? 1.0f / (float)v : 0.0f;
}

__global__ void scan2_kernel(int* __restrict__ bsum, int* __restrict__ boff) {
    if (threadIdx.x == 0) {
        int acc = 0;
        for (int b = 0; b < 32; ++b) { boff[b] = acc; acc += bsum[b]; }
    }
}

__global__ void scan3_kernel(int* __restrict__ start, int* __restrict__ cursor,
                             const int* __restrict__ boff) {
    int idx = blockIdx.x * 256 + threadIdx.x;
    int s = start[idx] + boff[idx >> 10];
    start[idx] = s;
    cursor[idx] = s;
}

__global__ void scatter_kernel(const int* __restrict__ src, const int* __restrict__ dst,
                               int* __restrict__ cursor, int* __restrict__ csr) {
    int t = blockIdx.x * blockDim.x + threadIdx.x;
    if (t < EE) {
        int d = dst[t];
        int pos = atomicAdd(&cursor[d], 1);
        csr[pos] = src[t];
    }
}

// -------- mean aggregation over CSR; multi-expert: grid = nExp*8192 blocks ---------------
template <bool F32IN>
__global__ void aggr_kernel(const void* __restrict__ hv, u16* __restrict__ outB,
                            const int* __restrict__ start, const int* __restrict__ deg,
                            const int* __restrict__ csr, const float* __restrict__ invd,
                            const float* __restrict__ wg, int eBase, size_t stride) {
    int eo = blockIdx.x >> 13;
    int node = ((blockIdx.x & 8191) << 2) + (threadIdx.x >> 6);
    int expert = eBase + eo;
    if (wg != nullptr && wg[(size_t)node * 4 + expert] == 0.f) return;
    int l = threadIdx.x & 63;
    int s0 = start[node];
    int dg = deg[node];
    u16* out = outB + (size_t)eo * stride;
    const u16* hB = (const u16*)hv + (size_t)eo * stride;
    const float* hF = (const float*)hv + (size_t)eo * stride;
    float a[8] = {0.f, 0.f, 0.f, 0.f, 0.f, 0.f, 0.f, 0.f};

    for (int base = 0; base < dg; base += 64) {
        int cnt = dg - base;
        if (cnt > 64) cnt = 64;
        int vidx = 0;
        if (l < cnt) vidx = csr[s0 + base + l];
        int q = 0;
        if (!F32IN) {
            for (; q + 8 <= cnt; q += 8) {
                int j0 = __shfl(vidx, q, 64);
                int j1 = __shfl(vidx, q + 1, 64);
                int j2 = __shfl(vidx, q + 2, 64);
                int j3 = __shfl(vidx, q + 3, 64);
                int j4 = __shfl(vidx, q + 4, 64);
                int j5 = __shfl(vidx, q + 5, 64);
                int j6 = __shfl(vidx, q + 6, 64);
                int j7 = __shfl(vidx, q + 7, 64);
                u16x8 v0 = *((const u16x8*)(hB + (size_t)j0 * DD) + l);
                u16x8 v1 = *((const u16x8*)(hB + (size_t)j1 * DD) + l);
                u16x8 v2 = *((const u16x8*)(hB + (size_t)j2 * DD) + l);
                u16x8 v3 = *((const u16x8*)(hB + (size_t)j3 * DD) + l);
                u16x8 v4 = *((const u16x8*)(hB + (size_t)j4 * DD) + l);
                u16x8 v5 = *((const u16x8*)(hB + (size_t)j5 * DD) + l);
                u16x8 v6 = *((const u16x8*)(hB + (size_t)j6 * DD) + l);
                u16x8 v7 = *((const u16x8*)(hB + (size_t)j7 * DD) + l);
#pragma unroll
                for (int q2 = 0; q2 < 8; ++q2)
                    a[q2] += ((b2f(v0[q2]) + b2f(v1[q2])) + (b2f(v2[q2]) + b2f(v3[q2]))) +
                             ((b2f(v4[q2]) + b2f(v5[q2])) + (b2f(v6[q2]) + b2f(v7[q2])));
            }
        }
        for (; q + 4 <= cnt; q += 4) {
            int j0 = __shfl(vidx, q, 64);
            int j1 = __shfl(vidx, q + 1, 64);
            int j2 = __shfl(vidx, q + 2, 64);
            int j3 = __shfl(vidx, q + 3, 64);
            if (F32IN) {
                const f32x4* r0 = (const f32x4*)(hF + (size_t)j0 * DD) + l * 2;
                const f32x4* r1 = (const f32x4*)(hF + (size_t)j1 * DD) + l * 2;
                const f32x4* r2 = (const f32x4*)(hF + (size_t)j2 * DD) + l * 2;
                const f32x4* r3 = (const f32x4*)(hF + (size_t)j3 * DD) + l * 2;
                f32x4 u0 = r0[0], u1 = r0[1];
                f32x4 u2 = r1[0], u3 = r1[1];
                f32x4 u4 = r2[0], u5 = r2[1];
                f32x4 u6 = r3[0], u7 = r3[1];
#pragma unroll
                for (int q2 = 0; q2 < 4; ++q2) {
                    a[q2] += (u0[q2] + u2[q2]) + (u4[q2] + u6[q2]);
                    a[4 + q2] += (u1[q2] + u3[q2]) + (u5[q2] + u7[q2]);
                }
            } else {
                u16x8 v0 = *((const u16x8*)(hB + (size_t)j0 * DD) + l);
                u16x8 v1 = *((const u16x8*)(hB + (size_t)j1 * DD) + l);
                u16x8 v2 = *((const u16x8*)(hB + (size_t)j2 * DD) + l);
                u16x8 v3 = *((const u16x8*)(hB + (size_t)j3 * DD) + l);
#pragma unroll
                for (int q2 = 0; q2 < 8; ++q2)
                    a[q2] += (b2f(v0[q2]) + b2f(v1[q2])) + (b2f(v2[q2]) + b2f(v3[q2]));
            }
        }
        for (; q < cnt; ++q) {
            int j = __shfl(vidx, q, 64);
            if (F32IN) {
                const f32x4* r = (const f32x4*)(hF + (size_t)j * DD) + l * 2;
                f32x4 u0 = r[0], u1 = r[1];
#pragma unroll
                for (int q2 = 0; q2 < 4; ++q2) { a[q2] += u0[q2]; a[4 + q2] += u1[q2]; }
            } else {
                u16x8 v = *((const u16x8*)(hB + (size_t)j * DD) + l);
#pragma unroll
                for (int q2 = 0; q2 < 8; ++q2) a[q2] += b2f(v[q2]);
            }
        }
    }
    float sc = invd[node];
    u16x8 o;
#pragma unroll
    for (int q2 = 0; q2 < 8; ++q2) o[q2] = f2b(a[q2] * sc);
    *((u16x8*)(out + (size_t)node * DD) + l) = o;
}

// -------- dual-expert gated aggregation -> COMPACTED output ------------------------------
// One wave = one node, both active experts; one csr index stream serves both; results
// written at compacted row ebase[e] + posn[node][e] so aggr1c is only 2*NN rows (64 MB).
__global__ void aggr2_kernel(const u16* __restrict__ h, u16* __restrict__ outC,
                             const int* __restrict__ start, const int* __restrict__ deg,
                             const int* __restrict__ csr, const float* __restrict__ invd,
                             const float* __restrict__ wg, const int* __restrict__ posn,
                             const int* __restrict__ cntb) {
    const int node = (blockIdx.x << 2) + (threadIdx.x >> 6);
    const int l = threadIdx.x & 63;
    const float* w = wg + (size_t)node * 4;
    int e0 = -1, e1 = -1;
#pragma unroll
    for (int e = 0; e < 4; ++e) {
        if (w[e] > 0.f) { if (e0 < 0) e0 = e; else e1 = e; }
    }
    if (e0 < 0) return;
    const int dual = (e1 >= 0);
    if (!dual) e1 = e0;
    const size_t STRE = (size_t)NN * DD;
    const u16* hA = h + (size_t)e0 * STRE;
    const u16* hC = h + (size_t)e1 * STRE;
    const int g0 = cntb[4 + e0] + posn[node * 4 + e0];
    const int g1 = cntb[4 + e1] + posn[node * 4 + e1];
    const int s0 = start[node];
    const int dg = deg[node];
    float a0[8] = {0.f, 0.f, 0.f, 0.f, 0.f, 0.f, 0.f, 0.f};
    float a1[8] = {0.f, 0.f, 0.f, 0.f, 0.f, 0.f, 0.f, 0.f};

    for (int base = 0; base < dg; base += 64) {
        int cnt = dg - base;
        if (cnt > 64) cnt = 64;
        int vidx = 0;
        if (l < cnt) vidx = csr[s0 + base + l];
        int q = 0;
        for (; q + 4 <= cnt; q += 4) {
            int j0 = __shfl(vidx, q, 64);
            int j1 = __shfl(vidx, q + 1, 64);
            int j2 = __shfl(vidx, q + 2, 64);
            int j3 = __shfl(vidx, q + 3, 64);
            u16x8 u0 = *((const u16x8*)(hA + (size_t)j0 * DD) + l);
            u16x8 u1 = *((const u16x8*)(hA + (size_t)j1 * DD) + l);
            u16x8 u2 = *((const u16x8*)(hA + (size_t)j2 * DD) + l);
            u16x8 u3 = *((const u16x8*)(hA + (size_t)j3 * DD) + l);
            u16x8 t0 = *((const u16x8*)(hC + (size_t)j0 * DD) + l);
            u16x8 t1 = *((const u16x8*)(hC + (size_t)j1 * DD) + l);
            u16x8 t2 = *((const u16x8*)(hC + (size_t)j2 * DD) + l);
            u16x8 t3 = *((const u16x8*)(hC + (size_t)j3 * DD) + l);
#pragma unroll
            for (int q2 = 0; q2 < 8; ++q2) {
                a0[q2] += (b2f(u0[q2]) + b2f(u1[q2])) + (b2f(u2[q2]) + b2f(u3[q2]));
                a1[q2] += (b2f(t0[q2]) + b2f(t1[q2])) + (b2f(t2[q2]) + b2f(t3[q2]));
            }
        }
        for (; q < cnt; ++q) {
            int j = __shfl(vidx, q, 64);
            u16x8 u = *((const u16x8*)(hA + (size_t)j * DD) + l);
            u16x8 t = *((const u16x8*)(hC + (size_t)j * DD) + l);
#pragma unroll
            for (int q2 = 0; q2 < 8; ++q2) { a0[q2] += b2f(u[q2]); a1[q2] += b2f(t[q2]); }
        }
    }
    float sc = invd[node];
    u16x8 o0, o1;
#pragma unroll
    for (int q2 = 0; q2 < 8; ++q2) { o0[q2] = f2b(a0[q2] * sc); o1[q2] = f2b(a1[q2] * sc); }
    *((u16x8*)(outC + (size_t)g0 * DD) + l) = o0;
    if (dual)
        *((u16x8*)(outC + (size_t)g1 * DD) + l) = o1;
}

__device__ __forceinline__ void gload16(const void* g, void* l) {
    __builtin_amdgcn_global_load_lds((const __attribute__((address_space(1))) void*)g,
                                     (__attribute__((address_space(3))) void*)l, 16, 0, 0);
}

// -------- fused GEMM (L0 + fallback tiers): A and B both staged through LDS --------------
// B-direct variant (round 6) measured 302 vs 194 us: per-lane B reads (16 rows x 64 B per
// wave, stride 2 KB) are uncoalesced -> L2 thrash, FETCH 141->225 MB. LDS staging of B via
// coalesced global_load_lds is load-bearing; keep it.
template <bool A2F32>
__global__ void __launch_bounds__(256, 4) gemm_kernel(
    const u16* __restrict__ A1, const u16* __restrict__ A2b, const float* __restrict__ A2f,
    size_t sA, const u16* __restrict__ Bt, size_t sBt,
    const float* __restrict__ bias, size_t sBias,
    u16* __restrict__ Hout, size_t sH, float* __restrict__ Out,
    const float* __restrict__ wg, int mode, int eBase, int ntt) {
    __shared__ u16 lds[A2F32 ? 12288 : 8192];
    u16* ldsA = lds;
    float* ldsF = (float*)lds;
    u16* ldsB = lds + (A2F32 ? 8192 : 4096);
    const int tid = threadIdx.x;
    const int lane = tid & 63;
    const int w = tid >> 6;

    const int bid = blockIdx.x;
    const int xcd = bid & 7;
    const int local = bid >> 3;
    const int mtl = local / ntt;
    const int sub = local - mtl * ntt;
    const int expert = sub >> 2;
    const int wgE = eBase + expert;
    const int m0 = (xcd * 32 + mtl) * 128;
    const int n0 = (sub & 3) * 128;

    const u16* A1p = A1 + (size_t)expert * sA;
    const u16* A2p = A2b + (size_t)expert * sA;
    const u16* Btp = Bt + (size_t)expert * sBt;
    const float* biasp = bias + (size_t)expert * sBias;
    u16* Houtp = Hout + (size_t)expert * sH;

    const int wm = (w >> 1) * 64;
    const int wn = (w & 1) * 64;

    f32x4 acc[4][4];
#pragma unroll
    for (int i = 0; i < 4; ++i)
#pragma unroll
        for (int j = 0; j < 4; ++j) acc[i][j] = (f32x4){0.f, 0.f, 0.f, 0.f};

    const int p0 = tid, p1 = 256 + tid;
    const int r0 = p0 >> 2, c0 = ((p0 & 3) - (r0 >> 1)) & 3;
    const int r1 = p1 >> 2, c1 = ((p1 & 3) - (r1 >> 1)) & 3;
    const int arow = lane & 15;
    const int kc = lane >> 4;

    for (int kb = 0; kb < 32; ++kb) {
        __syncthreads();
        if (!A2F32 || kb < 16) {
            const u16* As = (kb < 16) ? A1p : A2p;
            const int kcol = (kb & 15) * 32;
            gload16(As + (size_t)(m0 + r0) * DD + kcol + c0 * 8, ldsA + p0 * 8);
            gload16(As + (size_t)(m0 + r1) * DD + kcol + c1 * 8, ldsA + p1 * 8);
        } else {
            const float* Af = A2f + (size_t)m0 * DD + (kb - 16) * 32;
#pragma unroll
            for (int q = 0; q < 4; ++q) {
                int p = q * 256 + tid;
                int rr = p >> 3, cpos = p & 7, cc2 = (cpos - rr) & 7;
                gload16(Af + (size_t)rr * DD + cc2 * 4, ldsF + p * 4);
            }
        }
        gload16(Btp + (size_t)(n0 + r0) * 1024 + kb * 32 + c0 * 8, ldsB + p0 * 8);
        gload16(Btp + (size_t)(n0 + r1) * 1024 + kb * 32 + c1 * 8, ldsB + p1 * 8);
        __syncthreads();
        s16x8 af[4], bf[4];
        if (!A2F32 || kb < 16) {
#pragma unroll
            for (int f = 0; f < 4; ++f) {
                int ra = wm + f * 16 + arow;
                int pa = (kc + (ra >> 1)) & 3;
                af[f] = *(const s16x8*)(ldsA + (ra * 4 + pa) * 8);
            }
        } else {
#pragma unroll
            for (int f = 0; f < 4; ++f) {
                int ra = wm + f * 16 + arow;
                int plo = ra * 8 + ((2 * kc + ra) & 7);
                int phi = ra * 8 + ((2 * kc + 1 + ra) & 7);
                f32x4 lo = *(const f32x4*)(ldsF + plo * 4);
                f32x4 hi = *(const f32x4*)(ldsF + phi * 4);
                s16x8 t;
                t[0] = (short)f2b(lo[0]); t[1] = (short)f2b(lo[1]);
                t[2] = (short)f2b(lo[2]); t[3] = (short)f2b(lo[3]);
                t[4] = (short)f2b(hi[0]); t[5] = (short)f2b(hi[1]);
                t[6] = (short)f2b(hi[2]); t[7] = (short)f2b(hi[3]);
                af[f] = t;
            }
        }
#pragma unroll
        for (int f = 0; f < 4; ++f) {
            int rb = wn + f * 16 + arow;
            int pb = (kc + (rb >> 1)) & 3;
            bf[f] = *(const s16x8*)(ldsB + (rb * 4 + pb) * 8);
        }
#pragma unroll
        for (int i = 0; i < 4; ++i)
#pragma unroll
            for (int j = 0; j < 4; ++j)
                acc[i][j] = __builtin_amdgcn_mfma_f32_16x16x32_bf16(af[i], bf[j], acc[i][j], 0, 0, 0);
    }

    const int colq = lane & 15;
    const int rq = lane >> 4;
#pragma unroll
    for (int i = 0; i < 4; ++i) {
#pragma unroll
        for (int j = 0; j < 4; ++j) {
            int col = n0 + wn + j * 16 + colq;
            float bv = biasp[col];
#pragma unroll
            for (int r = 0; r < 4; ++r) {
                int row = m0 + wm + i * 16 + rq * 4 + r;
                float v = fmaxf(acc[i][j][r] + bv, 0.f);
                size_t idx = (size_t)row * DD + col;
                if (mode == 0) {
                    Houtp[idx] = f2b(v);
                } else {
                    float wv = wg[(size_t)row * 4 + wgE];
                    if (mode == 1) {
                        Out[idx] = wv * v;
                    } else if (mode == 2) {
                        if (wv > 0.f) Out[idx] += wv * v;
                    } else {
                        if (wv > 0.f) unsafeAtomicAdd(&Out[idx], wv * v);
                    }
                }
            }
        }
    }
}

// -------- L1 GEMM over compacted rows: out[node] += wv * relu([aggr1c|h1]@Bt^T + b) ------
// A1 = compacted aggregation (LINEAR rows, ebase[e]+base+r); A2 = h1 gathered via list;
// exactly the top-2 rows (2*NN) -> half the dense work. Padding rows clamped + masked.
// Validated round 6 (passed, absmax unchanged, < 302 us).
__global__ void __launch_bounds__(256, 4) gemm_gather_kernel(
    const u16* __restrict__ A1c, const u16* __restrict__ A2,
    const u16* __restrict__ Bt, const float* __restrict__ bias,
    float* __restrict__ Out, const float* __restrict__ wg,
    const int* __restrict__ list, const int* __restrict__ cntb,
    const int* __restrict__ tmap) {
    const int t = blockIdx.x >> 2;
    if (t >= cntb[8]) return;
    const u32 mi = (u32)tmap[t];
    const int e = mi >> 16;
    const int mt = mi & 0xffff;
    const int cntE = cntb[e];
    const int eb = cntb[4 + e];
    const int base = mt << 7;
    const int n0 = (blockIdx.x & 3) * 128;

    __shared__ u16 lds[8192];
    u16* ldsA = lds;
    u16* ldsB = lds + 4096;
    const int tid = threadIdx.x;
    const int lane = tid & 63;
    const int w = tid >> 6;

    const size_t STRE = (size_t)NN * DD;
    const u16* A2p = A2 + (size_t)e * STRE;
    const u16* Btp = Bt + (size_t)e * (2 * WMAT);
    const float* biasp = bias + (size_t)e * 1024;
    const int* listE = list + e * NN;

    const int wm = (w >> 1) * 64;
    const int wn = (w & 1) * 64;

    f32x4 acc[4][4];
#pragma unroll
    for (int i = 0; i < 4; ++i)
#pragma unroll
        for (int j = 0; j < 4; ++j) acc[i][j] = (f32x4){0.f, 0.f, 0.f, 0.f};

    const int p0 = tid, p1 = 256 + tid;
    const int r0 = p0 >> 2, c0 = ((p0 & 3) - (r0 >> 1)) & 3;
    const int r1 = p1 >> 2, c1 = ((p1 & 3) - (r1 >> 1)) & 3;
    int g0 = eb + base + r0; if (g0 > 2 * NN - 1) g0 = 2 * NN - 1;
    int g1 = eb + base + r1; if (g1 > 2 * NN - 1) g1 = 2 * NN - 1;
    int q0 = base + r0; if (q0 >= cntE) q0 = cntE - 1;
    int q1 = base + r1; if (q1 >= cntE) q1 = cntE - 1;
    const int gr0 = listE[q0];
    const int gr1 = listE[q1];
    const int arow = lane & 15;
    const int kc = lane >> 4;

    for (int kb = 0; kb < 32; ++kb) {
        __syncthreads();
        if (kb < 16) {
            const int kcol = kb * 32;
            gload16(A1c + (size_t)g0 * DD + kcol + c0 * 8, ldsA + p0 * 8);
            gload16(A1c + (size_t)g1 * DD + kcol + c1 * 8, ldsA + p1 * 8);
        } else {
            const int kcol = (kb - 16) * 32;
            gload16(A2p + (size_t)gr0 * DD + kcol + c0 * 8, ldsA + p0 * 8);
            gload16(A2p + (size_t)gr1 * DD + kcol + c1 * 8, ldsA + p1 * 8);
        }
        gload16(Btp + (size_t)(n0 + r0) * 1024 + kb * 32 + c0 * 8, ldsB + p0 * 8);
        gload16(Btp + (size_t)(n0 + r1) * 1024 + kb * 32 + c1 * 8, ldsB + p1 * 8);
        __syncthreads();
        s16x8 af[4], bf[4];
#pragma unroll
        for (int f = 0; f < 4; ++f) {
            int ra = wm + f * 16 + arow;
            int pa = (kc + (ra >> 1)) & 3;
            af[f] = *(const s16x8*)(ldsA + (ra * 4 + pa) * 8);
        }
#pragma unroll
        for (int f = 0; f < 4; ++f) {
            int rb = wn + f * 16 + arow;
            int pb = (kc + (rb >> 1)) & 3;
            bf[f] = *(const s16x8*)(ldsB + (rb * 4 + pb) * 8);
        }
#pragma unroll
        for (int i = 0; i < 4; ++i)
#pragma unroll
            for (int j = 0; j < 4; ++j)
                acc[i][j] = __builtin_amdgcn_mfma_f32_16x16x32_bf16(af[i], bf[j], acc[i][j], 0, 0, 0);
    }

    const int colq = lane & 15;
    const int rq = lane >> 4;
#pragma unroll
    for (int i = 0; i < 4; ++i) {
        int nd[4]; float wv4[4]; bool val[4];
#pragma unroll
        for (int r = 0; r < 4; ++r) {
            int rowl = base + wm + i * 16 + rq * 4 + r;
            val[r] = rowl < cntE;
            int qq = val[r] ? rowl : 0;
            nd[r] = listE[qq];
            wv4[r] = wg[(size_t)nd[r] * 4 + e];
        }
#pragma unroll
        for (int j = 0; j < 4; ++j) {
            int col = n0 + wn + j * 16 + colq;
            float bv = biasp[col];
#pragma unroll
            for (int r = 0; r < 4; ++r) {
                if (val[r]) {
                    float v = fmaxf(acc[i][j][r] + bv, 0.f);
                    unsafeAtomicAdd(&Out[(size_t)nd[r] * DD + col], wv4[r] * v);
                }
            }
        }
    }
}

extern "C" void kernel_launch(void* const* d_in, const int* in_sizes, int n_in,
                              void* d_out, int out_size, void* d_ws, size_t ws_size,
                              hipStream_t stream) {
    const float* x  = (const float*)d_in[0];
    const float* gW = (const float*)d_in[1];
    const float* gb = (const float*)d_in[2];
    const float* Wl = (const float*)d_in[3];
    const float* bl = (const float*)d_in[4];
    const float* Wr = (const float*)d_in[5];
    const u32*   ei = (const u32*)d_in[6];
    float* outp = (float*)d_out;

    char* ws = (char*)d_ws;
    size_t off = 0;
    auto alloc = [&](size_t bytes) -> void* {
        void* p = ws + off;
        off += (bytes + 255) & ~(size_t)255;
        return p;
    };
    const size_t MB32 = (size_t)NN * DD * 2;
    const size_t STR = (size_t)NN * DD;      // per-expert element stride
    int*   flags  = (int*)alloc(512);
    float* wg     = (float*)alloc((size_t)NN * 4 * 4);
    int*   deg    = (int*)alloc((size_t)NN * 4);
    int*   start  = (int*)alloc((size_t)NN * 4);
    int*   cursor = (int*)alloc((size_t)NN * 4);
    float* invd   = (float*)alloc((size_t)NN * 4);
    int*   src32  = (int*)alloc((size_t)EE * 4);
    int*   dst32  = (int*)alloc((size_t)EE * 4);
    int*   csr    = (int*)alloc((size_t)EE * 4);
    u16*   Bt     = (u16*)alloc((size_t)8 * WMAT * 2);       // 8 MB
    int*   cnt    = (int*)alloc(64);                          // [0..3] cnt, [4..7] ebase, [8] tcount
    int*   tmap   = (int*)alloc(1040 * 4);
    // Aliases (dead after scatter_kernel): list <- dst32, posn <- src32.
    int*   list   = dst32;
    int*   posn   = src32;

    size_t rem = (ws_size > off) ? ws_size - off : 0;
    // ws_size ~= 256 MiB on this harness. Tier 0 (compact-fused) sized to the validated
    // 224 MB budget: xb (32) + h1 (128) + aggr1c (64, compacted 2*NN rows).
    int tier;
    if      (rem >= 7 * MB32 + 65536) tier = 0;   // compact-fused (224 MB)
    else if (rem >= 6 * MB32 + 65536) tier = 2;   // bf16 fused L0, sequential L1 (192 MB)
    else if (rem >= 5 * MB32 + 65536) tier = 3;   // fp32-staged fused L0 (160 MB)
    else if (rem >= 4 * MB32 + 65536) tier = 4;   // sequential (128 MB)
    else                              tier = 5;   // fp32 fallback (96 MB)

    u16 *xb = nullptr, *h1 = nullptr, *aggr1 = nullptr, *aggr0 = nullptr;
    if (tier == 0) {
        xb = (u16*)alloc(MB32);
        h1 = (u16*)alloc(4 * MB32);
        aggr1 = (u16*)alloc(2 * MB32);      // compacted: 2*NN rows
        aggr0 = aggr1;                      // dense L0 aggr (32 MB) aliases head; dead before aggr2
    } else if (tier == 2) {
        xb = (u16*)alloc(MB32);
        h1 = (u16*)alloc(4 * MB32);
        aggr1 = (u16*)alloc(MB32);
        aggr0 = aggr1;
    } else if (tier == 3) {
        aggr0 = (u16*)alloc(MB32);
        h1 = (u16*)alloc(4 * MB32);
        aggr1 = aggr0;
    } else if (tier == 4) {
        aggr0 = (u16*)alloc(MB32);
        xb = (u16*)alloc(MB32);
        h1 = (u16*)alloc(MB32);
        aggr1 = (u16*)alloc(MB32);
    } else {
        aggr0 = (u16*)alloc(MB32);
        h1 = (u16*)alloc(MB32);
        aggr1 = (u16*)alloc(MB32);
    }

    int* bsum = flags + 16;
    int* boff = flags + 64;

    hipMemsetAsync(deg, 0, (size_t)NN * 4, stream);

    detect_kernel<<<1, 64, 0, stream>>>(ei, flags);
    edges_kernel<<<EE / 256, 256, 0, stream>>>(ei, flags, src32, dst32);
    transpose_kernel<<<16 * 256, 256, 0, stream>>>(Wl, Wr, Bt);
    if (xb != nullptr)
        gateconv_kernel<<<NN / 4, 256, 0, stream>>>(x, gW, gb, wg, xb);
    else
        gate_kernel<<<NN / 4, 256, 0, stream>>>(x, gW, gb, wg);
    deg_kernel<<<EE / 256, 256, 0, stream>>>(dst32, deg);
    scan1_kernel<<<32, 1024, 0, stream>>>(deg, start, invd, bsum);
    scan2_kernel<<<1, 64, 0, stream>>>(bsum, boff);
    scan3_kernel<<<NN / 256, 256, 0, stream>>>(start, cursor, boff);
    scatter_kernel<<<EE / 256, 256, 0, stream>>>(src32, dst32, cursor, csr);

    if (tier == 0) {
        // src32/dst32 dead; their storage backs posn/list from here.
        hipMemsetAsync(cnt, 0, 64, stream);
        compact_kernel<<<NN / 256, 256, 0, stream>>>(wg, cnt, list, posn);
        tilemap_kernel<<<1, 64, 0, stream>>>(cnt, tmap);
        // L0: dense aggr + LDS-staged GEMM (194-214 us validated; B-direct reverted)
        aggr_kernel<false><<<8192, 256, 0, stream>>>(xb, aggr0, start, deg, csr, invd,
                                                     nullptr, 0, 0);
        gemm_kernel<false><<<256 * 16, 256, 0, stream>>>(
            aggr0, xb, nullptr, /*sA=*/0, Bt, /*sBt=*/2 * WMAT, bl, /*sBias=*/1024,
            h1, /*sH=*/STR, nullptr, wg, /*mode=*/0, /*eBase=*/0, /*ntt=*/16);
        hipMemsetAsync(outp, 0, (size_t)NN * DD * 4, stream);
        // L1: dual-expert aggr -> compacted rows; gather-GEMM over exactly top-2 rows
        aggr2_kernel<<<8192, 256, 0, stream>>>(h1, aggr1, start, deg, csr, invd, wg,
                                               posn, cnt);
        gemm_gather_kernel<<<516 * 4, 256, 0, stream>>>(
            aggr1, h1, Bt + WMAT, bl + 512, outp, wg, list, cnt, tmap);
    } else if (tier == 2) {
        aggr_kernel<false><<<8192, 256, 0, stream>>>(xb, aggr0, start, deg, csr, invd,
                                                     nullptr, 0, 0);
        gemm_kernel<false><<<256 * 16, 256, 0, stream>>>(
            aggr0, xb, nullptr, 0, Bt, 2 * WMAT, bl, 1024,
            h1, STR, nullptr, wg, 0, 0, 16);
        for (int e = 0; e < 4; ++e) {
            aggr_kernel<false><<<8192, 256, 0, stream>>>(
                h1 + (size_t)e * STR, aggr1, start, deg, csr, invd, wg, e, 0);
            gemm_kernel<false><<<256 * 4, 256, 0, stream>>>(
                aggr1, h1 + (size_t)e * STR, nullptr, 0,
                Bt + (size_t)(e * 2 + 1) * WMAT, 0, bl + (e * 2 + 1) * 512, 0,
                nullptr, 0, outp, wg, (e == 0) ? 1 : 2, e, 4);
        }
    } else if (tier == 3) {
        aggr_kernel<true><<<8192, 256, 0, stream>>>(x, aggr0, start, deg, csr, invd,
                                                    nullptr, 0, 0);
        gemm_kernel<true><<<256 * 16, 256, 0, stream>>>(
            aggr0, nullptr, x, 0, Bt, 2 * WMAT, bl, 1024,
            h1, STR, nullptr, wg, 0, 0, 16);
        for (int e = 0; e < 4; ++e) {
            aggr_kernel<false><<<8192, 256, 0, stream>>>(
                h1 + (size_t)e * STR, aggr1, start, deg, csr, invd, wg, e, 0);
            gemm_kernel<false><<<256 * 4, 256, 0, stream>>>(
                aggr1, h1 + (size_t)e * STR, nullptr, 0,
                Bt + (size_t)(e * 2 + 1) * WMAT, 0, bl + (e * 2 + 1) * 512, 0,
                nullptr, 0, outp, wg, (e == 0) ? 1 : 2, e, 4);
        }
    } else {
        if (tier == 4) {
            aggr_kernel<false><<<8192, 256, 0, stream>>>(xb, aggr0, start, deg, csr, invd,
                                                         nullptr, 0, 0);
        } else {
            aggr_kernel<true><<<8192, 256, 0, stream>>>(x, aggr0, start, deg, csr, invd,
                                                        nullptr, 0, 0);
        }
        for (int e = 0; e < 4; ++e) {
            const u16* BtL0 = Bt + (size_t)(e * 2 + 0) * WMAT;
            const u16* BtL1 = Bt + (size_t)(e * 2 + 1) * WMAT;
            const float* b0 = bl + (e * 2 + 0) * 512;
            const float* b1 = bl + (e * 2 + 1) * 512;
            if (tier == 4)
                gemm_kernel<false><<<256 * 4, 256, 0, stream>>>(
                    aggr0, xb, nullptr, 0, BtL0, 0, b0, 0, h1, 0, nullptr, wg, 0, e, 4);
            else
                gemm_kernel<true><<<256 * 4, 256, 0, stream>>>(
                    aggr0, nullptr, x, 0, BtL0, 0, b0, 0, h1, 0, nullptr, wg, 0, e, 4);
            aggr_kernel<false><<<8192, 256, 0, stream>>>(h1, aggr1, start, deg, csr, invd,
                                                         wg, e, 0);
            gemm_kernel<false><<<256 * 4, 256, 0, stream>>>(
                aggr1, h1, nullptr, 0, BtL1, 0, b1, 0, nullptr, 0, outp, wg,
                (e == 0) ? 1 : 2, e, 4);
        }
    }
}

// Round 8
// 725.527 us; speedup vs baseline: 1.1645x; 1.0070x over previous
//
#include <hip/hip_runtime.h>

typedef unsigned short u16;
typedef unsigned int u32;
typedef u16 u16x8 __attribute__((ext_vector_type(8)));
typedef short s16x8 __attribute__((ext_vector_type(8)));
typedef float f32x4 __attribute__((ext_vector_type(4)));

#define NN 32768
#define EE 262144
#define DD 512
#define WMAT (512 * 1024)   // elements per Bt matrix

__device__ __forceinline__ float b2f(u16 u) {
    return __uint_as_float(((u32)u) << 16);
}
__device__ __forceinline__ u16 f2b(float f) {
    u32 u = __float_as_uint(f);
    u32 r = (u + 0x7FFFu + ((u >> 16) & 1u)) >> 16;
    return (u16)r;
}

// -------- edge-index width detection: int64 (high words zero) vs int32 ------------------
__global__ void detect_kernel(const u32* __restrict__ ei, int* __restrict__ flags) {
    if (threadIdx.x == 0) {
        int allzero = 1;
        for (int i = 0; i < 64; ++i)
            if (ei[2 * i + 1] != 0u) allzero = 0;
        flags[0] = allzero;  // 1 => int64 layout
    }
}

__global__ void edges_kernel(const u32* __restrict__ ei, const int* __restrict__ flags,
                             int* __restrict__ s32, int* __restrict__ d32) {
    int t = blockIdx.x * 256 + threadIdx.x;
    u32 s, d;
    if (flags[0]) {  // int64
        s = ei[2 * t];
        d = ei[2 * EE + 2 * t];
    } else {         // int32
        s = ei[t];
        d = ei[EE + t];
    }
    s32[t] = (int)(s & (NN - 1));
    d32[t] = (int)(d & (NN - 1));
}

// -------- weight transpose+cvt: W[e][l][k][n] fp32 -> Bt[e*2+l][n][k 0..1023] bf16 -------
__global__ void transpose_kernel(const float* __restrict__ Wl, const float* __restrict__ Wr,
                                 u16* __restrict__ Bt) {
    int bid = blockIdx.x;
    int matid = bid >> 8;
    int tile = bid & 255;
    int em = matid >> 1;
    int half = matid & 1;
    const float* W = (half ? Wr : Wl) + (size_t)em * DD * DD;
    u16* out = Bt + (size_t)em * DD * 1024 + half * DD;
    int tk = (tile >> 4) * 32, tn = (tile & 15) * 32;
    __shared__ float s[32][33];
    int t = threadIdx.x;
    int rr = t >> 5, cc = t & 31;
#pragma unroll
    for (int p = 0; p < 4; ++p) {
        int kr = p * 8 + rr;
        s[kr][cc] = W[(size_t)(tk + kr) * DD + tn + cc];
    }
    __syncthreads();
#pragma unroll
    for (int p = 0; p < 4; ++p) {
        int nr = p * 8 + rr;
        out[(size_t)(tn + nr) * 1024 + tk + cc] = f2b(s[cc][nr]);
    }
}

// -------- gating (standalone, tiers without xb) ------------------------------------------
__global__ void gate_kernel(const float* __restrict__ x, const float* __restrict__ gw,
                            const float* __restrict__ gb, float* __restrict__ wg) {
    int node = blockIdx.x * 4 + (threadIdx.x >> 6);
    int l = threadIdx.x & 63;
    const f32x4* xr = (const f32x4*)(x + (size_t)node * DD) + l * 2;
    f32x4 x0 = xr[0], x1 = xr[1];
    float a0 = 0.f, a1 = 0.f, a2 = 0.f, a3 = 0.f;
#pragma unroll
    for (int j = 0; j < 8; ++j) {
        float xf = (j < 4) ? x0[j & 3] : x1[j & 3];
        f32x4 wr = ((const f32x4*)gw)[l * 8 + j];
        a0 += xf * wr[0]; a1 += xf * wr[1]; a2 += xf * wr[2]; a3 += xf * wr[3];
    }
#pragma unroll
    for (int off = 32; off > 0; off >>= 1) {
        a0 += __shfl_down(a0, off, 64);
        a1 += __shfl_down(a1, off, 64);
        a2 += __shfl_down(a2, off, 64);
        a3 += __shfl_down(a3, off, 64);
    }
    if (l == 0) {
        float lg[4] = {a0 + gb[0], a1 + gb[1], a2 + gb[2], a3 + gb[3]};
        float m = fmaxf(fmaxf(lg[0], lg[1]), fmaxf(lg[2], lg[3]));
        float p[4]; float s = 0.f;
#pragma unroll
        for (int e = 0; e < 4; ++e) { p[e] = expf(lg[e] - m); s += p[e]; }
        float inv = 1.f / s;
#pragma unroll
        for (int e = 0; e < 4; ++e) p[e] *= inv;
        int i0 = 0;
#pragma unroll
        for (int e = 1; e < 4; ++e) if (p[e] > p[i0]) i0 = e;
        int i1 = -1;
#pragma unroll
        for (int e = 0; e < 4; ++e) if (e != i0 && (i1 < 0 || p[e] > p[i1])) i1 = e;
        float o[4] = {0.f, 0.f, 0.f, 0.f};
        o[i0] = p[i0]; o[i1] = p[i1];
        float* w = wg + (size_t)node * 4;
        w[0] = o[0]; w[1] = o[1]; w[2] = o[2]; w[3] = o[3];
    }
}

// -------- fused gating + fp32->bf16 convert: one pass over x -----------------------------
__global__ void gateconv_kernel(const float* __restrict__ x, const float* __restrict__ gw,
                                const float* __restrict__ gb, float* __restrict__ wg,
                                u16* __restrict__ xb) {
    int node = blockIdx.x * 4 + (threadIdx.x >> 6);
    int l = threadIdx.x & 63;
    const f32x4* xr = (const f32x4*)(x + (size_t)node * DD) + l * 2;
    f32x4 x0 = xr[0], x1 = xr[1];
    u16x8 o8;
    o8[0] = f2b(x0[0]); o8[1] = f2b(x0[1]); o8[2] = f2b(x0[2]); o8[3] = f2b(x0[3]);
    o8[4] = f2b(x1[0]); o8[5] = f2b(x1[1]); o8[6] = f2b(x1[2]); o8[7] = f2b(x1[3]);
    *((u16x8*)(xb + (size_t)node * DD) + l) = o8;
    float a0 = 0.f, a1 = 0.f, a2 = 0.f, a3 = 0.f;
#pragma unroll
    for (int j = 0; j < 8; ++j) {
        float xf = (j < 4) ? x0[j & 3] : x1[j & 3];
        f32x4 wr = ((const f32x4*)gw)[l * 8 + j];
        a0 += xf * wr[0]; a1 += xf * wr[1]; a2 += xf * wr[2]; a3 += xf * wr[3];
    }
#pragma unroll
    for (int off = 32; off > 0; off >>= 1) {
        a0 += __shfl_down(a0, off, 64);
        a1 += __shfl_down(a1, off, 64);
        a2 += __shfl_down(a2, off, 64);
        a3 += __shfl_down(a3, off, 64);
    }
    if (l == 0) {
        float lg[4] = {a0 + gb[0], a1 + gb[1], a2 + gb[2], a3 + gb[3]};
        float m = fmaxf(fmaxf(lg[0], lg[1]), fmaxf(lg[2], lg[3]));
        float p[4]; float s = 0.f;
#pragma unroll
        for (int e = 0; e < 4; ++e) { p[e] = expf(lg[e] - m); s += p[e]; }
        float inv = 1.f / s;
#pragma unroll
        for (int e = 0; e < 4; ++e) p[e] *= inv;
        int i0 = 0;
#pragma unroll
        for (int e = 1; e < 4; ++e) if (p[e] > p[i0]) i0 = e;
        int i1 = -1;
#pragma unroll
        for (int e = 0; e < 4; ++e) if (e != i0 && (i1 < 0 || p[e] > p[i1])) i1 = e;
        float o[4] = {0.f, 0.f, 0.f, 0.f};
        o[i0] = p[i0]; o[i1] = p[i1];
        float* w = wg + (size_t)node * 4;
        w[0] = o[0]; w[1] = o[1]; w[2] = o[2]; w[3] = o[3];
    }
}

// -------- expert compaction: per-expert active-node lists + positions --------------------
__global__ void compact_kernel(const float* __restrict__ wg, int* __restrict__ cnt,
                               int* __restrict__ list, int* __restrict__ posn) {
    int node = blockIdx.x * 256 + threadIdx.x;
    const float* w = wg + (size_t)node * 4;
#pragma unroll
    for (int e = 0; e < 4; ++e)
        if (w[e] > 0.f) {
            int p = atomicAdd(&cnt[e], 1);
            list[e * NN + p] = node;
            posn[node * 4 + e] = p;
        }
}

// tile map + per-expert compacted base offsets. cnt[0..3]=counts, cnt[4..7]=ebase,
// cnt[8]=tcount. Total compacted rows = exactly 2*NN (top-2) -> <= 516 tiles.
__global__ void tilemap_kernel(int* __restrict__ cnt, int* __restrict__ tmap) {
    if (threadIdx.x == 0) {
        int T = 0, acc = 0;
        for (int e = 0; e < 4; ++e) {
            cnt[4 + e] = acc;
            int c = cnt[e];
            acc += c;
            int nt = (c + 127) >> 7;
            for (int i = 0; i < nt; ++i) tmap[T++] = (e << 16) | i;
        }
        cnt[8] = T;
    }
}

// -------- CSR build ----------------------------------------------------------------------
__global__ void deg_kernel(const int* __restrict__ dst, int* __restrict__ deg) {
    int t = blockIdx.x * blockDim.x + threadIdx.x;
    if (t < EE) atomicAdd(&deg[dst[t]], 1);
}

__global__ void scan1_kernel(const int* __restrict__ deg, int* __restrict__ start,
                             float* __restrict__ invd, int* __restrict__ bsum) {
    int t = threadIdx.x;
    int idx = blockIdx.x * 1024 + t;
    int v = deg[idx];
    int sc = v;
#pragma unroll
    for (int off = 1; off < 64; off <<= 1) {
        int u = __shfl_up(sc, off, 64);
        if ((t & 63) >= off) sc += u;
    }
    __shared__ int wsum[16], woff[16];
    if ((t & 63) == 63) wsum[t >> 6] = sc;
    __syncthreads();
    if (t == 0) {
        int acc = 0;
        for (int w = 0; w < 16; ++w) { woff[w] = acc; acc += wsum[w]; }
        bsum[blockIdx.x] = acc;
    }
    __syncthreads();
    start[idx] = woff[t >> 6] + sc - v;
    invd[idx] = v > 0 ? 1.0f / (float)v : 0.0f;
}

__global__ void scan2_kernel(int* __restrict__ bsum, int* __restrict__ boff) {
    if (threadIdx.x == 0) {
        int acc = 0;
        for (int b = 0; b < 32; ++b) { boff[b] = acc; acc += bsum[b]; }
    }
}

__global__ void scan3_kernel(int* __restrict__ start, int* __restrict__ cursor,
                             const int* __restrict__ boff) {
    int idx = blockIdx.x * 256 + threadIdx.x;
    int s = start[idx] + boff[idx >> 10];
    start[idx] = s;
    cursor[idx] = s;
}

__global__ void scatter_kernel(const int* __restrict__ src, const int* __restrict__ dst,
                               int* __restrict__ cursor, int* __restrict__ csr) {
    int t = blockIdx.x * blockDim.x + threadIdx.x;
    if (t < EE) {
        int d = dst[t];
        int pos = atomicAdd(&cursor[d], 1);
        csr[pos] = src[t];
    }
}

// -------- mean aggregation over CSR; multi-expert: grid = nExp*8192 blocks ---------------
template <bool F32IN>
__global__ void aggr_kernel(const void* __restrict__ hv, u16* __restrict__ outB,
                            const int* __restrict__ start, const int* __restrict__ deg,
                            const int* __restrict__ csr, const float* __restrict__ invd,
                            const float* __restrict__ wg, int eBase, size_t stride) {
    int eo = blockIdx.x >> 13;
    int node = ((blockIdx.x & 8191) << 2) + (threadIdx.x >> 6);
    int expert = eBase + eo;
    if (wg != nullptr && wg[(size_t)node * 4 + expert] == 0.f) return;
    int l = threadIdx.x & 63;
    int s0 = start[node];
    int dg = deg[node];
    u16* out = outB + (size_t)eo * stride;
    const u16* hB = (const u16*)hv + (size_t)eo * stride;
    const float* hF = (const float*)hv + (size_t)eo * stride;
    float a[8] = {0.f, 0.f, 0.f, 0.f, 0.f, 0.f, 0.f, 0.f};

    for (int base = 0; base < dg; base += 64) {
        int cnt = dg - base;
        if (cnt > 64) cnt = 64;
        int vidx = 0;
        if (l < cnt) vidx = csr[s0 + base + l];
        int q = 0;
        if (!F32IN) {
            for (; q + 8 <= cnt; q += 8) {
                int j0 = __shfl(vidx, q, 64);
                int j1 = __shfl(vidx, q + 1, 64);
                int j2 = __shfl(vidx, q + 2, 64);
                int j3 = __shfl(vidx, q + 3, 64);
                int j4 = __shfl(vidx, q + 4, 64);
                int j5 = __shfl(vidx, q + 5, 64);
                int j6 = __shfl(vidx, q + 6, 64);
                int j7 = __shfl(vidx, q + 7, 64);
                u16x8 v0 = *((const u16x8*)(hB + (size_t)j0 * DD) + l);
                u16x8 v1 = *((const u16x8*)(hB + (size_t)j1 * DD) + l);
                u16x8 v2 = *((const u16x8*)(hB + (size_t)j2 * DD) + l);
                u16x8 v3 = *((const u16x8*)(hB + (size_t)j3 * DD) + l);
                u16x8 v4 = *((const u16x8*)(hB + (size_t)j4 * DD) + l);
                u16x8 v5 = *((const u16x8*)(hB + (size_t)j5 * DD) + l);
                u16x8 v6 = *((const u16x8*)(hB + (size_t)j6 * DD) + l);
                u16x8 v7 = *((const u16x8*)(hB + (size_t)j7 * DD) + l);
#pragma unroll
                for (int q2 = 0; q2 < 8; ++q2)
                    a[q2] += ((b2f(v0[q2]) + b2f(v1[q2])) + (b2f(v2[q2]) + b2f(v3[q2]))) +
                             ((b2f(v4[q2]) + b2f(v5[q2])) + (b2f(v6[q2]) + b2f(v7[q2])));
            }
        }
        for (; q + 4 <= cnt; q += 4) {
            int j0 = __shfl(vidx, q, 64);
            int j1 = __shfl(vidx, q + 1, 64);
            int j2 = __shfl(vidx, q + 2, 64);
            int j3 = __shfl(vidx, q + 3, 64);
            if (F32IN) {
                const f32x4* r0 = (const f32x4*)(hF + (size_t)j0 * DD) + l * 2;
                const f32x4* r1 = (const f32x4*)(hF + (size_t)j1 * DD) + l * 2;
                const f32x4* r2 = (const f32x4*)(hF + (size_t)j2 * DD) + l * 2;
                const f32x4* r3 = (const f32x4*)(hF + (size_t)j3 * DD) + l * 2;
                f32x4 u0 = r0[0], u1 = r0[1];
                f32x4 u2 = r1[0], u3 = r1[1];
                f32x4 u4 = r2[0], u5 = r2[1];
                f32x4 u6 = r3[0], u7 = r3[1];
#pragma unroll
                for (int q2 = 0; q2 < 4; ++q2) {
                    a[q2] += (u0[q2] + u2[q2]) + (u4[q2] + u6[q2]);
                    a[4 + q2] += (u1[q2] + u3[q2]) + (u5[q2] + u7[q2]);
                }
            } else {
                u16x8 v0 = *((const u16x8*)(hB + (size_t)j0 * DD) + l);
                u16x8 v1 = *((const u16x8*)(hB + (size_t)j1 * DD) + l);
                u16x8 v2 = *((const u16x8*)(hB + (size_t)j2 * DD) + l);
                u16x8 v3 = *((const u16x8*)(hB + (size_t)j3 * DD) + l);
#pragma unroll
                for (int q2 = 0; q2 < 8; ++q2)
                    a[q2] += (b2f(v0[q2]) + b2f(v1[q2])) + (b2f(v2[q2]) + b2f(v3[q2]));
            }
        }
        for (; q < cnt; ++q) {
            int j = __shfl(vidx, q, 64);
            if (F32IN) {
                const f32x4* r = (const f32x4*)(hF + (size_t)j * DD) + l * 2;
                f32x4 u0 = r[0], u1 = r[1];
#pragma unroll
                for (int q2 = 0; q2 < 4; ++q2) { a[q2] += u0[q2]; a[4 + q2] += u1[q2]; }
            } else {
                u16x8 v = *((const u16x8*)(hB + (size_t)j * DD) + l);
#pragma unroll
                for (int q2 = 0; q2 < 8; ++q2) a[q2] += b2f(v[q2]);
            }
        }
    }
    float sc = invd[node];
    u16x8 o;
#pragma unroll
    for (int q2 = 0; q2 < 8; ++q2) o[q2] = f2b(a[q2] * sc);
    *((u16x8*)(out + (size_t)node * DD) + l) = o;
}

// -------- dual-expert gated aggregation -> COMPACTED output ------------------------------
// One wave = one node, both active experts; one csr index stream serves both; results
// written at compacted row ebase[e] + posn[node][e] so aggr1c is only 2*NN rows (64 MB).
__global__ void aggr2_kernel(const u16* __restrict__ h, u16* __restrict__ outC,
                             const int* __restrict__ start, const int* __restrict__ deg,
                             const int* __restrict__ csr, const float* __restrict__ invd,
                             const float* __restrict__ wg, const int* __restrict__ posn,
                             const int* __restrict__ cntb) {
    const int node = (blockIdx.x << 2) + (threadIdx.x >> 6);
    const int l = threadIdx.x & 63;
    const float* w = wg + (size_t)node * 4;
    int e0 = -1, e1 = -1;
#pragma unroll
    for (int e = 0; e < 4; ++e) {
        if (w[e] > 0.f) { if (e0 < 0) e0 = e; else e1 = e; }
    }
    if (e0 < 0) return;
    const int dual = (e1 >= 0);
    if (!dual) e1 = e0;
    const size_t STRE = (size_t)NN * DD;
    const u16* hA = h + (size_t)e0 * STRE;
    const u16* hC = h + (size_t)e1 * STRE;
    const int g0 = cntb[4 + e0] + posn[node * 4 + e0];
    const int g1 = cntb[4 + e1] + posn[node * 4 + e1];
    const int s0 = start[node];
    const int dg = deg[node];
    float a0[8] = {0.f, 0.f, 0.f, 0.f, 0.f, 0.f, 0.f, 0.f};
    float a1[8] = {0.f, 0.f, 0.f, 0.f, 0.f, 0.f, 0.f, 0.f};

    for (int base = 0; base < dg; base += 64) {
        int cnt = dg - base;
        if (cnt > 64) cnt = 64;
        int vidx = 0;
        if (l < cnt) vidx = csr[s0 + base + l];
        int q = 0;
        for (; q + 4 <= cnt; q += 4) {
            int j0 = __shfl(vidx, q, 64);
            int j1 = __shfl(vidx, q + 1, 64);
            int j2 = __shfl(vidx, q + 2, 64);
            int j3 = __shfl(vidx, q + 3, 64);
            u16x8 u0 = *((const u16x8*)(hA + (size_t)j0 * DD) + l);
            u16x8 u1 = *((const u16x8*)(hA + (size_t)j1 * DD) + l);
            u16x8 u2 = *((const u16x8*)(hA + (size_t)j2 * DD) + l);
            u16x8 u3 = *((const u16x8*)(hA + (size_t)j3 * DD) + l);
            u16x8 t0 = *((const u16x8*)(hC + (size_t)j0 * DD) + l);
            u16x8 t1 = *((const u16x8*)(hC + (size_t)j1 * DD) + l);
            u16x8 t2 = *((const u16x8*)(hC + (size_t)j2 * DD) + l);
            u16x8 t3 = *((const u16x8*)(hC + (size_t)j3 * DD) + l);
#pragma unroll
            for (int q2 = 0; q2 < 8; ++q2) {
                a0[q2] += (b2f(u0[q2]) + b2f(u1[q2])) + (b2f(u2[q2]) + b2f(u3[q2]));
                a1[q2] += (b2f(t0[q2]) + b2f(t1[q2])) + (b2f(t2[q2]) + b2f(t3[q2]));
            }
        }
        for (; q < cnt; ++q) {
            int j = __shfl(vidx, q, 64);
            u16x8 u = *((const u16x8*)(hA + (size_t)j * DD) + l);
            u16x8 t = *((const u16x8*)(hC + (size_t)j * DD) + l);
#pragma unroll
            for (int q2 = 0; q2 < 8; ++q2) { a0[q2] += b2f(u[q2]); a1[q2] += b2f(t[q2]); }
        }
    }
    float sc = invd[node];
    u16x8 o0, o1;
#pragma unroll
    for (int q2 = 0; q2 < 8; ++q2) { o0[q2] = f2b(a0[q2] * sc); o1[q2] = f2b(a1[q2] * sc); }
    *((u16x8*)(outC + (size_t)g0 * DD) + l) = o0;
    if (dual)
        *((u16x8*)(outC + (size_t)g1 * DD) + l) = o1;
}

__device__ __forceinline__ void gload16(const void* g, void* l) {
    __builtin_amdgcn_global_load_lds((const __attribute__((address_space(1))) void*)g,
                                     (__attribute__((address_space(3))) void*)l, 16, 0, 0);
}

// -------- fused GEMM (L0 + fallback tiers): A and B both staged through LDS --------------
template <bool A2F32>
__global__ void __launch_bounds__(256, 4) gemm_kernel(
    const u16* __restrict__ A1, const u16* __restrict__ A2b, const float* __restrict__ A2f,
    size_t sA, const u16* __restrict__ Bt, size_t sBt,
    const float* __restrict__ bias, size_t sBias,
    u16* __restrict__ Hout, size_t sH, float* __restrict__ Out,
    const float* __restrict__ wg, int mode, int eBase, int ntt) {
    __shared__ u16 lds[A2F32 ? 12288 : 8192];
    u16* ldsA = lds;
    float* ldsF = (float*)lds;
    u16* ldsB = lds + (A2F32 ? 8192 : 4096);
    const int tid = threadIdx.x;
    const int lane = tid & 63;
    const int w = tid >> 6;

    const int bid = blockIdx.x;
    const int xcd = bid & 7;
    const int local = bid >> 3;
    const int mtl = local / ntt;
    const int sub = local - mtl * ntt;
    const int expert = sub >> 2;
    const int wgE = eBase + expert;
    const int m0 = (xcd * 32 + mtl) * 128;
    const int n0 = (sub & 3) * 128;

    const u16* A1p = A1 + (size_t)expert * sA;
    const u16* A2p = A2b + (size_t)expert * sA;
    const u16* Btp = Bt + (size_t)expert * sBt;
    const float* biasp = bias + (size_t)expert * sBias;
    u16* Houtp = Hout + (size_t)expert * sH;

    const int wm = (w >> 1) * 64;
    const int wn = (w & 1) * 64;

    f32x4 acc[4][4];
#pragma unroll
    for (int i = 0; i < 4; ++i)
#pragma unroll
        for (int j = 0; j < 4; ++j) acc[i][j] = (f32x4){0.f, 0.f, 0.f, 0.f};

    const int p0 = tid, p1 = 256 + tid;
    const int r0 = p0 >> 2, c0 = ((p0 & 3) - (r0 >> 1)) & 3;
    const int r1 = p1 >> 2, c1 = ((p1 & 3) - (r1 >> 1)) & 3;
    const int arow = lane & 15;
    const int kc = lane >> 4;

    for (int kb = 0; kb < 32; ++kb) {
        __syncthreads();
        if (!A2F32 || kb < 16) {
            const u16* As = (kb < 16) ? A1p : A2p;
            const int kcol = (kb & 15) * 32;
            gload16(As + (size_t)(m0 + r0) * DD + kcol + c0 * 8, ldsA + p0 * 8);
            gload16(As + (size_t)(m0 + r1) * DD + kcol + c1 * 8, ldsA + p1 * 8);
        } else {
            const float* Af = A2f + (size_t)m0 * DD + (kb - 16) * 32;
#pragma unroll
            for (int q = 0; q < 4; ++q) {
                int p = q * 256 + tid;
                int rr = p >> 3, cpos = p & 7, cc2 = (cpos - rr) & 7;
                gload16(Af + (size_t)rr * DD + cc2 * 4, ldsF + p * 4);
            }
        }
        gload16(Btp + (size_t)(n0 + r0) * 1024 + kb * 32 + c0 * 8, ldsB + p0 * 8);
        gload16(Btp + (size_t)(n0 + r1) * 1024 + kb * 32 + c1 * 8, ldsB + p1 * 8);
        __syncthreads();
        s16x8 af[4], bf[4];
        if (!A2F32 || kb < 16) {
#pragma unroll
            for (int f = 0; f < 4; ++f) {
                int ra = wm + f * 16 + arow;
                int pa = (kc + (ra >> 1)) & 3;
                af[f] = *(const s16x8*)(ldsA + (ra * 4 + pa) * 8);
            }
        } else {
#pragma unroll
            for (int f = 0; f < 4; ++f) {
                int ra = wm + f * 16 + arow;
                int plo = ra * 8 + ((2 * kc + ra) & 7);
                int phi = ra * 8 + ((2 * kc + 1 + ra) & 7);
                f32x4 lo = *(const f32x4*)(ldsF + plo * 4);
                f32x4 hi = *(const f32x4*)(ldsF + phi * 4);
                s16x8 t;
                t[0] = (short)f2b(lo[0]); t[1] = (short)f2b(lo[1]);
                t[2] = (short)f2b(lo[2]); t[3] = (short)f2b(lo[3]);
                t[4] = (short)f2b(hi[0]); t[5] = (short)f2b(hi[1]);
                t[6] = (short)f2b(hi[2]); t[7] = (short)f2b(hi[3]);
                af[f] = t;
            }
        }
#pragma unroll
        for (int f = 0; f < 4; ++f) {
            int rb = wn + f * 16 + arow;
            int pb = (kc + (rb >> 1)) & 3;
            bf[f] = *(const s16x8*)(ldsB + (rb * 4 + pb) * 8);
        }
#pragma unroll
        for (int i = 0; i < 4; ++i)
#pragma unroll
            for (int j = 0; j < 4; ++j)
                acc[i][j] = __builtin_amdgcn_mfma_f32_16x16x32_bf16(af[i], bf[j], acc[i][j], 0, 0, 0);
    }

    const int colq = lane & 15;
    const int rq = lane >> 4;
#pragma unroll
    for (int i = 0; i < 4; ++i) {
#pragma unroll
        for (int j = 0; j < 4; ++j) {
            int col = n0 + wn + j * 16 + colq;
            float bv = biasp[col];
#pragma unroll
            for (int r = 0; r < 4; ++r) {
                int row = m0 + wm + i * 16 + rq * 4 + r;
                float v = fmaxf(acc[i][j][r] + bv, 0.f);
                size_t idx = (size_t)row * DD + col;
                if (mode == 0) {
                    Houtp[idx] = f2b(v);
                } else {
                    float wv = wg[(size_t)row * 4 + wgE];
                    if (mode == 1) {
                        Out[idx] = wv * v;
                    } else if (mode == 2) {
                        if (wv > 0.f) Out[idx] += wv * v;
                    } else {
                        if (wv > 0.f) unsafeAtomicAdd(&Out[idx], wv * v);
                    }
                }
            }
        }
    }
}

// -------- L1 GEMM over compacted rows: out[node] += wv * relu([aggr1c|h1]@Bt^T + b) ------
// XCD-local decode (round-8 fix): round 7 measured FETCH 275 MB / MfmaUtil 13% because
// the 4 n-blocks of a tile had consecutive blockIdx -> 4 different XCDs -> the shared
// A panel was fetched 4x from HBM. Now tile t lives on XCD (t&7): its 4 n-blocks take
// bids ((slot*4+j)<<3)|xcd, all congruent mod 8 -> same XCD L2 -> one A fetch per tile.
__global__ void __launch_bounds__(256, 4) gemm_gather_kernel(
    const u16* __restrict__ A1c, const u16* __restrict__ A2,
    const u16* __restrict__ Bt, const float* __restrict__ bias,
    float* __restrict__ Out, const float* __restrict__ wg,
    const int* __restrict__ list, const int* __restrict__ cntb,
    const int* __restrict__ tmap) {
    const int xcd = blockIdx.x & 7;
    const int local = blockIdx.x >> 3;
    const int j4 = local & 3;
    const int slot = local >> 2;
    const int t = slot * 8 + xcd;
    if (t >= cntb[8]) return;
    const u32 mi = (u32)tmap[t];
    const int e = mi >> 16;
    const int mt = mi & 0xffff;
    const int cntE = cntb[e];
    const int eb = cntb[4 + e];
    const int base = mt << 7;
    const int n0 = j4 * 128;

    __shared__ u16 lds[8192];
    u16* ldsA = lds;
    u16* ldsB = lds + 4096;
    const int tid = threadIdx.x;
    const int lane = tid & 63;
    const int w = tid >> 6;

    const size_t STRE = (size_t)NN * DD;
    const u16* A2p = A2 + (size_t)e * STRE;
    const u16* Btp = Bt + (size_t)e * (2 * WMAT);
    const float* biasp = bias + (size_t)e * 1024;
    const int* listE = list + e * NN;

    const int wm = (w >> 1) * 64;
    const int wn = (w & 1) * 64;

    f32x4 acc[4][4];
#pragma unroll
    for (int i = 0; i < 4; ++i)
#pragma unroll
        for (int j = 0; j < 4; ++j) acc[i][j] = (f32x4){0.f, 0.f, 0.f, 0.f};

    const int p0 = tid, p1 = 256 + tid;
    const int r0 = p0 >> 2, c0 = ((p0 & 3) - (r0 >> 1)) & 3;
    const int r1 = p1 >> 2, c1 = ((p1 & 3) - (r1 >> 1)) & 3;
    int g0 = eb + base + r0; if (g0 > 2 * NN - 1) g0 = 2 * NN - 1;
    int g1 = eb + base + r1; if (g1 > 2 * NN - 1) g1 = 2 * NN - 1;
    int q0 = base + r0; if (q0 >= cntE) q0 = cntE - 1;
    int q1 = base + r1; if (q1 >= cntE) q1 = cntE - 1;
    const int gr0 = listE[q0];
    const int gr1 = listE[q1];
    const int arow = lane & 15;
    const int kc = lane >> 4;

    for (int kb = 0; kb < 32; ++kb) {
        __syncthreads();
        if (kb < 16) {
            const int kcol = kb * 32;
            gload16(A1c + (size_t)g0 * DD + kcol + c0 * 8, ldsA + p0 * 8);
            gload16(A1c + (size_t)g1 * DD + kcol + c1 * 8, ldsA + p1 * 8);
        } else {
            const int kcol = (kb - 16) * 32;
            gload16(A2p + (size_t)gr0 * DD + kcol + c0 * 8, ldsA + p0 * 8);
            gload16(A2p + (size_t)gr1 * DD + kcol + c1 * 8, ldsA + p1 * 8);
        }
        gload16(Btp + (size_t)(n0 + r0) * 1024 + kb * 32 + c0 * 8, ldsB + p0 * 8);
        gload16(Btp + (size_t)(n0 + r1) * 1024 + kb * 32 + c1 * 8, ldsB + p1 * 8);
        __syncthreads();
        s16x8 af[4], bf[4];
#pragma unroll
        for (int f = 0; f < 4; ++f) {
            int ra = wm + f * 16 + arow;
            int pa = (kc + (ra >> 1)) & 3;
            af[f] = *(const s16x8*)(ldsA + (ra * 4 + pa) * 8);
        }
#pragma unroll
        for (int f = 0; f < 4; ++f) {
            int rb = wn + f * 16 + arow;
            int pb = (kc + (rb >> 1)) & 3;
            bf[f] = *(const s16x8*)(ldsB + (rb * 4 + pb) * 8);
        }
#pragma unroll
        for (int i = 0; i < 4; ++i)
#pragma unroll
            for (int j = 0; j < 4; ++j)
                acc[i][j] = __builtin_amdgcn_mfma_f32_16x16x32_bf16(af[i], bf[j], acc[i][j], 0, 0, 0);
    }

    const int colq = lane & 15;
    const int rq = lane >> 4;
#pragma unroll
    for (int i = 0; i < 4; ++i) {
        int nd[4]; float wv4[4]; bool val[4];
#pragma unroll
        for (int r = 0; r < 4; ++r) {
            int rowl = base + wm + i * 16 + rq * 4 + r;
            val[r] = rowl < cntE;
            int qq = val[r] ? rowl : 0;
            nd[r] = listE[qq];
            wv4[r] = wg[(size_t)nd[r] * 4 + e];
        }
#pragma unroll
        for (int j = 0; j < 4; ++j) {
            int col = n0 + wn + j * 16 + colq;
            float bv = biasp[col];
#pragma unroll
            for (int r = 0; r < 4; ++r) {
                if (val[r]) {
                    float v = fmaxf(acc[i][j][r] + bv, 0.f);
                    unsafeAtomicAdd(&Out[(size_t)nd[r] * DD + col], wv4[r] * v);
                }
            }
        }
    }
}

extern "C" void kernel_launch(void* const* d_in, const int* in_sizes, int n_in,
                              void* d_out, int out_size, void* d_ws, size_t ws_size,
                              hipStream_t stream) {
    const float* x  = (const float*)d_in[0];
    const float* gW = (const float*)d_in[1];
    const float* gb = (const float*)d_in[2];
    const float* Wl = (const float*)d_in[3];
    const float* bl = (const float*)d_in[4];
    const float* Wr = (const float*)d_in[5];
    const u32*   ei = (const u32*)d_in[6];
    float* outp = (float*)d_out;

    char* ws = (char*)d_ws;
    size_t off = 0;
    auto alloc = [&](size_t bytes) -> void* {
        void* p = ws + off;
        off += (bytes + 255) & ~(size_t)255;
        return p;
    };
    const size_t MB32 = (size_t)NN * DD * 2;
    const size_t STR = (size_t)NN * DD;      // per-expert element stride
    int*   flags  = (int*)alloc(512);
    float* wg     = (float*)alloc((size_t)NN * 4 * 4);
    int*   deg    = (int*)alloc((size_t)NN * 4);
    int*   start  = (int*)alloc((size_t)NN * 4);
    int*   cursor = (int*)alloc((size_t)NN * 4);
    float* invd   = (float*)alloc((size_t)NN * 4);
    int*   src32  = (int*)alloc((size_t)EE * 4);
    int*   dst32  = (int*)alloc((size_t)EE * 4);
    int*   csr    = (int*)alloc((size_t)EE * 4);
    u16*   Bt     = (u16*)alloc((size_t)8 * WMAT * 2);       // 8 MB
    int*   cnt    = (int*)alloc(64);                          // [0..3] cnt, [4..7] ebase, [8] tcount
    int*   tmap   = (int*)alloc(1040 * 4);
    // Aliases (dead after scatter_kernel): list <- dst32, posn <- src32.
    int*   list   = dst32;
    int*   posn   = src32;

    size_t rem = (ws_size > off) ? ws_size - off : 0;
    // ws_size ~= 256 MiB on this harness. Tier 0 (compact-fused) sized to the validated
    // 224 MB budget: xb (32) + h1 (128) + aggr1c (64, compacted 2*NN rows).
    int tier;
    if      (rem >= 7 * MB32 + 65536) tier = 0;   // compact-fused (224 MB)
    else if (rem >= 6 * MB32 + 65536) tier = 2;   // bf16 fused L0, sequential L1 (192 MB)
    else if (rem >= 5 * MB32 + 65536) tier = 3;   // fp32-staged fused L0 (160 MB)
    else if (rem >= 4 * MB32 + 65536) tier = 4;   // sequential (128 MB)
    else                              tier = 5;   // fp32 fallback (96 MB)

    u16 *xb = nullptr, *h1 = nullptr, *aggr1 = nullptr, *aggr0 = nullptr;
    if (tier == 0) {
        xb = (u16*)alloc(MB32);
        h1 = (u16*)alloc(4 * MB32);
        aggr1 = (u16*)alloc(2 * MB32);      // compacted: 2*NN rows
        aggr0 = aggr1;                      // dense L0 aggr (32 MB) aliases head; dead before aggr2
    } else if (tier == 2) {
        xb = (u16*)alloc(MB32);
        h1 = (u16*)alloc(4 * MB32);
        aggr1 = (u16*)alloc(MB32);
        aggr0 = aggr1;
    } else if (tier == 3) {
        aggr0 = (u16*)alloc(MB32);
        h1 = (u16*)alloc(4 * MB32);
        aggr1 = aggr0;
    } else if (tier == 4) {
        aggr0 = (u16*)alloc(MB32);
        xb = (u16*)alloc(MB32);
        h1 = (u16*)alloc(MB32);
        aggr1 = (u16*)alloc(MB32);
    } else {
        aggr0 = (u16*)alloc(MB32);
        h1 = (u16*)alloc(MB32);
        aggr1 = (u16*)alloc(MB32);
    }

    int* bsum = flags + 16;
    int* boff = flags + 64;

    hipMemsetAsync(deg, 0, (size_t)NN * 4, stream);

    detect_kernel<<<1, 64, 0, stream>>>(ei, flags);
    edges_kernel<<<EE / 256, 256, 0, stream>>>(ei, flags, src32, dst32);
    transpose_kernel<<<16 * 256, 256, 0, stream>>>(Wl, Wr, Bt);
    if (xb != nullptr)
        gateconv_kernel<<<NN / 4, 256, 0, stream>>>(x, gW, gb, wg, xb);
    else
        gate_kernel<<<NN / 4, 256, 0, stream>>>(x, gW, gb, wg);
    deg_kernel<<<EE / 256, 256, 0, stream>>>(dst32, deg);
    scan1_kernel<<<32, 1024, 0, stream>>>(deg, start, invd, bsum);
    scan2_kernel<<<1, 64, 0, stream>>>(bsum, boff);
    scan3_kernel<<<NN / 256, 256, 0, stream>>>(start, cursor, boff);
    scatter_kernel<<<EE / 256, 256, 0, stream>>>(src32, dst32, cursor, csr);

    if (tier == 0) {
        // src32/dst32 dead; their storage backs posn/list from here.
        hipMemsetAsync(cnt, 0, 64, stream);
        compact_kernel<<<NN / 256, 256, 0, stream>>>(wg, cnt, list, posn);
        tilemap_kernel<<<1, 64, 0, stream>>>(cnt, tmap);
        // L0: dense aggr + LDS-staged GEMM
        aggr_kernel<false><<<8192, 256, 0, stream>>>(xb, aggr0, start, deg, csr, invd,
                                                     nullptr, 0, 0);
        gemm_kernel<false><<<256 * 16, 256, 0, stream>>>(
            aggr0, xb, nullptr, /*sA=*/0, Bt, /*sBt=*/2 * WMAT, bl, /*sBias=*/1024,
            h1, /*sH=*/STR, nullptr, wg, /*mode=*/0, /*eBase=*/0, /*ntt=*/16);
        hipMemsetAsync(outp, 0, (size_t)NN * DD * 4, stream);
        // L1: dual-expert aggr -> compacted rows; XCD-local gather-GEMM over top-2 rows
        aggr2_kernel<<<8192, 256, 0, stream>>>(h1, aggr1, start, deg, csr, invd, wg,
                                               posn, cnt);
        // grid = slots(65) x 4 n-blocks x 8 xcds; covers tcount <= 520
        gemm_gather_kernel<<<65 * 4 * 8, 256, 0, stream>>>(
            aggr1, h1, Bt + WMAT, bl + 512, outp, wg, list, cnt, tmap);
    } else if (tier == 2) {
        aggr_kernel<false><<<8192, 256, 0, stream>>>(xb, aggr0, start, deg, csr, invd,
                                                     nullptr, 0, 0);
        gemm_kernel<false><<<256 * 16, 256, 0, stream>>>(
            aggr0, xb, nullptr, 0, Bt, 2 * WMAT, bl, 1024,
            h1, STR, nullptr, wg, 0, 0, 16);
        for (int e = 0; e < 4; ++e) {
            aggr_kernel<false><<<8192, 256, 0, stream>>>(
                h1 + (size_t)e * STR, aggr1, start, deg, csr, invd, wg, e, 0);
            gemm_kernel<false><<<256 * 4, 256, 0, stream>>>(
                aggr1, h1 + (size_t)e * STR, nullptr, 0,
                Bt + (size_t)(e * 2 + 1) * WMAT, 0, bl + (e * 2 + 1) * 512, 0,
                nullptr, 0, outp, wg, (e == 0) ? 1 : 2, e, 4);
        }
    } else if (tier == 3) {
        aggr_kernel<true><<<8192, 256, 0, stream>>>(x, aggr0, start, deg, csr, invd,
                                                    nullptr, 0, 0);
        gemm_kernel<true><<<256 * 16, 256, 0, stream>>>(
            aggr0, nullptr, x, 0, Bt, 2 * WMAT, bl, 1024,
            h1, STR, nullptr, wg, 0, 0, 16);
        for (int e = 0; e < 4; ++e) {
            aggr_kernel<false><<<8192, 256, 0, stream>>>(
                h1 + (size_t)e * STR, aggr1, start, deg, csr, invd, wg, e, 0);
            gemm_kernel<false><<<256 * 4, 256, 0, stream>>>(
                aggr1, h1 + (size_t)e * STR, nullptr, 0,
                Bt + (size_t)(e * 2 + 1) * WMAT, 0, bl + (e * 2 + 1) * 512, 0,
                nullptr, 0, outp, wg, (e == 0) ? 1 : 2, e, 4);
        }
    } else {
        if (tier == 4) {
            aggr_kernel<false><<<8192, 256, 0, stream>>>(xb, aggr0, start, deg, csr, invd,
                                                         nullptr, 0, 0);
        } else {
            aggr_kernel<true><<<8192, 256, 0, stream>>>(x, aggr0, start, deg, csr, invd,
                                                        nullptr, 0, 0);
        }
        for (int e = 0; e < 4; ++e) {
            const u16* BtL0 = Bt + (size_t)(e * 2 + 0) * WMAT;
            const u16* BtL1 = Bt + (size_t)(e * 2 + 1) * WMAT;
            const float* b0 = bl + (e * 2 + 0) * 512;
            const float* b1 = bl + (e * 2 + 1) * 512;
            if (tier == 4)
                gemm_kernel<false><<<256 * 4, 256, 0, stream>>>(
                    aggr0, xb, nullptr, 0, BtL0, 0, b0, 0, h1, 0, nullptr, wg, 0, e, 4);
            else
                gemm_kernel<true><<<256 * 4, 256, 0, stream>>>(
                    aggr0, nullptr, x, 0, BtL0, 0, b0, 0, h1, 0, nullptr, wg, 0, e, 4);
            aggr_kernel<false><<<8192, 256, 0, stream>>>(h1, aggr1, start, deg, csr, invd,
                                                         wg, e, 0);
            gemm_kernel<false><<<256 * 4, 256, 0, stream>>>(
                aggr1, h1, nullptr, 0, BtL1, 0, b1, 0, nullptr, 0, outp, wg,
                (e == 0) ? 1 : 2, e, 4);
        }
    }
}